// Round 1
// baseline (50974.194 us; speedup 1.0000x reference)
//
#include <hip/hip_runtime.h>
#include <math.h>

#define DEV static __device__ __forceinline__

// ---------------- calibration (s, z) constants, computed like the reference ----------------
struct SZ { float s, z; };

constexpr double cfloor_(double v){ long long i=(long long)v; return ((double)i > v) ? (double)(i-1) : (double)i; }
constexpr double cround_(double v){            // round half-to-even (Python round / nearbyint)
  double fl = cfloor_(v); double fr = v - fl;
  return (fr > 0.5) ? fl + 1.0 : (fr < 0.5 ? fl : ((((long long)fl) & 1LL) == 0 ? fl : fl + 1.0));
}
constexpr SZ mksz(double mn, double mx){
  double s = (mx - mn) / 255.0;
  double z = cround_(-mn / s);
  return SZ{ (float)s, (float)z };
}

constexpr SZ Zx     = mksz(-0.0025095, 0.0022181);
constexpr SZ ZW1    = mksz(-0.22075387835502625, 0.208940327167511);
constexpr SZ Zfc1mm = mksz(-0.00291599917, 0.0017367251);
constexpr SZ Zbfc1  = mksz(-0.48688140511512756, 0.5176185369491577);
constexpr SZ Zfc1add= mksz(-0.48778465390205383, 0.5181604027748108);
// layer-1 weights/biases
constexpr SZ ZWiz1 = mksz(-0.43284985423088074, 0.46175122261047363);
constexpr SZ ZWir1 = mksz(-0.34401071071624756, 0.29191476106643677);
constexpr SZ ZWin1 = mksz(-0.3236880302429199, 0.39607325196266174);
constexpr SZ ZWhz1 = mksz(-1.8417714834213257, 1.7173254489898682);
constexpr SZ ZWhr1 = mksz(-1.1574513912200928, 1.0300449132919312);
constexpr SZ ZWhn1 = mksz(-0.7756922245025635, 0.9530389308929443);
constexpr SZ Zbiz1 = mksz(-0.5063393712043762, 0.36664387583732605);
constexpr SZ Zbir1 = mksz(-0.07920225709676743, 0.20611026883125305);
constexpr SZ Zbin1 = mksz(-0.5539973378181458, 0.17938342690467834);
constexpr SZ Zbhz1 = mksz(-0.5337516665458679, 0.4148772358894348);
constexpr SZ Zbhr1 = mksz(-0.07688436657190323, 0.14814253151416779);
constexpr SZ Zbhn1 = mksz(-0.7828555107116699, 0.9008108973503113);
// layer-2 weights/biases
constexpr SZ ZWiz2 = mksz(-0.9102030992507935, 0.9408696889877319);
constexpr SZ ZWir2 = mksz(-0.9560997486114502, 0.6683358550071716);
constexpr SZ ZWin2 = mksz(-0.4721935987472534, 0.48561596870422363);
constexpr SZ ZWhz2 = mksz(-1.2992678880691528, 1.2991048097610474);
constexpr SZ ZWhr2 = mksz(-0.8318714499473572, 1.1085889339447021);
constexpr SZ ZWhn2 = mksz(-0.955470085144043, 1.046797513961792);
constexpr SZ Zbiz2 = mksz(-0.44805487990379333, 0.1560053527355194);
constexpr SZ Zbir2 = mksz(-0.08767592161893845, 0.11347303539514542);
constexpr SZ Zbin2 = mksz(-0.239909827709198, 0.12033259868621826);
constexpr SZ Zbhz2 = mksz(-0.43745461106300354, 0.12699371576309204);
constexpr SZ Zbhr2 = mksz(-0.09617264568805695, 0.07690174877643585);
constexpr SZ Zbhn2 = mksz(-0.17204178869724274, 0.19739042222499847);
// fc tail
constexpr SZ ZWfc2 = mksz(-1.3657219409942627, 1.158295750617981);
constexpr SZ Zbfc2 = mksz(-0.1750922054052353, 0.1385071724653244);
constexpr SZ ZWfc3 = mksz(-3.1666038036346436, 2.5026357173919678);
constexpr SZ Zbfc3 = mksz(-0.10188056528568268, 0.0899151861667633);
constexpr SZ ZWfc4 = mksz(-1.300571084022522, 1.928941249847412);
constexpr SZ Zbfc4 = mksz(-0.10699586570262909, 0.04597663879394531);
// gru1 stages
constexpr SZ Za_1 = mksz(-0.6389939785003662, 0.7715625762939453);
constexpr SZ Za1  = mksz(-0.6046768426895142, 0.8871182203292847);
constexpr SZ Zb_1 = mksz(-0.004922409541904926, 0.004103424027562141);
constexpr SZ Zb1  = mksz(-0.07475128024816513, 0.14630259573459625);
constexpr SZ Zc_1 = mksz(-1.5660111904144287, 1.0454494953155518);
constexpr SZ Zc1  = mksz(-1.9779117107391357, 1.3700535297393799);
constexpr SZ Zd_1 = mksz(-0.008429044857621193, 0.006403823848813772);
constexpr SZ Zd1  = mksz(-0.5529640316963196, 0.41507571935653687);
constexpr SZ Ze_1 = mksz(-1.3637111186981201, 1.018247127532959);
constexpr SZ Ze1  = mksz(-1.8583884239196777, 1.1587692499160767);
constexpr SZ Zf_1 = mksz(-0.005411399528384209, 0.0061536869034171104);
constexpr SZ Zf1  = mksz(-0.7833794355392456, 0.8978855013847351);
constexpr SZ Zr_1 = mksz(-0.6226556301116943, 0.9800534844398499);
constexpr SZ Zr1  = mksz(0.3491777181625366, 0.7271188497543335);
constexpr SZ Zz_1 = mksz(-2.392332077026367, 1.7851293087005615);
constexpr SZ Zz1  = mksz(0.08375928550958633, 0.856329083442688);
constexpr SZ Zn11 = mksz(-0.5516456365585327, 0.4556601643562317);
constexpr SZ Zn21 = mksz(-2.4100341796875, 1.1423156261444092);
constexpr SZ Zn1  = mksz(-0.983996570110321, 0.8151924014091492);
constexpr SZ Zhn11= mksz(0.143670916557312, 0.9162406921386719);
constexpr SZ Zhn21= mksz(-0.9015777111053467, 0.45391541719436646);
constexpr SZ Zhn31= mksz(-0.0016954239690676332, 0.0016671211924403906);
constexpr SZ Zrnn = mksz(-0.9016271829605103, 0.4546271562576294);
// gru2 explicit entries (the rest fall back to gru1 values, incl. rnn2GRU)
constexpr SZ Za_2 = mksz(-0.681461751461029, 0.9113116264343262);
constexpr SZ Za2  = mksz(-0.7149235010147095, 0.908741295337677);
constexpr SZ Zb_2 = mksz(-0.005148397758603096, 0.011014967225492);
constexpr SZ Zb2g = mksz(-0.09436552226543427, 0.07623167335987091);
constexpr SZ Zc_2 = mksz(-1.2279887199401855, 1.1102137565612793);
constexpr SZ Zc2  = mksz(-1.6760436296463013, 1.200895071029663);
constexpr SZ Zd_2 = mksz(-0.008141756057739258, 0.00894666276872158);
constexpr SZ Zd2  = mksz(-0.43875735998153687, 0.1262134611606598);
constexpr SZ Ze_2 = mksz(-0.6732944250106812, 0.6314664483070374);

struct RecP {
  SZ wr, wz, wn;                 // Wh scale/zero for gates r,z,n
  SZ a, c, e;                    // code grids of A/C/E
  SZ b1, b2, d1, d2, f1, f2;     // b_,b,d_,d,f_,f
  SZ r1, r2, z1, z2;             // r_,r,z_,z
  SZ n1, n2, n3;                 // n1,n2,n
  SZ hn1, hn2, hn3, rnn;
};
constexpr RecP PL1 = { ZWhr1, ZWhz1, ZWhn1, Za1, Zc1, Ze1, Zb_1, Zb1, Zd_1, Zd1, Zf_1, Zf1,
                       Zr_1, Zr1, Zz_1, Zz1, Zn11, Zn21, Zn1, Zhn11, Zhn21, Zhn31, Zrnn };
constexpr RecP PL2 = { ZWhr2, ZWhz2, ZWhn2, Za2, Zc2, Ze1, Zb_2, Zb2g, Zd_2, Zd2, Zf_1, Zf1,
                       Zr_1, Zr1, Zz_1, Zz1, Zn11, Zn21, Zn1, Zhn11, Zhn21, Zhn31, Zrnn };

// ---------------- device helpers ----------------
DEV float fq_(float x, float s, float z){
  float q = rintf(x / s) + z;                 // jnp.round = half-even = rintf
  q = fminf(fmaxf(q, 0.f), 255.f);
  return (q - z) * s;
}
DEV float sigm_(float v){ return 1.f / (1.f + expf(-v)); }

DEV unsigned udot4_(unsigned a, unsigned b, unsigned c){
#if defined(__has_builtin) && __has_builtin(__builtin_amdgcn_udot4)
  return __builtin_amdgcn_udot4(a, b, c, false);
#else
  return c + (a & 255u) * (b & 255u) + ((a >> 8) & 255u) * ((b >> 8) & 255u)
           + ((a >> 16) & 255u) * ((b >> 16) & 255u) + (a >> 24) * (b >> 24);
#endif
}

// ---------------- prep kernels ----------------
__global__ __launch_bounds__(256) void kfq(const float* __restrict__ src, float* __restrict__ dst,
                                           int n, float s, float z){
  int i = blockIdx.x * 256 + threadIdx.x;
  if (i < n) dst[i] = fq_(src[i], s, z);
}
// Wh [400][400] (k-major) -> u8 codes, column-major [j][k]
__global__ __launch_bounds__(256) void kwhc(const float* __restrict__ W, unsigned char* __restrict__ dst,
                                            float s, float z){
  int i = blockIdx.x * 256 + threadIdx.x;
  if (i < 160000) {
    int j = i / 400, k = i - j * 400;
    float q = rintf(W[k * 400 + j] / s) + z;
    q = fminf(fmaxf(q, 0.f), 255.f);
    dst[i] = (unsigned char)q;
  }
}
__global__ __launch_bounds__(256) void kcolsum(const unsigned char* __restrict__ WhC, int* __restrict__ cs){
  int i = blockIdx.x * 256 + threadIdx.x;
  if (i < 2400) {
    const unsigned char* p = WhC + (size_t)i * 400;
    int s = 0;
    for (int k = 0; k < 400; ++k) s += p[k];
    cs[i] = s;
  }
}
__global__ __launch_bounds__(256) void kinit(unsigned char* __restrict__ hbuf, unsigned int* __restrict__ cnt,
                                             int code){
  int i = blockIdx.x * 256 + threadIdx.x;
  if (i < 25600) { hbuf[i] = (unsigned char)code; hbuf[51200 + i] = (unsigned char)code; }
  if (i < 128) cnt[i] = 0u;
}

// ---------------- tiled f32 GEMM with fused fq epilogues ----------------
// BM=BN=128, BK=16, 256 threads, 8x8 microtile. M must be a multiple of 128.
// aMode: 0 = f32 plain, 1 = u8 codes dequant (K%16==0), 2 = x [B,T,F] permuted + fq('x')
// epMode: 0 = fq(e1) + bias -> fq-code(e2) u8 ; 2 = +bias, relu -> f32 ; 3 = +bias, sigmoid -> f32 permuted [B,T,F]
__global__ __launch_bounds__(256) void gemm_k(
    const float* __restrict__ Af, const unsigned char* __restrict__ Au8,
    const float* __restrict__ B, const float* __restrict__ bias,
    float* __restrict__ outF, unsigned char* __restrict__ outU8,
    int M, int N, int K, int aMode, int epMode, int rowOff,
    float aS, float aZ, float e1S, float e1Z, float e2S, float e2Z)
{
  __shared__ __align__(16) float As[16][132];
  __shared__ __align__(16) float Bs[16][132];
  const int tid = threadIdx.x;
  const int m0 = blockIdx.x * 128;
  const int n0 = blockIdx.y * 128;
  const int tx = tid & 15, ty = tid >> 4;
  float acc[8][8];
#pragma unroll
  for (int i = 0; i < 8; ++i)
#pragma unroll
    for (int j = 0; j < 8; ++j) acc[i][j] = 0.f;

  const int kq = tid & 3;       // A staging: k-quad
  const int am = tid >> 2;      // A staging: row 0..63 (+64)
  const int bc = (tid & 31) * 4;// B staging: col
  const int br = tid >> 5;      // B staging: row 0..7 (+8)

  for (int k0 = 0; k0 < K; k0 += 16) {
    // ---- stage A (transposed into As[k][m]) ----
#pragma unroll
    for (int it = 0; it < 2; ++it) {
      int mr = am + it * 64;
      int row = m0 + mr;
      int kk = k0 + kq * 4;
      float v0, v1, v2, v3;
      if (aMode == 1) {
        const unsigned char* p = Au8 + (size_t)row * K + kk;
        uchar4 c4 = *(const uchar4*)p;
        v0 = ((float)c4.x - aZ) * aS; v1 = ((float)c4.y - aZ) * aS;
        v2 = ((float)c4.z - aZ) * aS; v3 = ((float)c4.w - aZ) * aS;
      } else if (aMode == 0) {
        const float* p = Af + (size_t)row * K + kk;
        if (kk + 3 < K) { float4 f = *(const float4*)p; v0 = f.x; v1 = f.y; v2 = f.z; v3 = f.w; }
        else {
          v0 = (kk     < K) ? p[0] : 0.f; v1 = (kk + 1 < K) ? p[1] : 0.f;
          v2 = (kk + 2 < K) ? p[2] : 0.f; v3 = (kk + 3 < K) ? p[3] : 0.f;
        }
      } else { // aMode 2: x[b][t][f], row = t*64+b
        int tt = row >> 6, bb = row & 63;
        const float* p = Af + ((size_t)bb * 1000 + tt) * 257 + kk;
        v0 = (kk     < K) ? fq_(p[0], aS, aZ) : 0.f;
        v1 = (kk + 1 < K) ? fq_(p[1], aS, aZ) : 0.f;
        v2 = (kk + 2 < K) ? fq_(p[2], aS, aZ) : 0.f;
        v3 = (kk + 3 < K) ? fq_(p[3], aS, aZ) : 0.f;
      }
      As[kq * 4 + 0][mr] = v0; As[kq * 4 + 1][mr] = v1;
      As[kq * 4 + 2][mr] = v2; As[kq * 4 + 3][mr] = v3;
    }
    // ---- stage B ----
#pragma unroll
    for (int it = 0; it < 2; ++it) {
      int rr = br + it * 8;
      int k = k0 + rr;
      int c = n0 + bc;
      float v0 = 0.f, v1 = 0.f, v2 = 0.f, v3 = 0.f;
      if (k < K) {
        const float* p = B + (size_t)k * N + c;
        if (((N & 3) == 0) && (c + 3 < N)) { float4 f = *(const float4*)p; v0 = f.x; v1 = f.y; v2 = f.z; v3 = f.w; }
        else {
          if (c     < N) v0 = p[0];
          if (c + 1 < N) v1 = p[1];
          if (c + 2 < N) v2 = p[2];
          if (c + 3 < N) v3 = p[3];
        }
      }
      float4 f4; f4.x = v0; f4.y = v1; f4.z = v2; f4.w = v3;
      *(float4*)&Bs[rr][bc] = f4;
    }
    __syncthreads();
#pragma unroll
    for (int kk = 0; kk < 16; ++kk) {
      float a_[8], b_[8];
      *(float4*)&a_[0] = *(const float4*)&As[kk][ty * 8];
      *(float4*)&a_[4] = *(const float4*)&As[kk][ty * 8 + 4];
      *(float4*)&b_[0] = *(const float4*)&Bs[kk][tx * 8];
      *(float4*)&b_[4] = *(const float4*)&Bs[kk][tx * 8 + 4];
#pragma unroll
      for (int i = 0; i < 8; ++i)
#pragma unroll
        for (int j = 0; j < 8; ++j) acc[i][j] = fmaf(a_[i], b_[j], acc[i][j]);
    }
    __syncthreads();
  }
  // ---- epilogue ----
#pragma unroll
  for (int i = 0; i < 8; ++i) {
    int row = m0 + ty * 8 + i;
#pragma unroll
    for (int j = 0; j < 8; ++j) {
      int col = n0 + tx * 8 + j;
      if (col >= N) continue;
      float v = acc[i][j];
      if (epMode == 0) {
        v = fq_(v, e1S, e1Z);
        v = v + bias[col];
        float q = rintf(v / e2S) + e2Z;
        q = fminf(fmaxf(q, 0.f), 255.f);
        outU8[(size_t)row * N + col] = (unsigned char)q;
      } else if (epMode == 2) {
        v += bias[col];
        v = fmaxf(v, 0.f);
        outF[(size_t)row * N + col] = v;
      } else {
        v += bias[col];
        v = sigm_(v);
        int rg = rowOff + row;
        int tt = rg >> 6, bb = rg & 63;
        outF[((size_t)bb * 1000 + tt) * 257 + col] = v;
      }
    }
  }
}

// ---------------- GRU recurrence ----------------
// 256 blocks = 64 batch rows x 4 column-slices (100 cols per gate each).
// Exact integer dot products on u8 codes; sibling blocks sync via a per-row
// monotonic device-scope counter; h codes double-buffered by step parity.
__global__ __launch_bounds__(320) void gru_rec(
    const unsigned char* __restrict__ WhC,   // [3][400][400] layout [g][j][k]
    const int* __restrict__ colsum,          // [3][400]
    const unsigned char* __restrict__ Aq, const unsigned char* __restrict__ Cq,
    const unsigned char* __restrict__ Eq,
    const float* __restrict__ bhr, const float* __restrict__ bhz, const float* __restrict__ bhn,
    unsigned char* __restrict__ hs, unsigned char* hbuf, unsigned int* cnt, RecP P)
{
  __shared__ __align__(16) unsigned int hqp[100]; // packed h codes (400 u8)
  __shared__ int psum[100];
  __shared__ float dots[3][100];
  __shared__ int HqS;

  const int tid = threadIdx.x;
  const int blk = blockIdx.x;
  const int b = blk & 63;           // batch row (siblings b, b+64, b+128, b+192 -> same XCD)
  const int sl = blk >> 6;          // column slice 0..3
  const int jbase = sl * 100;

  // per-thread loop-invariant constants for the dot threads
  int g = tid / 100;
  int jj = tid - g * 100;
  int j = jbase + jj;
  float sw = 0.f, s1S = 1.f, s1Z = 0.f, s2S = 1.f, s2Z = 0.f, biasj = 0.f, swsh = 0.f;
  int zwi = 0, CSj = 0;
  const unsigned char* wcol = WhC;
  if (tid < 300) {
    SZ w  = (g == 0) ? P.wr : (g == 1) ? P.wz : P.wn;
    SZ s1 = (g == 0) ? P.b1 : (g == 1) ? P.d1 : P.f1;
    SZ s2 = (g == 0) ? P.b2 : (g == 1) ? P.d2 : P.f2;
    sw = w.s; zwi = (int)w.z;
    s1S = s1.s; s1Z = s1.z; s2S = s2.s; s2Z = s2.z;
    biasj = ((g == 0) ? bhr : (g == 1) ? bhz : bhn)[j];
    CSj = colsum[g * 400 + j];
    wcol = WhC + ((size_t)(g * 400) + j) * 400;
    swsh = sw * P.rnn.s;
  }
  const int zhi = (int)P.rnn.z;

  for (int t = 0; t < 1000; ++t) {
    const int par = t & 1;
    unsigned char ca = 0, cc2 = 0, ce = 0;
    // Phase A: wait for siblings' h_t, stage codes to LDS; prefetch a/c/e
    if (tid < 100) {
      if (t > 0) {
        while (__hip_atomic_load(cnt + b, __ATOMIC_ACQUIRE, __HIP_MEMORY_SCOPE_AGENT) < (unsigned)(4 * t))
          __builtin_amdgcn_s_sleep(1);
      }
      const unsigned char* hrow = hbuf + ((size_t)par * 64 + b) * 400 + tid * 4;
      uchar4 h4 = *(const uchar4*)hrow;
      hqp[tid] = (unsigned)h4.x | ((unsigned)h4.y << 8) | ((unsigned)h4.z << 16) | ((unsigned)h4.w << 24);
      psum[tid] = (int)h4.x + (int)h4.y + (int)h4.z + (int)h4.w;
      size_t row = (size_t)t * 64 + b;
      int jc = jbase + tid;
      ca  = Aq[row * 400 + jc];
      cc2 = Cq[row * 400 + jc];
      ce  = Eq[row * 400 + jc];
    }
    __syncthreads();
    // reduce sum of h codes (wave 0)
    if (tid < 64) {
      int v = psum[tid] + ((tid < 36) ? psum[tid + 64] : 0);
      for (int off = 32; off; off >>= 1) v += __shfl_down(v, off, 64);
      if (tid == 0) HqS = v;
    }
    __syncthreads();
    // Phase B: exact-int dots h @ Wh{r,z,n} for this block's 100 columns/gate
    if (tid < 300) {
      unsigned acc = 0;
#pragma unroll 5
      for (int kk = 0; kk < 25; ++kk) {
        uint4 w = *(const uint4*)(wcol + kk * 16);
        uint4 h = *(const uint4*)&hqp[kk * 4];
        acc = udot4_(w.x, h.x, acc);
        acc = udot4_(w.y, h.y, acc);
        acc = udot4_(w.z, h.z, acc);
        acc = udot4_(w.w, h.w, acc);
      }
      int I = (int)acc - zwi * HqS - zhi * CSj + 400 * zhi * zwi;  // exact, |I| < 2^24
      float dot = (float)I * swsh;
      float v = fq_(dot, s1S, s1Z) + biasj;
      v = fq_(v, s2S, s2Z);
      dots[g][jj] = v;
    }
    __syncthreads();
    // Phase C: elementwise GRU update for this block's 100 h entries
    if (tid < 100) {
      int jc = jbase + tid;
      float a = ((float)ca  - P.a.z) * P.a.s;
      float c = ((float)cc2 - P.c.z) * P.c.s;
      float e = ((float)ce  - P.e.z) * P.e.s;
      float bb = dots[0][tid], dd = dots[1][tid], ff = dots[2][tid];
      float r  = fq_(sigm_(fq_(a + bb, P.r1.s, P.r1.z)), P.r2.s, P.r2.z);
      float zz = fq_(sigm_(fq_(c + dd, P.z1.s, P.z1.z)), P.z2.s, P.z2.z);
      float nn = fq_(tanhf(fq_(e + fq_(r * ff, P.n1.s, P.n1.z), P.n2.s, P.n2.z)), P.n3.s, P.n3.z);
      unsigned hq = (hqp[jc >> 2] >> ((jc & 3) * 8)) & 255u;
      float hold = ((float)hq - P.rnn.z) * P.rnn.s;
      float hn2v = fq_(fq_(1.f - zz, P.hn1.s, P.hn1.z) * nn, P.hn2.s, P.hn2.z);
      float hn3v = fq_(zz * hold, P.hn3.s, P.hn3.z);
      float hnew = hn2v + hn3v;
      float q = rintf(hnew / P.rnn.s) + P.rnn.z;
      q = fminf(fmaxf(q, 0.f), 255.f);
      unsigned char code = (unsigned char)q;
      hbuf[((size_t)(1 - par) * 64 + b) * 400 + jc] = code;
      hs[((size_t)t * 64 + b) * 400 + jc] = code;
      __threadfence();
    }
    __syncthreads();
    if (tid == 0) __hip_atomic_fetch_add(cnt + b, 1u, __ATOMIC_RELEASE, __HIP_MEMORY_SCOPE_AGENT);
  }
}

// ---------------- host launch ----------------
extern "C" void kernel_launch(void* const* d_in, const int* in_sizes, int n_in,
                              void* d_out, int out_size, void* d_ws, size_t ws_size,
                              hipStream_t stream)
{
  const float* x    = (const float*)d_in[0];
  const float* Wfc1 = (const float*)d_in[1];
  const float* bfc1 = (const float*)d_in[2];
  // dict order per setup_inputs: for L in (1,2): for g in (z,r,n): Wi, Wh, bi, bh
  const float* Wiz1 = (const float*)d_in[3];  const float* Whz1 = (const float*)d_in[4];
  const float* biz1 = (const float*)d_in[5];  const float* bhz1 = (const float*)d_in[6];
  const float* Wir1 = (const float*)d_in[7];  const float* Whr1 = (const float*)d_in[8];
  const float* bir1 = (const float*)d_in[9];  const float* bhr1 = (const float*)d_in[10];
  const float* Win1 = (const float*)d_in[11]; const float* Whn1 = (const float*)d_in[12];
  const float* bin1 = (const float*)d_in[13]; const float* bhn1 = (const float*)d_in[14];
  const float* Wiz2 = (const float*)d_in[15]; const float* Whz2 = (const float*)d_in[16];
  const float* biz2 = (const float*)d_in[17]; const float* bhz2 = (const float*)d_in[18];
  const float* Wir2 = (const float*)d_in[19]; const float* Whr2 = (const float*)d_in[20];
  const float* bir2 = (const float*)d_in[21]; const float* bhr2 = (const float*)d_in[22];
  const float* Win2 = (const float*)d_in[23]; const float* Whn2 = (const float*)d_in[24];
  const float* bin2 = (const float*)d_in[25]; const float* bhn2 = (const float*)d_in[26];
  const float* Wfc2 = (const float*)d_in[27]; const float* bfc2 = (const float*)d_in[28];
  const float* Wfc3 = (const float*)d_in[29]; const float* bfc3 = (const float*)d_in[30];
  const float* Wfc4 = (const float*)d_in[31]; const float* bfc4 = (const float*)d_in[32];
  float* out = (float*)d_out;

  // ---- workspace carve (total ~160 MB) ----
  char* wp = (char*)d_ws;
  auto alloc = [&](size_t bytes) -> void* {
    void* p = (void*)wp;
    wp += (bytes + 255) & ~(size_t)255;
    return p;
  };
  float* W1q = (float*)alloc(102800 * 4);
  float* Wiq = (float*)alloc(960000 * 4);   // [L][r,z,n][400*400]
  float* W2q = (float*)alloc(240000 * 4);
  float* W3q = (float*)alloc(360000 * 4);
  float* W4q = (float*)alloc(154200 * 4);
  float* b1q = (float*)alloc(400 * 4);
  float* biq = (float*)alloc(2400 * 4);     // [L][r,z,n][400]
  float* bhq = (float*)alloc(2400 * 4);
  float* b2q = (float*)alloc(600 * 4);
  float* b3q = (float*)alloc(600 * 4);
  float* b4q = (float*)alloc(257 * 4);
  unsigned char* WhC = (unsigned char*)alloc(960000);  // [L][r,z,n][j][k] codes
  int* colsum = (int*)alloc(2400 * 4);
  unsigned char* xsq = (unsigned char*)alloc(25600000);
  unsigned char* Aq  = (unsigned char*)alloc(25600000);
  unsigned char* Cq  = (unsigned char*)alloc(25600000);
  unsigned char* Eq  = (unsigned char*)alloc(25600000);
  unsigned char* hs1 = (unsigned char*)alloc(25600000);
  unsigned char* hs2 = (unsigned char*)alloc(25600000);
  unsigned char* hbuf = (unsigned char*)alloc(102400); // [L][2][64][400]
  unsigned int* cnt = (unsigned int*)alloc(512);       // [L][64]
  // f32 FC-chain chunk buffers overlay the dead A/C/E region (contiguous 76.8 MB)
  float* y2c = (float*)Aq;
  float* y3c = (float*)(Aq + 38400000);

  auto fqk = [&](const float* s, float* d, int n, SZ p) {
    kfq<<<dim3((n + 255) / 256), dim3(256), 0, stream>>>(s, d, n, p.s, p.z);
  };
  // ---- prep: fake-quantized weights/biases + recurrence weight codes ----
  fqk(Wfc1, W1q, 102800, ZW1);
  fqk(Wir1, Wiq + 0,      160000, ZWir1); fqk(Wiz1, Wiq + 160000, 160000, ZWiz1);
  fqk(Win1, Wiq + 320000, 160000, ZWin1);
  fqk(Wir2, Wiq + 480000, 160000, ZWir2); fqk(Wiz2, Wiq + 640000, 160000, ZWiz2);
  fqk(Win2, Wiq + 800000, 160000, ZWin2);
  fqk(Wfc2, W2q, 240000, ZWfc2); fqk(Wfc3, W3q, 360000, ZWfc3); fqk(Wfc4, W4q, 154200, ZWfc4);
  fqk(bfc1, b1q, 400, Zbfc1);
  fqk(bir1, biq + 0, 400, Zbir1);    fqk(biz1, biq + 400, 400, Zbiz1);  fqk(bin1, biq + 800, 400, Zbin1);
  fqk(bir2, biq + 1200, 400, Zbir2); fqk(biz2, biq + 1600, 400, Zbiz2); fqk(bin2, biq + 2000, 400, Zbin2);
  fqk(bhr1, bhq + 0, 400, Zbhr1);    fqk(bhz1, bhq + 400, 400, Zbhz1);  fqk(bhn1, bhq + 800, 400, Zbhn1);
  fqk(bhr2, bhq + 1200, 400, Zbhr2); fqk(bhz2, bhq + 1600, 400, Zbhz2); fqk(bhn2, bhq + 2000, 400, Zbhn2);
  fqk(bfc2, b2q, 600, Zbfc2); fqk(bfc3, b3q, 600, Zbfc3); fqk(bfc4, b4q, 257, Zbfc4);

  dim3 g625((160000 + 255) / 256);
  kwhc<<<g625, dim3(256), 0, stream>>>(Whr1, WhC + 0,      ZWhr1.s, ZWhr1.z);
  kwhc<<<g625, dim3(256), 0, stream>>>(Whz1, WhC + 160000, ZWhz1.s, ZWhz1.z);
  kwhc<<<g625, dim3(256), 0, stream>>>(Whn1, WhC + 320000, ZWhn1.s, ZWhn1.z);
  kwhc<<<g625, dim3(256), 0, stream>>>(Whr2, WhC + 480000, ZWhr2.s, ZWhr2.z);
  kwhc<<<g625, dim3(256), 0, stream>>>(Whz2, WhC + 640000, ZWhz2.s, ZWhz2.z);
  kwhc<<<g625, dim3(256), 0, stream>>>(Whn2, WhC + 800000, ZWhn2.s, ZWhn2.z);
  kcolsum<<<dim3(10), dim3(256), 0, stream>>>(WhC, colsum);
  int code0 = (int)(Zrnn.z < 0.f ? 0.f : (Zrnn.z > 255.f ? 255.f : Zrnn.z)); // fq(0,'hL') == 0 on rnn grid
  kinit<<<dim3(100), dim3(256), 0, stream>>>(hbuf, cnt, code0);

  auto gemm = [&](const float* Af, const unsigned char* Au8, const float* B, const float* bias,
                  float* outF, unsigned char* outU8, int M, int N, int K,
                  int aMode, int epMode, int rowOff, SZ aSZ, SZ e1, SZ e2) {
    dim3 grid(M / 128, (N + 127) / 128);
    gemm_k<<<grid, dim3(256), 0, stream>>>(Af, Au8, B, bias, outF, outU8,
                                           M, N, K, aMode, epMode, rowOff,
                                           aSZ.s, aSZ.z, e1.s, e1.z, e2.s, e2.z);
  };

  // ---- FC1: xs codes [T*64+b][400] ----
  gemm(x, nullptr, W1q, b1q, nullptr, xsq, 64000, 400, 257, 2, 0, 0, Zx, Zfc1mm, Zfc1add);

  // ---- GRU layer 1 input projections -> A/C/E codes ----
  gemm(nullptr, xsq, Wiq + 0,      biq + 0,   nullptr, Aq, 64000, 400, 400, 1, 0, 0, Zfc1add, Za_1, Za1);
  gemm(nullptr, xsq, Wiq + 160000, biq + 400, nullptr, Cq, 64000, 400, 400, 1, 0, 0, Zfc1add, Zc_1, Zc1);
  gemm(nullptr, xsq, Wiq + 320000, biq + 800, nullptr, Eq, 64000, 400, 400, 1, 0, 0, Zfc1add, Ze_1, Ze1);
  // ---- GRU layer 1 recurrence ----
  gru_rec<<<dim3(256), dim3(320), 0, stream>>>(WhC, colsum, Aq, Cq, Eq,
                                               bhq + 0, bhq + 400, bhq + 800,
                                               hs1, hbuf, cnt, PL1);
  // ---- GRU layer 2 input projections (from hs1 codes) ----
  gemm(nullptr, hs1, Wiq + 480000, biq + 1200, nullptr, Aq, 64000, 400, 400, 1, 0, 0, Zrnn, Za_2, Za2);
  gemm(nullptr, hs1, Wiq + 640000, biq + 1600, nullptr, Cq, 64000, 400, 400, 1, 0, 0, Zrnn, Zc_2, Zc2);
  gemm(nullptr, hs1, Wiq + 800000, biq + 2000, nullptr, Eq, 64000, 400, 400, 1, 0, 0, Zrnn, Ze_2, Ze1);
  // ---- GRU layer 2 recurrence ----
  gru_rec<<<dim3(256), dim3(320), 0, stream>>>(WhC + 480000, colsum + 1200, Aq, Cq, Eq,
                                               bhq + 1200, bhq + 1600, bhq + 2000,
                                               hs2, hbuf + 51200, cnt + 64, PL2);
  // ---- FC2 -> FC3 -> FC4 in 4 row chunks (activations overlay dead A/C/E region) ----
  for (int rc = 0; rc < 4; ++rc) {
    const unsigned char* a2 = hs2 + (size_t)rc * 16000 * 400;
    gemm(nullptr, a2, W2q, b2q, y2c, nullptr, 16000, 600, 400, 1, 2, 0, Zrnn, Zrnn, Zrnn);
    gemm(y2c, nullptr, W3q, b3q, y3c, nullptr, 16000, 600, 600, 0, 2, 0, Zrnn, Zrnn, Zrnn);
    gemm(y3c, nullptr, W4q, b4q, out, nullptr, 16000, 257, 600, 0, 3, rc * 16000, Zrnn, Zrnn, Zrnn);
  }
  (void)in_sizes; (void)n_in; (void)out_size; (void)ws_size;
}

// Round 2
// 10499.578 us; speedup vs baseline: 4.8549x; 4.8549x over previous
//
#include <hip/hip_runtime.h>
#include <math.h>

#define DEV static __device__ __forceinline__

// ---------------- calibration (s, z) constants, computed like the reference ----------------
struct SZ { float s, z; };

constexpr double cfloor_(double v){ long long i=(long long)v; return ((double)i > v) ? (double)(i-1) : (double)i; }
constexpr double cround_(double v){            // round half-to-even (Python round / nearbyint)
  double fl = cfloor_(v); double fr = v - fl;
  return (fr > 0.5) ? fl + 1.0 : (fr < 0.5 ? fl : ((((long long)fl) & 1LL) == 0 ? fl : fl + 1.0));
}
constexpr SZ mksz(double mn, double mx){
  double s = (mx - mn) / 255.0;
  double z = cround_(-mn / s);
  return SZ{ (float)s, (float)z };
}

constexpr SZ Zx     = mksz(-0.0025095, 0.0022181);
constexpr SZ ZW1    = mksz(-0.22075387835502625, 0.208940327167511);
constexpr SZ Zfc1mm = mksz(-0.00291599917, 0.0017367251);
constexpr SZ Zbfc1  = mksz(-0.48688140511512756, 0.5176185369491577);
constexpr SZ Zfc1add= mksz(-0.48778465390205383, 0.5181604027748108);
// layer-1 weights/biases
constexpr SZ ZWiz1 = mksz(-0.43284985423088074, 0.46175122261047363);
constexpr SZ ZWir1 = mksz(-0.34401071071624756, 0.29191476106643677);
constexpr SZ ZWin1 = mksz(-0.3236880302429199, 0.39607325196266174);
constexpr SZ ZWhz1 = mksz(-1.8417714834213257, 1.7173254489898682);
constexpr SZ ZWhr1 = mksz(-1.1574513912200928, 1.0300449132919312);
constexpr SZ ZWhn1 = mksz(-0.7756922245025635, 0.9530389308929443);
constexpr SZ Zbiz1 = mksz(-0.5063393712043762, 0.36664387583732605);
constexpr SZ Zbir1 = mksz(-0.07920225709676743, 0.20611026883125305);
constexpr SZ Zbin1 = mksz(-0.5539973378181458, 0.17938342690467834);
constexpr SZ Zbhz1 = mksz(-0.5337516665458679, 0.4148772358894348);
constexpr SZ Zbhr1 = mksz(-0.07688436657190323, 0.14814253151416779);
constexpr SZ Zbhn1 = mksz(-0.7828555107116699, 0.9008108973503113);
// layer-2 weights/biases
constexpr SZ ZWiz2 = mksz(-0.9102030992507935, 0.9408696889877319);
constexpr SZ ZWir2 = mksz(-0.9560997486114502, 0.6683358550071716);
constexpr SZ ZWin2 = mksz(-0.4721935987472534, 0.48561596870422363);
constexpr SZ ZWhz2 = mksz(-1.2992678880691528, 1.2991048097610474);
constexpr SZ ZWhr2 = mksz(-0.8318714499473572, 1.1085889339447021);
constexpr SZ ZWhn2 = mksz(-0.955470085144043, 1.046797513961792);
constexpr SZ Zbiz2 = mksz(-0.44805487990379333, 0.1560053527355194);
constexpr SZ Zbir2 = mksz(-0.08767592161893845, 0.11347303539514542);
constexpr SZ Zbin2 = mksz(-0.239909827709198, 0.12033259868621826);
constexpr SZ Zbhz2 = mksz(-0.43745461106300354, 0.12699371576309204);
constexpr SZ Zbhr2 = mksz(-0.09617264568805695, 0.07690174877643585);
constexpr SZ Zbhn2 = mksz(-0.17204178869724274, 0.19739042222499847);
// fc tail
constexpr SZ ZWfc2 = mksz(-1.3657219409942627, 1.158295750617981);
constexpr SZ Zbfc2 = mksz(-0.1750922054052353, 0.1385071724653244);
constexpr SZ ZWfc3 = mksz(-3.1666038036346436, 2.5026357173919678);
constexpr SZ Zbfc3 = mksz(-0.10188056528568268, 0.0899151861667633);
constexpr SZ ZWfc4 = mksz(-1.300571084022522, 1.928941249847412);
constexpr SZ Zbfc4 = mksz(-0.10699586570262909, 0.04597663879394531);
// gru1 stages
constexpr SZ Za_1 = mksz(-0.6389939785003662, 0.7715625762939453);
constexpr SZ Za1  = mksz(-0.6046768426895142, 0.8871182203292847);
constexpr SZ Zb_1 = mksz(-0.004922409541904926, 0.004103424027562141);
constexpr SZ Zb1  = mksz(-0.07475128024816513, 0.14630259573459625);
constexpr SZ Zc_1 = mksz(-1.5660111904144287, 1.0454494953155518);
constexpr SZ Zc1  = mksz(-1.9779117107391357, 1.3700535297393799);
constexpr SZ Zd_1 = mksz(-0.008429044857621193, 0.006403823848813772);
constexpr SZ Zd1  = mksz(-0.5529640316963196, 0.41507571935653687);
constexpr SZ Ze_1 = mksz(-1.3637111186981201, 1.018247127532959);
constexpr SZ Ze1  = mksz(-1.8583884239196777, 1.1587692499160767);
constexpr SZ Zf_1 = mksz(-0.005411399528384209, 0.0061536869034171104);
constexpr SZ Zf1  = mksz(-0.7833794355392456, 0.8978855013847351);
constexpr SZ Zr_1 = mksz(-0.6226556301116943, 0.9800534844398499);
constexpr SZ Zr1  = mksz(0.3491777181625366, 0.7271188497543335);
constexpr SZ Zz_1 = mksz(-2.392332077026367, 1.7851293087005615);
constexpr SZ Zz1  = mksz(0.08375928550958633, 0.856329083442688);
constexpr SZ Zn11 = mksz(-0.5516456365585327, 0.4556601643562317);
constexpr SZ Zn21 = mksz(-2.4100341796875, 1.1423156261444092);
constexpr SZ Zn1  = mksz(-0.983996570110321, 0.8151924014091492);
constexpr SZ Zhn11= mksz(0.143670916557312, 0.9162406921386719);
constexpr SZ Zhn21= mksz(-0.9015777111053467, 0.45391541719436646);
constexpr SZ Zhn31= mksz(-0.0016954239690676332, 0.0016671211924403906);
constexpr SZ Zrnn = mksz(-0.9016271829605103, 0.4546271562576294);
// gru2 explicit entries (the rest fall back to gru1 values, incl. rnn2GRU)
constexpr SZ Za_2 = mksz(-0.681461751461029, 0.9113116264343262);
constexpr SZ Za2  = mksz(-0.7149235010147095, 0.908741295337677);
constexpr SZ Zb_2 = mksz(-0.005148397758603096, 0.011014967225492);
constexpr SZ Zb2g = mksz(-0.09436552226543427, 0.07623167335987091);
constexpr SZ Zc_2 = mksz(-1.2279887199401855, 1.1102137565612793);
constexpr SZ Zc2  = mksz(-1.6760436296463013, 1.200895071029663);
constexpr SZ Zd_2 = mksz(-0.008141756057739258, 0.00894666276872158);
constexpr SZ Zd2  = mksz(-0.43875735998153687, 0.1262134611606598);
constexpr SZ Ze_2 = mksz(-0.6732944250106812, 0.6314664483070374);

struct RecP {
  SZ wr, wz, wn;                 // Wh scale/zero for gates r,z,n
  SZ a, c, e;                    // code grids of A/C/E
  SZ b1, b2, d1, d2, f1, f2;     // b_,b,d_,d,f_,f
  SZ r1, r2, z1, z2;             // r_,r,z_,z
  SZ n1, n2, n3;                 // n1,n2,n
  SZ hn1, hn2, hn3, rnn;
};
constexpr RecP PL1 = { ZWhr1, ZWhz1, ZWhn1, Za1, Zc1, Ze1, Zb_1, Zb1, Zd_1, Zd1, Zf_1, Zf1,
                       Zr_1, Zr1, Zz_1, Zz1, Zn11, Zn21, Zn1, Zhn11, Zhn21, Zhn31, Zrnn };
constexpr RecP PL2 = { ZWhr2, ZWhz2, ZWhn2, Za2, Zc2, Ze1, Zb_2, Zb2g, Zd_2, Zd2, Zf_1, Zf1,
                       Zr_1, Zr1, Zz_1, Zz1, Zn11, Zn21, Zn1, Zhn11, Zhn21, Zhn31, Zrnn };

// ---------------- device helpers ----------------
DEV float fq_(float x, float s, float z){
  float q = rintf(x / s) + z;                 // jnp.round = half-even = rintf
  q = fminf(fmaxf(q, 0.f), 255.f);
  return (q - z) * s;
}
DEV float sigm_(float v){ return 1.f / (1.f + expf(-v)); }

DEV unsigned udot4_(unsigned a, unsigned b, unsigned c){
#if defined(__has_builtin) && __has_builtin(__builtin_amdgcn_udot4)
  return __builtin_amdgcn_udot4(a, b, c, false);
#else
  return c + (a & 255u) * (b & 255u) + ((a >> 8) & 255u) * ((b >> 8) & 255u)
           + ((a >> 16) & 255u) * ((b >> 16) & 255u) + (a >> 24) * (b >> 24);
#endif
}

// ---------------- prep kernels ----------------
__global__ __launch_bounds__(256) void kfq(const float* __restrict__ src, float* __restrict__ dst,
                                           int n, float s, float z){
  int i = blockIdx.x * 256 + threadIdx.x;
  if (i < n) dst[i] = fq_(src[i], s, z);
}
// Wh [400][400] (k-major) -> u8 codes, column-major [j][k]
__global__ __launch_bounds__(256) void kwhc(const float* __restrict__ W, unsigned char* __restrict__ dst,
                                            float s, float z){
  int i = blockIdx.x * 256 + threadIdx.x;
  if (i < 160000) {
    int j = i / 400, k = i - j * 400;
    float q = rintf(W[k * 400 + j] / s) + z;
    q = fminf(fmaxf(q, 0.f), 255.f);
    dst[i] = (unsigned char)q;
  }
}
__global__ __launch_bounds__(256) void kcolsum(const unsigned char* __restrict__ WhC, int* __restrict__ cs){
  int i = blockIdx.x * 256 + threadIdx.x;
  if (i < 2400) {
    const unsigned char* p = WhC + (size_t)i * 400;
    int s = 0;
    for (int k = 0; k < 400; ++k) s += p[k];
    cs[i] = s;
  }
}
// init tag-0 slot of both h-publish rings with h0 codes (tag in hi-32 = 0)
__global__ __launch_bounds__(256) void kinit(unsigned long long* __restrict__ hp1,
                                             unsigned long long* __restrict__ hp2, unsigned code){
  int i = blockIdx.x * 256 + threadIdx.x;
  if (i < 6400) {
    unsigned long long w = (unsigned long long)(code * 0x01010101u); // tag 0 in hi-32
    hp1[i] = w; hp2[i] = w;
  }
}

// ---------------- tiled f32 GEMM with fused fq epilogues ----------------
// BM=BN=128, BK=16, 256 threads, 8x8 microtile. M must be a multiple of 128.
// aMode: 0 = f32 plain, 1 = u8 codes dequant (K%16==0), 2 = x [B,T,F] permuted + fq('x')
// epMode: 0 = fq(e1) + bias -> fq-code(e2) u8 ; 2 = +bias, relu -> f32 ; 3 = +bias, sigmoid -> f32 permuted [B,T,F]
__global__ __launch_bounds__(256) void gemm_k(
    const float* __restrict__ Af, const unsigned char* __restrict__ Au8,
    const float* __restrict__ B, const float* __restrict__ bias,
    float* __restrict__ outF, unsigned char* __restrict__ outU8,
    int M, int N, int K, int aMode, int epMode, int rowOff,
    float aS, float aZ, float e1S, float e1Z, float e2S, float e2Z)
{
  __shared__ __align__(16) float As[16][132];
  __shared__ __align__(16) float Bs[16][132];
  const int tid = threadIdx.x;
  const int m0 = blockIdx.x * 128;
  const int n0 = blockIdx.y * 128;
  const int tx = tid & 15, ty = tid >> 4;
  float acc[8][8];
#pragma unroll
  for (int i = 0; i < 8; ++i)
#pragma unroll
    for (int j = 0; j < 8; ++j) acc[i][j] = 0.f;

  const int kq = tid & 3;       // A staging: k-quad
  const int am = tid >> 2;      // A staging: row 0..63 (+64)
  const int bc = (tid & 31) * 4;// B staging: col
  const int br = tid >> 5;      // B staging: row 0..7 (+8)

  for (int k0 = 0; k0 < K; k0 += 16) {
    // ---- stage A (transposed into As[k][m]) ----
#pragma unroll
    for (int it = 0; it < 2; ++it) {
      int mr = am + it * 64;
      int row = m0 + mr;
      int kk = k0 + kq * 4;
      float v0, v1, v2, v3;
      if (aMode == 1) {
        const unsigned char* p = Au8 + (size_t)row * K + kk;
        uchar4 c4 = *(const uchar4*)p;
        v0 = ((float)c4.x - aZ) * aS; v1 = ((float)c4.y - aZ) * aS;
        v2 = ((float)c4.z - aZ) * aS; v3 = ((float)c4.w - aZ) * aS;
      } else if (aMode == 0) {
        const float* p = Af + (size_t)row * K + kk;
        if (kk + 3 < K) { float4 f = *(const float4*)p; v0 = f.x; v1 = f.y; v2 = f.z; v3 = f.w; }
        else {
          v0 = (kk     < K) ? p[0] : 0.f; v1 = (kk + 1 < K) ? p[1] : 0.f;
          v2 = (kk + 2 < K) ? p[2] : 0.f; v3 = (kk + 3 < K) ? p[3] : 0.f;
        }
      } else { // aMode 2: x[b][t][f], row = t*64+b
        int tt = row >> 6, bb = row & 63;
        const float* p = Af + ((size_t)bb * 1000 + tt) * 257 + kk;
        v0 = (kk     < K) ? fq_(p[0], aS, aZ) : 0.f;
        v1 = (kk + 1 < K) ? fq_(p[1], aS, aZ) : 0.f;
        v2 = (kk + 2 < K) ? fq_(p[2], aS, aZ) : 0.f;
        v3 = (kk + 3 < K) ? fq_(p[3], aS, aZ) : 0.f;
      }
      As[kq * 4 + 0][mr] = v0; As[kq * 4 + 1][mr] = v1;
      As[kq * 4 + 2][mr] = v2; As[kq * 4 + 3][mr] = v3;
    }
    // ---- stage B ----
#pragma unroll
    for (int it = 0; it < 2; ++it) {
      int rr = br + it * 8;
      int k = k0 + rr;
      int c = n0 + bc;
      float v0 = 0.f, v1 = 0.f, v2 = 0.f, v3 = 0.f;
      if (k < K) {
        const float* p = B + (size_t)k * N + c;
        if (((N & 3) == 0) && (c + 3 < N)) { float4 f = *(const float4*)p; v0 = f.x; v1 = f.y; v2 = f.z; v3 = f.w; }
        else {
          if (c     < N) v0 = p[0];
          if (c + 1 < N) v1 = p[1];
          if (c + 2 < N) v2 = p[2];
          if (c + 3 < N) v3 = p[3];
        }
      }
      float4 f4; f4.x = v0; f4.y = v1; f4.z = v2; f4.w = v3;
      *(float4*)&Bs[rr][bc] = f4;
    }
    __syncthreads();
#pragma unroll
    for (int kk = 0; kk < 16; ++kk) {
      float a_[8], b_[8];
      *(float4*)&a_[0] = *(const float4*)&As[kk][ty * 8];
      *(float4*)&a_[4] = *(const float4*)&As[kk][ty * 8 + 4];
      *(float4*)&b_[0] = *(const float4*)&Bs[kk][tx * 8];
      *(float4*)&b_[4] = *(const float4*)&Bs[kk][tx * 8 + 4];
#pragma unroll
      for (int i = 0; i < 8; ++i)
#pragma unroll
        for (int j = 0; j < 8; ++j) acc[i][j] = fmaf(a_[i], b_[j], acc[i][j]);
    }
    __syncthreads();
  }
  // ---- epilogue ----
#pragma unroll
  for (int i = 0; i < 8; ++i) {
    int row = m0 + ty * 8 + i;
#pragma unroll
    for (int j = 0; j < 8; ++j) {
      int col = n0 + tx * 8 + j;
      if (col >= N) continue;
      float v = acc[i][j];
      if (epMode == 0) {
        v = fq_(v, e1S, e1Z);
        v = v + bias[col];
        float q = rintf(v / e2S) + e2Z;
        q = fminf(fmaxf(q, 0.f), 255.f);
        outU8[(size_t)row * N + col] = (unsigned char)q;
      } else if (epMode == 2) {
        v += bias[col];
        v = fmaxf(v, 0.f);
        outF[(size_t)row * N + col] = v;
      } else {
        v += bias[col];
        v = sigm_(v);
        int rg = rowOff + row;
        int tt = rg >> 6, bb = rg & 63;
        outF[((size_t)bb * 1000 + tt) * 257 + col] = v;
      }
    }
  }
}

// ---------------- GRU recurrence (LDS-resident weights, fence-free tagged sync) ----------------
// 256 blocks = 64 batch rows x 4 column-slices (100 cols per gate each); 1 block/CU
// (LDS-limited) so all 256 are co-resident. Weights live in LDS (117 KiB/block,
// XOR-swizzled 512B column stride -> conflict-free b128 reads). h codes are
// exchanged via self-validating u64 words [tag32|4xu8] with RELAXED agent-scope
// atomics into a depth-4 ring: no fences, no buffer_wbl2/buffer_inv, L2 stays warm.
__global__ __launch_bounds__(320) void gru_rec(
    const unsigned char* __restrict__ WhC,   // [3][400][400] layout [g][j][k] (this layer)
    const int* __restrict__ colsum,          // [3][400]
    const unsigned char* __restrict__ Aq, const unsigned char* __restrict__ Cq,
    const unsigned char* __restrict__ Eq,
    const float* __restrict__ bhr, const float* __restrict__ bhz, const float* __restrict__ bhn,
    unsigned char* __restrict__ hs,
    unsigned long long* hpub,                // [4][64][100] u64 ring
    RecP P)
{
  __shared__ __align__(16) uint4 Wlds[9600];        // 300 cols * 32 chunks (153.6 KB)
  __shared__ __align__(16) unsigned int hqp[100];   // 400 h codes
  __shared__ float dots[3][100];

  const int tid = threadIdx.x;
  const int b = blockIdx.x & 63;    // batch row
  const int sl = blockIdx.x >> 6;   // column slice 0..3
  const int jbase = sl * 100;

  // ---- one-time: stage this block's weight columns into LDS (swizzled) ----
  for (int idx = tid; idx < 7500; idx += 320) {
    int cid = idx / 25;             // 0..299 = g*100 + jj
    int kk  = idx - cid * 25;       // 0..24 (16B chunk)
    int g = cid / 100, jj = cid - g * 100;
    const uint4* src = (const uint4*)(WhC + ((size_t)(g * 400) + jbase + jj) * 400) + kk;
    Wlds[cid * 32 + (kk ^ (cid & 31))] = *src;
  }

  // per-thread loop-invariant constants for the dot threads
  const int cid = tid;                     // dot thread id = g*100+jj
  int g = cid / 100;
  int jj = cid - g * 100;
  float s1S = 1.f, s1Z = 0.f, s2S = 1.f, s2Z = 0.f, biasj = 0.f, swsh = 0.f;
  int zwi = 0, CSj = 0;
  if (tid < 300) {
    int j = jbase + jj;
    SZ w  = (g == 0) ? P.wr : (g == 1) ? P.wz : P.wn;
    SZ s1 = (g == 0) ? P.b1 : (g == 1) ? P.d1 : P.f1;
    SZ s2 = (g == 0) ? P.b2 : (g == 1) ? P.d2 : P.f2;
    zwi = (int)w.z;
    s1S = s1.s; s1Z = s1.z; s2S = s2.s; s2Z = s2.z;
    biasj = ((g == 0) ? bhr : (g == 1) ? bhz : bhn)[j];
    CSj = colsum[g * 400 + j];
    swsh = w.s * P.rnn.s;
  }
  const int zhi = (int)P.rnn.z;
  const int swm = cid & 31;                // this column's XOR swizzle mask
  __syncthreads();

  for (int t = 0; t < 1000; ++t) {
    // ---- Phase A: load a/c/e codes; poll siblings' tagged h words ----
    unsigned char ca = 0, cc2 = 0, ce = 0;
    if (tid < 100) {
      size_t row = (size_t)t * 64 + b;
      int jc = jbase + tid;
      ca  = Aq[row * 400 + jc];
      cc2 = Cq[row * 400 + jc];
      ce  = Eq[row * 400 + jc];
      const unsigned long long* p = hpub + ((size_t)(t & 3) * 64 + b) * 100 + tid;
      unsigned long long w64;
      while ((unsigned)((w64 = __hip_atomic_load(p, __ATOMIC_RELAXED, __HIP_MEMORY_SCOPE_AGENT)) >> 32)
             != (unsigned)t)
        __builtin_amdgcn_s_sleep(1);
      hqp[tid] = (unsigned)w64;
    }
    __syncthreads();
    // ---- Phase B: exact-int dots h @ Wh{r,z,n} from LDS ----
    if (tid < 300) {
      unsigned acc = 0, hsum = 0;
      const uint4* wb = &Wlds[cid * 32];
#pragma unroll 5
      for (int kk = 0; kk < 25; ++kk) {
        uint4 h = *(const uint4*)&hqp[kk * 4];
        uint4 w = wb[kk ^ swm];
        acc = udot4_(w.x, h.x, acc);  hsum = udot4_(0x01010101u, h.x, hsum);
        acc = udot4_(w.y, h.y, acc);  hsum = udot4_(0x01010101u, h.y, hsum);
        acc = udot4_(w.z, h.z, acc);  hsum = udot4_(0x01010101u, h.z, hsum);
        acc = udot4_(w.w, h.w, acc);  hsum = udot4_(0x01010101u, h.w, hsum);
      }
      int I = (int)acc - zwi * (int)hsum - zhi * CSj + 400 * zhi * zwi;  // exact, |I| < 2^24
      float dot = (float)I * swsh;
      float v = fq_(dot, s1S, s1Z) + biasj;
      v = fq_(v, s2S, s2Z);
      dots[g][jj] = v;
    }
    __syncthreads();
    // ---- Phase C: elementwise GRU update + tagged publish ----
    if (tid < 128) {                 // waves 0,1 fully active so shfl sources are valid
      int m = (tid < 100) ? tid : 99;
      int jc = jbase + m;
      float a = ((float)ca  - P.a.z) * P.a.s;
      float c = ((float)cc2 - P.c.z) * P.c.s;
      float e = ((float)ce  - P.e.z) * P.e.s;
      float bb = dots[0][m], dd = dots[1][m], ff = dots[2][m];
      float r  = fq_(sigm_(fq_(a + bb, P.r1.s, P.r1.z)), P.r2.s, P.r2.z);
      float zz = fq_(sigm_(fq_(c + dd, P.z1.s, P.z1.z)), P.z2.s, P.z2.z);
      float nn = fq_(tanhf(fq_(e + fq_(r * ff, P.n1.s, P.n1.z), P.n2.s, P.n2.z)), P.n3.s, P.n3.z);
      unsigned hq = (hqp[jc >> 2] >> ((jc & 3) * 8)) & 255u;
      float hold = ((float)hq - P.rnn.z) * P.rnn.s;
      float hn2v = fq_(fq_(1.f - zz, P.hn1.s, P.hn1.z) * nn, P.hn2.s, P.hn2.z);
      float hn3v = fq_(zz * hold, P.hn3.s, P.hn3.z);
      float hnew = hn2v + hn3v;
      float q = rintf(hnew / P.rnn.s) + P.rnn.z;
      q = fminf(fmaxf(q, 0.f), 255.f);
      unsigned code = (unsigned)q;
      // pack 4 codes/word via intra-wave shuffles (4 | 64, so sources stay in-wave)
      unsigned c1 = __shfl_down(code, 1);
      unsigned c2 = __shfl_down(code, 2);
      unsigned c3 = __shfl_down(code, 3);
      if (tid < 100) {
        hs[((size_t)t * 64 + b) * 400 + jc] = (unsigned char)code;
        if ((tid & 3) == 0) {
          unsigned packed = code | (c1 << 8) | (c2 << 16) | (c3 << 24);
          unsigned long long out64 = ((unsigned long long)(unsigned)(t + 1) << 32) | packed;
          unsigned long long* dst = hpub + ((size_t)((t + 1) & 3) * 64 + b) * 100 + sl * 25 + (tid >> 2);
          __hip_atomic_store(dst, out64, __ATOMIC_RELAXED, __HIP_MEMORY_SCOPE_AGENT);
        }
      }
    }
    __syncthreads();
  }
}

// ---------------- host launch ----------------
extern "C" void kernel_launch(void* const* d_in, const int* in_sizes, int n_in,
                              void* d_out, int out_size, void* d_ws, size_t ws_size,
                              hipStream_t stream)
{
  const float* x    = (const float*)d_in[0];
  const float* Wfc1 = (const float*)d_in[1];
  const float* bfc1 = (const float*)d_in[2];
  // dict order per setup_inputs: for L in (1,2): for g in (z,r,n): Wi, Wh, bi, bh
  const float* Wiz1 = (const float*)d_in[3];  const float* Whz1 = (const float*)d_in[4];
  const float* biz1 = (const float*)d_in[5];  const float* bhz1 = (const float*)d_in[6];
  const float* Wir1 = (const float*)d_in[7];  const float* Whr1 = (const float*)d_in[8];
  const float* bir1 = (const float*)d_in[9];  const float* bhr1 = (const float*)d_in[10];
  const float* Win1 = (const float*)d_in[11]; const float* Whn1 = (const float*)d_in[12];
  const float* bin1 = (const float*)d_in[13]; const float* bhn1 = (const float*)d_in[14];
  const float* Wiz2 = (const float*)d_in[15]; const float* Whz2 = (const float*)d_in[16];
  const float* biz2 = (const float*)d_in[17]; const float* bhz2 = (const float*)d_in[18];
  const float* Wir2 = (const float*)d_in[19]; const float* Whr2 = (const float*)d_in[20];
  const float* bir2 = (const float*)d_in[21]; const float* bhr2 = (const float*)d_in[22];
  const float* Win2 = (const float*)d_in[23]; const float* Whn2 = (const float*)d_in[24];
  const float* bin2 = (const float*)d_in[25]; const float* bhn2 = (const float*)d_in[26];
  const float* Wfc2 = (const float*)d_in[27]; const float* bfc2 = (const float*)d_in[28];
  const float* Wfc3 = (const float*)d_in[29]; const float* bfc3 = (const float*)d_in[30];
  const float* Wfc4 = (const float*)d_in[31]; const float* bfc4 = (const float*)d_in[32];
  float* out = (float*)d_out;

  // ---- workspace carve (total ~160 MB) ----
  char* wp = (char*)d_ws;
  auto alloc = [&](size_t bytes) -> void* {
    void* p = (void*)wp;
    wp += (bytes + 255) & ~(size_t)255;
    return p;
  };
  float* W1q = (float*)alloc(102800 * 4);
  float* Wiq = (float*)alloc(960000 * 4);   // [L][r,z,n][400*400]
  float* W2q = (float*)alloc(240000 * 4);
  float* W3q = (float*)alloc(360000 * 4);
  float* W4q = (float*)alloc(154200 * 4);
  float* b1q = (float*)alloc(400 * 4);
  float* biq = (float*)alloc(2400 * 4);     // [L][r,z,n][400]
  float* bhq = (float*)alloc(2400 * 4);
  float* b2q = (float*)alloc(600 * 4);
  float* b3q = (float*)alloc(600 * 4);
  float* b4q = (float*)alloc(257 * 4);
  unsigned char* WhC = (unsigned char*)alloc(960000);  // [L][r,z,n][j][k] codes
  int* colsum = (int*)alloc(2400 * 4);
  unsigned char* xsq = (unsigned char*)alloc(25600000);
  unsigned char* Aq  = (unsigned char*)alloc(25600000);
  unsigned char* Cq  = (unsigned char*)alloc(25600000);
  unsigned char* Eq  = (unsigned char*)alloc(25600000);
  unsigned char* hs1 = (unsigned char*)alloc(25600000);
  unsigned char* hs2 = (unsigned char*)alloc(25600000);
  unsigned long long* hpub1 = (unsigned long long*)alloc(4 * 64 * 100 * 8); // depth-4 ring
  unsigned long long* hpub2 = (unsigned long long*)alloc(4 * 64 * 100 * 8);
  // f32 FC-chain chunk buffers overlay the dead A/C/E region (contiguous 76.8 MB)
  float* y2c = (float*)Aq;
  float* y3c = (float*)(Aq + 38400000);

  auto fqk = [&](const float* s, float* d, int n, SZ p) {
    kfq<<<dim3((n + 255) / 256), dim3(256), 0, stream>>>(s, d, n, p.s, p.z);
  };
  // ---- prep: fake-quantized weights/biases + recurrence weight codes ----
  fqk(Wfc1, W1q, 102800, ZW1);
  fqk(Wir1, Wiq + 0,      160000, ZWir1); fqk(Wiz1, Wiq + 160000, 160000, ZWiz1);
  fqk(Win1, Wiq + 320000, 160000, ZWin1);
  fqk(Wir2, Wiq + 480000, 160000, ZWir2); fqk(Wiz2, Wiq + 640000, 160000, ZWiz2);
  fqk(Win2, Wiq + 800000, 160000, ZWin2);
  fqk(Wfc2, W2q, 240000, ZWfc2); fqk(Wfc3, W3q, 360000, ZWfc3); fqk(Wfc4, W4q, 154200, ZWfc4);
  fqk(bfc1, b1q, 400, Zbfc1);
  fqk(bir1, biq + 0, 400, Zbir1);    fqk(biz1, biq + 400, 400, Zbiz1);  fqk(bin1, biq + 800, 400, Zbin1);
  fqk(bir2, biq + 1200, 400, Zbir2); fqk(biz2, biq + 1600, 400, Zbiz2); fqk(bin2, biq + 2000, 400, Zbin2);
  fqk(bhr1, bhq + 0, 400, Zbhr1);    fqk(bhz1, bhq + 400, 400, Zbhz1);  fqk(bhn1, bhq + 800, 400, Zbhn1);
  fqk(bhr2, bhq + 1200, 400, Zbhr2); fqk(bhz2, bhq + 1600, 400, Zbhz2); fqk(bhn2, bhq + 2000, 400, Zbhn2);
  fqk(bfc2, b2q, 600, Zbfc2); fqk(bfc3, b3q, 600, Zbfc3); fqk(bfc4, b4q, 257, Zbfc4);

  dim3 g625((160000 + 255) / 256);
  kwhc<<<g625, dim3(256), 0, stream>>>(Whr1, WhC + 0,      ZWhr1.s, ZWhr1.z);
  kwhc<<<g625, dim3(256), 0, stream>>>(Whz1, WhC + 160000, ZWhz1.s, ZWhz1.z);
  kwhc<<<g625, dim3(256), 0, stream>>>(Whn1, WhC + 320000, ZWhn1.s, ZWhn1.z);
  kwhc<<<g625, dim3(256), 0, stream>>>(Whr2, WhC + 480000, ZWhr2.s, ZWhr2.z);
  kwhc<<<g625, dim3(256), 0, stream>>>(Whz2, WhC + 640000, ZWhz2.s, ZWhz2.z);
  kwhc<<<g625, dim3(256), 0, stream>>>(Whn2, WhC + 800000, ZWhn2.s, ZWhn2.z);
  kcolsum<<<dim3(10), dim3(256), 0, stream>>>(WhC, colsum);
  unsigned code0 = (unsigned)(Zrnn.z < 0.f ? 0.f : (Zrnn.z > 255.f ? 255.f : Zrnn.z)); // fq(0) code on rnn grid
  kinit<<<dim3(25), dim3(256), 0, stream>>>(hpub1, hpub2, code0);

  auto gemm = [&](const float* Af, const unsigned char* Au8, const float* B, const float* bias,
                  float* outF, unsigned char* outU8, int M, int N, int K,
                  int aMode, int epMode, int rowOff, SZ aSZ, SZ e1, SZ e2) {
    dim3 grid(M / 128, (N + 127) / 128);
    gemm_k<<<grid, dim3(256), 0, stream>>>(Af, Au8, B, bias, outF, outU8,
                                           M, N, K, aMode, epMode, rowOff,
                                           aSZ.s, aSZ.z, e1.s, e1.z, e2.s, e2.z);
  };

  // ---- FC1: xs codes [T*64+b][400] ----
  gemm(x, nullptr, W1q, b1q, nullptr, xsq, 64000, 400, 257, 2, 0, 0, Zx, Zfc1mm, Zfc1add);

  // ---- GRU layer 1 input projections -> A/C/E codes ----
  gemm(nullptr, xsq, Wiq + 0,      biq + 0,   nullptr, Aq, 64000, 400, 400, 1, 0, 0, Zfc1add, Za_1, Za1);
  gemm(nullptr, xsq, Wiq + 160000, biq + 400, nullptr, Cq, 64000, 400, 400, 1, 0, 0, Zfc1add, Zc_1, Zc1);
  gemm(nullptr, xsq, Wiq + 320000, biq + 800, nullptr, Eq, 64000, 400, 400, 1, 0, 0, Zfc1add, Ze_1, Ze1);
  // ---- GRU layer 1 recurrence ----
  gru_rec<<<dim3(256), dim3(320), 0, stream>>>(WhC, colsum, Aq, Cq, Eq,
                                               bhq + 0, bhq + 400, bhq + 800,
                                               hs1, hpub1, PL1);
  // ---- GRU layer 2 input projections (from hs1 codes) ----
  gemm(nullptr, hs1, Wiq + 480000, biq + 1200, nullptr, Aq, 64000, 400, 400, 1, 0, 0, Zrnn, Za_2, Za2);
  gemm(nullptr, hs1, Wiq + 640000, biq + 1600, nullptr, Cq, 64000, 400, 400, 1, 0, 0, Zrnn, Zc_2, Zc2);
  gemm(nullptr, hs1, Wiq + 800000, biq + 2000, nullptr, Eq, 64000, 400, 400, 1, 0, 0, Zrnn, Ze_2, Ze1);
  // ---- GRU layer 2 recurrence ----
  gru_rec<<<dim3(256), dim3(320), 0, stream>>>(WhC + 480000, colsum + 1200, Aq, Cq, Eq,
                                               bhq + 1200, bhq + 1600, bhq + 2000,
                                               hs2, hpub2, PL2);
  // ---- FC2 -> FC3 -> FC4 in 4 row chunks (activations overlay dead A/C/E region) ----
  for (int rc = 0; rc < 4; ++rc) {
    const unsigned char* a2 = hs2 + (size_t)rc * 16000 * 400;
    gemm(nullptr, a2, W2q, b2q, y2c, nullptr, 16000, 600, 400, 1, 2, 0, Zrnn, Zrnn, Zrnn);
    gemm(y2c, nullptr, W3q, b3q, y3c, nullptr, 16000, 600, 600, 0, 2, 0, Zrnn, Zrnn, Zrnn);
    gemm(y3c, nullptr, W4q, b4q, out, nullptr, 16000, 257, 600, 0, 3, rc * 16000, Zrnn, Zrnn, Zrnn);
  }
  (void)in_sizes; (void)n_in; (void)out_size; (void)ws_size;
}

// Round 3
// 10248.575 us; speedup vs baseline: 4.9738x; 1.0245x over previous
//
#include <hip/hip_runtime.h>
#include <math.h>

#define DEV static __device__ __forceinline__

// ---------------- calibration (s, z) constants, computed like the reference ----------------
struct SZ { float s, z; };

constexpr double cfloor_(double v){ long long i=(long long)v; return ((double)i > v) ? (double)(i-1) : (double)i; }
constexpr double cround_(double v){            // round half-to-even (Python round / nearbyint)
  double fl = cfloor_(v); double fr = v - fl;
  return (fr > 0.5) ? fl + 1.0 : (fr < 0.5 ? fl : ((((long long)fl) & 1LL) == 0 ? fl : fl + 1.0));
}
constexpr SZ mksz(double mn, double mx){
  double s = (mx - mn) / 255.0;
  double z = cround_(-mn / s);
  return SZ{ (float)s, (float)z };
}

constexpr SZ Zx     = mksz(-0.0025095, 0.0022181);
constexpr SZ ZW1    = mksz(-0.22075387835502625, 0.208940327167511);
constexpr SZ Zfc1mm = mksz(-0.00291599917, 0.0017367251);
constexpr SZ Zbfc1  = mksz(-0.48688140511512756, 0.5176185369491577);
constexpr SZ Zfc1add= mksz(-0.48778465390205383, 0.5181604027748108);
// layer-1 weights/biases
constexpr SZ ZWiz1 = mksz(-0.43284985423088074, 0.46175122261047363);
constexpr SZ ZWir1 = mksz(-0.34401071071624756, 0.29191476106643677);
constexpr SZ ZWin1 = mksz(-0.3236880302429199, 0.39607325196266174);
constexpr SZ ZWhz1 = mksz(-1.8417714834213257, 1.7173254489898682);
constexpr SZ ZWhr1 = mksz(-1.1574513912200928, 1.0300449132919312);
constexpr SZ ZWhn1 = mksz(-0.7756922245025635, 0.9530389308929443);
constexpr SZ Zbiz1 = mksz(-0.5063393712043762, 0.36664387583732605);
constexpr SZ Zbir1 = mksz(-0.07920225709676743, 0.20611026883125305);
constexpr SZ Zbin1 = mksz(-0.5539973378181458, 0.17938342690467834);
constexpr SZ Zbhz1 = mksz(-0.5337516665458679, 0.4148772358894348);
constexpr SZ Zbhr1 = mksz(-0.07688436657190323, 0.14814253151416779);
constexpr SZ Zbhn1 = mksz(-0.7828555107116699, 0.9008108973503113);
// layer-2 weights/biases
constexpr SZ ZWiz2 = mksz(-0.9102030992507935, 0.9408696889877319);
constexpr SZ ZWir2 = mksz(-0.9560997486114502, 0.6683358550071716);
constexpr SZ ZWin2 = mksz(-0.4721935987472534, 0.48561596870422363);
constexpr SZ ZWhz2 = mksz(-1.2992678880691528, 1.2991048097610474);
constexpr SZ ZWhr2 = mksz(-0.8318714499473572, 1.1085889339447021);
constexpr SZ ZWhn2 = mksz(-0.955470085144043, 1.046797513961792);
constexpr SZ Zbiz2 = mksz(-0.44805487990379333, 0.1560053527355194);
constexpr SZ Zbir2 = mksz(-0.08767592161893845, 0.11347303539514542);
constexpr SZ Zbin2 = mksz(-0.239909827709198, 0.12033259868621826);
constexpr SZ Zbhz2 = mksz(-0.43745461106300354, 0.12699371576309204);
constexpr SZ Zbhr2 = mksz(-0.09617264568805695, 0.07690174877643585);
constexpr SZ Zbhn2 = mksz(-0.17204178869724274, 0.19739042222499847);
// fc tail
constexpr SZ ZWfc2 = mksz(-1.3657219409942627, 1.158295750617981);
constexpr SZ Zbfc2 = mksz(-0.1750922054052353, 0.1385071724653244);
constexpr SZ ZWfc3 = mksz(-3.1666038036346436, 2.5026357173919678);
constexpr SZ Zbfc3 = mksz(-0.10188056528568268, 0.0899151861667633);
constexpr SZ ZWfc4 = mksz(-1.300571084022522, 1.928941249847412);
constexpr SZ Zbfc4 = mksz(-0.10699586570262909, 0.04597663879394531);
// gru1 stages
constexpr SZ Za_1 = mksz(-0.6389939785003662, 0.7715625762939453);
constexpr SZ Za1  = mksz(-0.6046768426895142, 0.8871182203292847);
constexpr SZ Zb_1 = mksz(-0.004922409541904926, 0.004103424027562141);
constexpr SZ Zb1  = mksz(-0.07475128024816513, 0.14630259573459625);
constexpr SZ Zc_1 = mksz(-1.5660111904144287, 1.0454494953155518);
constexpr SZ Zc1  = mksz(-1.9779117107391357, 1.3700535297393799);
constexpr SZ Zd_1 = mksz(-0.008429044857621193, 0.006403823848813772);
constexpr SZ Zd1  = mksz(-0.5529640316963196, 0.41507571935653687);
constexpr SZ Ze_1 = mksz(-1.3637111186981201, 1.018247127532959);
constexpr SZ Ze1  = mksz(-1.8583884239196777, 1.1587692499160767);
constexpr SZ Zf_1 = mksz(-0.005411399528384209, 0.0061536869034171104);
constexpr SZ Zf1  = mksz(-0.7833794355392456, 0.8978855013847351);
constexpr SZ Zr_1 = mksz(-0.6226556301116943, 0.9800534844398499);
constexpr SZ Zr1  = mksz(0.3491777181625366, 0.7271188497543335);
constexpr SZ Zz_1 = mksz(-2.392332077026367, 1.7851293087005615);
constexpr SZ Zz1  = mksz(0.08375928550958633, 0.856329083442688);
constexpr SZ Zn11 = mksz(-0.5516456365585327, 0.4556601643562317);
constexpr SZ Zn21 = mksz(-2.4100341796875, 1.1423156261444092);
constexpr SZ Zn1  = mksz(-0.983996570110321, 0.8151924014091492);
constexpr SZ Zhn11= mksz(0.143670916557312, 0.9162406921386719);
constexpr SZ Zhn21= mksz(-0.9015777111053467, 0.45391541719436646);
constexpr SZ Zhn31= mksz(-0.0016954239690676332, 0.0016671211924403906);
constexpr SZ Zrnn = mksz(-0.9016271829605103, 0.4546271562576294);
// gru2 explicit entries (the rest fall back to gru1 values, incl. rnn2GRU)
constexpr SZ Za_2 = mksz(-0.681461751461029, 0.9113116264343262);
constexpr SZ Za2  = mksz(-0.7149235010147095, 0.908741295337677);
constexpr SZ Zb_2 = mksz(-0.005148397758603096, 0.011014967225492);
constexpr SZ Zb2g = mksz(-0.09436552226543427, 0.07623167335987091);
constexpr SZ Zc_2 = mksz(-1.2279887199401855, 1.1102137565612793);
constexpr SZ Zc2  = mksz(-1.6760436296463013, 1.200895071029663);
constexpr SZ Zd_2 = mksz(-0.008141756057739258, 0.00894666276872158);
constexpr SZ Zd2  = mksz(-0.43875735998153687, 0.1262134611606598);
constexpr SZ Ze_2 = mksz(-0.6732944250106812, 0.6314664483070374);

struct RecP {
  SZ wr, wz, wn;                 // Wh scale/zero for gates r,z,n
  SZ a, c, e;                    // code grids of A/C/E
  SZ b1, b2, d1, d2, f1, f2;     // b_,b,d_,d,f_,f
  SZ r1, r2, z1, z2;             // r_,r,z_,z
  SZ n1, n2, n3;                 // n1,n2,n
  SZ hn1, hn2, hn3, rnn;
};
constexpr RecP PL1 = { ZWhr1, ZWhz1, ZWhn1, Za1, Zc1, Ze1, Zb_1, Zb1, Zd_1, Zd1, Zf_1, Zf1,
                       Zr_1, Zr1, Zz_1, Zz1, Zn11, Zn21, Zn1, Zhn11, Zhn21, Zhn31, Zrnn };
constexpr RecP PL2 = { ZWhr2, ZWhz2, ZWhn2, Za2, Zc2, Ze1, Zb_2, Zb2g, Zd_2, Zd2, Zf_1, Zf1,
                       Zr_1, Zr1, Zz_1, Zz1, Zn11, Zn21, Zn1, Zhn11, Zhn21, Zhn31, Zrnn };

// ---------------- device helpers ----------------
DEV float fq_(float x, float s, float z){
  float q = rintf(x / s) + z;                 // jnp.round = half-even = rintf
  q = fminf(fmaxf(q, 0.f), 255.f);
  return (q - z) * s;
}
DEV float sigm_(float v){ return 1.f / (1.f + expf(-v)); }

DEV unsigned udot4_(unsigned a, unsigned b, unsigned c){
#if defined(__has_builtin) && __has_builtin(__builtin_amdgcn_udot4)
  return __builtin_amdgcn_udot4(a, b, c, false);
#else
  return c + (a & 255u) * (b & 255u) + ((a >> 8) & 255u) * ((b >> 8) & 255u)
           + ((a >> 16) & 255u) * ((b >> 16) & 255u) + (a >> 24) * (b >> 24);
#endif
}

// ---------------- prep kernels ----------------
__global__ __launch_bounds__(256) void kfq(const float* __restrict__ src, float* __restrict__ dst,
                                           int n, float s, float z){
  int i = blockIdx.x * 256 + threadIdx.x;
  if (i < n) dst[i] = fq_(src[i], s, z);
}
// Wh [400][400] (k-major) -> u8 codes, column-major [j][k]
__global__ __launch_bounds__(256) void kwhc(const float* __restrict__ W, unsigned char* __restrict__ dst,
                                            float s, float z){
  int i = blockIdx.x * 256 + threadIdx.x;
  if (i < 160000) {
    int j = i / 400, k = i - j * 400;
    float q = rintf(W[k * 400 + j] / s) + z;
    q = fminf(fmaxf(q, 0.f), 255.f);
    dst[i] = (unsigned char)q;
  }
}
__global__ __launch_bounds__(256) void kcolsum(const unsigned char* __restrict__ WhC, int* __restrict__ cs){
  int i = blockIdx.x * 256 + threadIdx.x;
  if (i < 2400) {
    const unsigned char* p = WhC + (size_t)i * 400;
    int s = 0;
    for (int k = 0; k < 400; ++k) s += p[k];
    cs[i] = s;
  }
}
// init tag-0 slot of both h-publish rings with h0 codes (tag in hi-32 = 0)
__global__ __launch_bounds__(256) void kinit(unsigned long long* __restrict__ hp1,
                                             unsigned long long* __restrict__ hp2, unsigned code){
  int i = blockIdx.x * 256 + threadIdx.x;
  if (i < 6400) {
    unsigned long long w = (unsigned long long)(code * 0x01010101u); // tag 0 in hi-32
    hp1[i] = w; hp2[i] = w;
  }
}

// ---------------- tiled f32 GEMM with fused fq epilogues ----------------
// BM=BN=128, BK=16, 256 threads, 8x8 microtile. M must be a multiple of 128.
// aMode: 0 = f32 plain, 1 = u8 codes dequant (K%16==0), 2 = x [B,T,F] permuted + fq('x')
// epMode: 0 = fq(e1) + bias -> fq-code(e2) u8 ; 2 = +bias, relu -> f32 ; 3 = +bias, sigmoid -> f32 permuted [B,T,F]
__global__ __launch_bounds__(256) void gemm_k(
    const float* __restrict__ Af, const unsigned char* __restrict__ Au8,
    const float* __restrict__ B, const float* __restrict__ bias,
    float* __restrict__ outF, unsigned char* __restrict__ outU8,
    int M, int N, int K, int aMode, int epMode, int rowOff,
    float aS, float aZ, float e1S, float e1Z, float e2S, float e2Z)
{
  __shared__ __align__(16) float As[16][132];
  __shared__ __align__(16) float Bs[16][132];
  const int tid = threadIdx.x;
  const int m0 = blockIdx.x * 128;
  const int n0 = blockIdx.y * 128;
  const int tx = tid & 15, ty = tid >> 4;
  float acc[8][8];
#pragma unroll
  for (int i = 0; i < 8; ++i)
#pragma unroll
    for (int j = 0; j < 8; ++j) acc[i][j] = 0.f;

  const int kq = tid & 3;       // A staging: k-quad
  const int am = tid >> 2;      // A staging: row 0..63 (+64)
  const int bc = (tid & 31) * 4;// B staging: col
  const int br = tid >> 5;      // B staging: row 0..7 (+8)

  for (int k0 = 0; k0 < K; k0 += 16) {
    // ---- stage A (transposed into As[k][m]) ----
#pragma unroll
    for (int it = 0; it < 2; ++it) {
      int mr = am + it * 64;
      int row = m0 + mr;
      int kk = k0 + kq * 4;
      float v0, v1, v2, v3;
      if (aMode == 1) {
        const unsigned char* p = Au8 + (size_t)row * K + kk;
        uchar4 c4 = *(const uchar4*)p;
        v0 = ((float)c4.x - aZ) * aS; v1 = ((float)c4.y - aZ) * aS;
        v2 = ((float)c4.z - aZ) * aS; v3 = ((float)c4.w - aZ) * aS;
      } else if (aMode == 0) {
        const float* p = Af + (size_t)row * K + kk;
        if (kk + 3 < K) { float4 f = *(const float4*)p; v0 = f.x; v1 = f.y; v2 = f.z; v3 = f.w; }
        else {
          v0 = (kk     < K) ? p[0] : 0.f; v1 = (kk + 1 < K) ? p[1] : 0.f;
          v2 = (kk + 2 < K) ? p[2] : 0.f; v3 = (kk + 3 < K) ? p[3] : 0.f;
        }
      } else { // aMode 2: x[b][t][f], row = t*64+b
        int tt = row >> 6, bb = row & 63;
        const float* p = Af + ((size_t)bb * 1000 + tt) * 257 + kk;
        v0 = (kk     < K) ? fq_(p[0], aS, aZ) : 0.f;
        v1 = (kk + 1 < K) ? fq_(p[1], aS, aZ) : 0.f;
        v2 = (kk + 2 < K) ? fq_(p[2], aS, aZ) : 0.f;
        v3 = (kk + 3 < K) ? fq_(p[3], aS, aZ) : 0.f;
      }
      As[kq * 4 + 0][mr] = v0; As[kq * 4 + 1][mr] = v1;
      As[kq * 4 + 2][mr] = v2; As[kq * 4 + 3][mr] = v3;
    }
    // ---- stage B ----
#pragma unroll
    for (int it = 0; it < 2; ++it) {
      int rr = br + it * 8;
      int k = k0 + rr;
      int c = n0 + bc;
      float v0 = 0.f, v1 = 0.f, v2 = 0.f, v3 = 0.f;
      if (k < K) {
        const float* p = B + (size_t)k * N + c;
        if (((N & 3) == 0) && (c + 3 < N)) { float4 f = *(const float4*)p; v0 = f.x; v1 = f.y; v2 = f.z; v3 = f.w; }
        else {
          if (c     < N) v0 = p[0];
          if (c + 1 < N) v1 = p[1];
          if (c + 2 < N) v2 = p[2];
          if (c + 3 < N) v3 = p[3];
        }
      }
      float4 f4; f4.x = v0; f4.y = v1; f4.z = v2; f4.w = v3;
      *(float4*)&Bs[rr][bc] = f4;
    }
    __syncthreads();
#pragma unroll
    for (int kk = 0; kk < 16; ++kk) {
      float a_[8], b_[8];
      *(float4*)&a_[0] = *(const float4*)&As[kk][ty * 8];
      *(float4*)&a_[4] = *(const float4*)&As[kk][ty * 8 + 4];
      *(float4*)&b_[0] = *(const float4*)&Bs[kk][tx * 8];
      *(float4*)&b_[4] = *(const float4*)&Bs[kk][tx * 8 + 4];
#pragma unroll
      for (int i = 0; i < 8; ++i)
#pragma unroll
        for (int j = 0; j < 8; ++j) acc[i][j] = fmaf(a_[i], b_[j], acc[i][j]);
    }
    __syncthreads();
  }
  // ---- epilogue ----
#pragma unroll
  for (int i = 0; i < 8; ++i) {
    int row = m0 + ty * 8 + i;
#pragma unroll
    for (int j = 0; j < 8; ++j) {
      int col = n0 + tx * 8 + j;
      if (col >= N) continue;
      float v = acc[i][j];
      if (epMode == 0) {
        v = fq_(v, e1S, e1Z);
        v = v + bias[col];
        float q = rintf(v / e2S) + e2Z;
        q = fminf(fmaxf(q, 0.f), 255.f);
        outU8[(size_t)row * N + col] = (unsigned char)q;
      } else if (epMode == 2) {
        v += bias[col];
        v = fmaxf(v, 0.f);
        outF[(size_t)row * N + col] = v;
      } else {
        v += bias[col];
        v = sigm_(v);
        int rg = rowOff + row;
        int tt = rg >> 6, bb = rg & 63;
        outF[((size_t)bb * 1000 + tt) * 257 + col] = v;
      }
    }
  }
}

// ---------------- GRU recurrence (LDS weights, comm wave + own-chunk pipelining) ----------------
// 256 blocks = 64 batch rows x 4 column-slices; 384 threads = 5 dot waves + 1 comm wave.
// 1 block/CU (LDS-limited) -> all 256 co-resident. Wave 5 polls the 75 remote tagged
// h-words (relaxed agent atomics, IF$), stashes to LDS, releases a workgroup-scope LDS
// flag. Dot waves start immediately on the OWN 100-k chunk (published via LDS only),
// then spin on the LDS flag for the 3 remote chunks. 2 barriers/step, dots parity-
// double-buffered, A/C/E prefetched one step ahead, old-h kept in registers.
__global__ __launch_bounds__(384) void gru_rec(
    const unsigned char* __restrict__ WhC,   // [3][400][400] layout [g][j][k] (this layer)
    const int* __restrict__ colsum,          // [3][400]
    const unsigned char* __restrict__ Aq, const unsigned char* __restrict__ Cq,
    const unsigned char* __restrict__ Eq,
    const float* __restrict__ bhr, const float* __restrict__ bhz, const float* __restrict__ bhn,
    unsigned char* __restrict__ hs,
    unsigned long long* hpub,                // [4][64][100] u64 ring
    RecP P)
{
  __shared__ __align__(16) uint4 Wlds[9600];     // 300 cols * 32 uint4 (153.6 KB), chunk-padded+swizzled
  __shared__ __align__(16) uint4 hq_own[7];      // own chunk: 25 h-words + 3 zero pads
  __shared__ __align__(16) uint4 hqr[21];        // 3 remote chunks * 7
  __shared__ float dots[2][3][100];              // parity double-buffer
  __shared__ int flag;

  const int tid = threadIdx.x;
  const int wv  = tid >> 6;
  const int ln  = tid & 63;
  const int b   = blockIdx.x & 63;    // batch row
  const int sl  = blockIdx.x >> 6;    // column slice 0..3
  const int jbase = sl * 100;

  unsigned* Wled = (unsigned*)Wlds;
  unsigned* hqow = (unsigned*)hq_own;
  unsigned* hqrw = (unsigned*)hqr;

  // ---- preamble: stage weights word-granular into chunk-padded swizzled layout ----
  // column cid: 4 chunks (k-slices of 100B = 25 words) at uint4 slots [c*7, c*7+7),
  // word p of chunk c -> uint4 slot (c*7 + p/4) ^ (cid&31), word-in-slot p&3.
  for (int idx = tid; idx < 30000; idx += 384) {
    int cid = idx / 100, w = idx - cid * 100;
    int c = w / 25, p = w - c * 25;
    int g = cid / 100, jj = cid - g * 100;
    unsigned word = ((const unsigned*)(WhC + ((size_t)(g * 400) + jbase + jj) * 400))[w];
    int slot = (c * 7 + (p >> 2)) ^ (cid & 31);
    Wled[cid * 128 + slot * 4 + (p & 3)] = word;
  }
  for (int idx = tid; idx < 3600; idx += 384) {   // zero the 3 pad words per chunk
    int cid = idx / 12, r = idx - cid * 12;
    int c = r / 3, wd = r - c * 3 + 1;
    int slot = (c * 7 + 6) ^ (cid & 31);
    Wled[cid * 128 + slot * 4 + wd] = 0u;
  }
  const unsigned code0 = (unsigned)fminf(fmaxf(P.rnn.z, 0.f), 255.f);  // fq(0) code on rnn grid
  if (tid < 28) hqow[tid] = (tid < 25) ? code0 * 0x01010101u : 0u;
  if (tid >= 32 && tid < 41) {                    // hqr pads: chunk o words 25..27
    int r = tid - 32; int o = r / 3, wd = r - o * 3 + 1;
    hqrw[o * 28 + 24 + wd] = 0u;
  }
  if (tid == 383) flag = -1;

  // per-thread loop-invariant constants for the dot threads
  const int cid = tid;
  int g = cid / 100;
  int jj = cid - g * 100;
  float s1S = 1.f, s1Z = 0.f, s2S = 1.f, s2Z = 0.f, biasj = 0.f, swsh = 0.f;
  int zwi = 0, CSj = 0;
  if (tid < 300) {
    int j = jbase + jj;
    SZ w  = (g == 0) ? P.wr : (g == 1) ? P.wz : P.wn;
    SZ s1 = (g == 0) ? P.b1 : (g == 1) ? P.d1 : P.f1;
    SZ s2 = (g == 0) ? P.b2 : (g == 1) ? P.d2 : P.f2;
    zwi = (int)w.z;
    s1S = s1.s; s1Z = s1.z; s2S = s2.s; s2Z = s2.z;
    biasj = ((g == 0) ? bhr : (g == 1) ? bhz : bhn)[j];
    CSj = colsum[g * 400 + j];
    swsh = w.s * P.rnn.s;
  }
  const int zhi = (int)P.rnn.z;
  const int swm = cid & 31;

  // Phase-C persistent registers
  unsigned hprev = code0;
  unsigned char ca = 0, cc2 = 0, ce = 0;
  if (tid < 100) {
    int jc = jbase + tid;
    ca  = Aq[(size_t)b * 400 + jc];
    cc2 = Cq[(size_t)b * 400 + jc];
    ce  = Eq[(size_t)b * 400 + jc];
  }
  __syncthreads();

  for (int t = 0; t < 1000; ++t) {
    if (wv == 5) {
      // ---- comm wave: poll 75 remote tagged words, stash, release LDS flag ----
      const unsigned long long* base = hpub + ((size_t)(t & 3) * 64 + b) * 100;
#pragma unroll
      for (int rnd = 0; rnd < 2; ++rnd) {
        int widx = ln + rnd * 64;
        if (widx < 75) {
          int o = widx / 25, p = widx - o * 25;
          int so = (sl + o + 1) & 3;
          const unsigned long long* src = base + so * 25 + p;
          unsigned long long w64;
          while ((unsigned)((w64 = __hip_atomic_load(src, __ATOMIC_RELAXED, __HIP_MEMORY_SCOPE_AGENT)) >> 32)
                 != (unsigned)t)
            __builtin_amdgcn_s_sleep(1);
          hqrw[o * 28 + ((p >> 2) * 4) + (p & 3)] = (unsigned)w64;
        }
      }
      __hip_atomic_store(&flag, t, __ATOMIC_RELEASE, __HIP_MEMORY_SCOPE_WORKGROUP);
    } else if (tid < 300) {
      // ---- dot waves: own chunk first, then remotes behind the LDS flag ----
      unsigned acc = 0, hsum = 0;
      const uint4* wcol = &Wlds[cid * 32];
#pragma unroll
      for (int i = 0; i < 7; ++i) {
        uint4 h = hq_own[i];
        uint4 w = wcol[(sl * 7 + i) ^ swm];
        acc = udot4_(w.x, h.x, acc);  hsum = udot4_(0x01010101u, h.x, hsum);
        acc = udot4_(w.y, h.y, acc);  hsum = udot4_(0x01010101u, h.y, hsum);
        acc = udot4_(w.z, h.z, acc);  hsum = udot4_(0x01010101u, h.z, hsum);
        acc = udot4_(w.w, h.w, acc);  hsum = udot4_(0x01010101u, h.w, hsum);
      }
      while (__hip_atomic_load(&flag, __ATOMIC_ACQUIRE, __HIP_MEMORY_SCOPE_WORKGROUP) < t)
        __builtin_amdgcn_s_sleep(1);
#pragma unroll
      for (int o = 0; o < 3; ++o) {
        int c = (sl + o + 1) & 3;
#pragma unroll
        for (int i = 0; i < 7; ++i) {
          uint4 h = hqr[o * 7 + i];
          uint4 w = wcol[(c * 7 + i) ^ swm];
          acc = udot4_(w.x, h.x, acc);  hsum = udot4_(0x01010101u, h.x, hsum);
          acc = udot4_(w.y, h.y, acc);  hsum = udot4_(0x01010101u, h.y, hsum);
          acc = udot4_(w.z, h.z, acc);  hsum = udot4_(0x01010101u, h.z, hsum);
          acc = udot4_(w.w, h.w, acc);  hsum = udot4_(0x01010101u, h.w, hsum);
        }
      }
      int I = (int)acc - zwi * (int)hsum - zhi * CSj + 400 * zhi * zwi;  // exact, |I| < 2^24
      float dot = (float)I * swsh;
      float v = fq_(dot, s1S, s1Z) + biasj;
      v = fq_(v, s2S, s2Z);
      dots[t & 1][g][jj] = v;
    }
    __syncthreads();
    // ---- Phase C: elementwise GRU update + publish (waves 0/1) ----
    if (tid < 128) {                 // waves 0,1 fully active so shfl sources are valid
      int m = (tid < 100) ? tid : 99;
      int jc = jbase + m;
      float a = ((float)ca  - P.a.z) * P.a.s;
      float c = ((float)cc2 - P.c.z) * P.c.s;
      float e = ((float)ce  - P.e.z) * P.e.s;
      float bb = dots[t & 1][0][m], dd = dots[t & 1][1][m], ff = dots[t & 1][2][m];
      float r  = fq_(sigm_(fq_(a + bb, P.r1.s, P.r1.z)), P.r2.s, P.r2.z);
      float zz = fq_(sigm_(fq_(c + dd, P.z1.s, P.z1.z)), P.z2.s, P.z2.z);
      float nn = fq_(tanhf(fq_(e + fq_(r * ff, P.n1.s, P.n1.z), P.n2.s, P.n2.z)), P.n3.s, P.n3.z);
      float hold = ((float)hprev - P.rnn.z) * P.rnn.s;
      float hn2v = fq_(fq_(1.f - zz, P.hn1.s, P.hn1.z) * nn, P.hn2.s, P.hn2.z);
      float hn3v = fq_(zz * hold, P.hn3.s, P.hn3.z);
      float hnew = hn2v + hn3v;
      float q = rintf(hnew / P.rnn.s) + P.rnn.z;
      q = fminf(fmaxf(q, 0.f), 255.f);
      unsigned code = (unsigned)q;
      // pack 4 codes/word via intra-wave shuffles
      unsigned c1 = __shfl_down(code, 1);
      unsigned c2 = __shfl_down(code, 2);
      unsigned c3 = __shfl_down(code, 3);
      if (tid < 100) {
        hprev = code;
        hs[((size_t)t * 64 + b) * 400 + jc] = (unsigned char)code;
        if ((tid & 3) == 0) {
          unsigned packed = code | (c1 << 8) | (c2 << 16) | (c3 << 24);
          unsigned long long out64 = ((unsigned long long)(unsigned)(t + 1) << 32) | packed;
          unsigned long long* dst = hpub + ((size_t)((t + 1) & 3) * 64 + b) * 100 + sl * 25 + (tid >> 2);
          __hip_atomic_store(dst, out64, __ATOMIC_RELAXED, __HIP_MEMORY_SCOPE_AGENT);
          hqow[tid >> 2] = packed;            // own chunk straight to LDS (no global round-trip)
        }
        if (t < 999) {                        // prefetch a/c/e for step t+1
          size_t row = (size_t)(t + 1) * 64 + b;
          ca  = Aq[row * 400 + jc];
          cc2 = Cq[row * 400 + jc];
          ce  = Eq[row * 400 + jc];
        }
      }
    }
    __syncthreads();
  }
}

// ---------------- host launch ----------------
extern "C" void kernel_launch(void* const* d_in, const int* in_sizes, int n_in,
                              void* d_out, int out_size, void* d_ws, size_t ws_size,
                              hipStream_t stream)
{
  const float* x    = (const float*)d_in[0];
  const float* Wfc1 = (const float*)d_in[1];
  const float* bfc1 = (const float*)d_in[2];
  // dict order per setup_inputs: for L in (1,2): for g in (z,r,n): Wi, Wh, bi, bh
  const float* Wiz1 = (const float*)d_in[3];  const float* Whz1 = (const float*)d_in[4];
  const float* biz1 = (const float*)d_in[5];  const float* bhz1 = (const float*)d_in[6];
  const float* Wir1 = (const float*)d_in[7];  const float* Whr1 = (const float*)d_in[8];
  const float* bir1 = (const float*)d_in[9];  const float* bhr1 = (const float*)d_in[10];
  const float* Win1 = (const float*)d_in[11]; const float* Whn1 = (const float*)d_in[12];
  const float* bin1 = (const float*)d_in[13]; const float* bhn1 = (const float*)d_in[14];
  const float* Wiz2 = (const float*)d_in[15]; const float* Whz2 = (const float*)d_in[16];
  const float* biz2 = (const float*)d_in[17]; const float* bhz2 = (const float*)d_in[18];
  const float* Wir2 = (const float*)d_in[19]; const float* Whr2 = (const float*)d_in[20];
  const float* bir2 = (const float*)d_in[21]; const float* bhr2 = (const float*)d_in[22];
  const float* Win2 = (const float*)d_in[23]; const float* Whn2 = (const float*)d_in[24];
  const float* bin2 = (const float*)d_in[25]; const float* bhn2 = (const float*)d_in[26];
  const float* Wfc2 = (const float*)d_in[27]; const float* bfc2 = (const float*)d_in[28];
  const float* Wfc3 = (const float*)d_in[29]; const float* bfc3 = (const float*)d_in[30];
  const float* Wfc4 = (const float*)d_in[31]; const float* bfc4 = (const float*)d_in[32];
  float* out = (float*)d_out;

  // ---- workspace carve (total ~160 MB) ----
  char* wp = (char*)d_ws;
  auto alloc = [&](size_t bytes) -> void* {
    void* p = (void*)wp;
    wp += (bytes + 255) & ~(size_t)255;
    return p;
  };
  float* W1q = (float*)alloc(102800 * 4);
  float* Wiq = (float*)alloc(960000 * 4);   // [L][r,z,n][400*400]
  float* W2q = (float*)alloc(240000 * 4);
  float* W3q = (float*)alloc(360000 * 4);
  float* W4q = (float*)alloc(154200 * 4);
  float* b1q = (float*)alloc(400 * 4);
  float* biq = (float*)alloc(2400 * 4);     // [L][r,z,n][400]
  float* bhq = (float*)alloc(2400 * 4);
  float* b2q = (float*)alloc(600 * 4);
  float* b3q = (float*)alloc(600 * 4);
  float* b4q = (float*)alloc(257 * 4);
  unsigned char* WhC = (unsigned char*)alloc(960000);  // [L][r,z,n][j][k] codes
  int* colsum = (int*)alloc(2400 * 4);
  unsigned char* xsq = (unsigned char*)alloc(25600000);
  unsigned char* Aq  = (unsigned char*)alloc(25600000);
  unsigned char* Cq  = (unsigned char*)alloc(25600000);
  unsigned char* Eq  = (unsigned char*)alloc(25600000);
  unsigned char* hs1 = (unsigned char*)alloc(25600000);
  unsigned char* hs2 = (unsigned char*)alloc(25600000);
  unsigned long long* hpub1 = (unsigned long long*)alloc(4 * 64 * 100 * 8); // depth-4 ring
  unsigned long long* hpub2 = (unsigned long long*)alloc(4 * 64 * 100 * 8);
  // f32 FC-chain chunk buffers overlay the dead A/C/E region (contiguous 76.8 MB)
  float* y2c = (float*)Aq;
  float* y3c = (float*)(Aq + 38400000);

  auto fqk = [&](const float* s, float* d, int n, SZ p) {
    kfq<<<dim3((n + 255) / 256), dim3(256), 0, stream>>>(s, d, n, p.s, p.z);
  };
  // ---- prep: fake-quantized weights/biases + recurrence weight codes ----
  fqk(Wfc1, W1q, 102800, ZW1);
  fqk(Wir1, Wiq + 0,      160000, ZWir1); fqk(Wiz1, Wiq + 160000, 160000, ZWiz1);
  fqk(Win1, Wiq + 320000, 160000, ZWin1);
  fqk(Wir2, Wiq + 480000, 160000, ZWir2); fqk(Wiz2, Wiq + 640000, 160000, ZWiz2);
  fqk(Win2, Wiq + 800000, 160000, ZWin2);
  fqk(Wfc2, W2q, 240000, ZWfc2); fqk(Wfc3, W3q, 360000, ZWfc3); fqk(Wfc4, W4q, 154200, ZWfc4);
  fqk(bfc1, b1q, 400, Zbfc1);
  fqk(bir1, biq + 0, 400, Zbir1);    fqk(biz1, biq + 400, 400, Zbiz1);  fqk(bin1, biq + 800, 400, Zbin1);
  fqk(bir2, biq + 1200, 400, Zbir2); fqk(biz2, biq + 1600, 400, Zbiz2); fqk(bin2, biq + 2000, 400, Zbin2);
  fqk(bhr1, bhq + 0, 400, Zbhr1);    fqk(bhz1, bhq + 400, 400, Zbhz1);  fqk(bhn1, bhq + 800, 400, Zbhn1);
  fqk(bhr2, bhq + 1200, 400, Zbhr2); fqk(bhz2, bhq + 1600, 400, Zbhz2); fqk(bhn2, bhq + 2000, 400, Zbhn2);
  fqk(bfc2, b2q, 600, Zbfc2); fqk(bfc3, b3q, 600, Zbfc3); fqk(bfc4, b4q, 257, Zbfc4);

  dim3 g625((160000 + 255) / 256);
  kwhc<<<g625, dim3(256), 0, stream>>>(Whr1, WhC + 0,      ZWhr1.s, ZWhr1.z);
  kwhc<<<g625, dim3(256), 0, stream>>>(Whz1, WhC + 160000, ZWhz1.s, ZWhz1.z);
  kwhc<<<g625, dim3(256), 0, stream>>>(Whn1, WhC + 320000, ZWhn1.s, ZWhn1.z);
  kwhc<<<g625, dim3(256), 0, stream>>>(Whr2, WhC + 480000, ZWhr2.s, ZWhr2.z);
  kwhc<<<g625, dim3(256), 0, stream>>>(Whz2, WhC + 640000, ZWhz2.s, ZWhz2.z);
  kwhc<<<g625, dim3(256), 0, stream>>>(Whn2, WhC + 800000, ZWhn2.s, ZWhn2.z);
  kcolsum<<<dim3(10), dim3(256), 0, stream>>>(WhC, colsum);
  unsigned code0 = (unsigned)(Zrnn.z < 0.f ? 0.f : (Zrnn.z > 255.f ? 255.f : Zrnn.z)); // fq(0) code on rnn grid
  kinit<<<dim3(25), dim3(256), 0, stream>>>(hpub1, hpub2, code0);

  auto gemm = [&](const float* Af, const unsigned char* Au8, const float* B, const float* bias,
                  float* outF, unsigned char* outU8, int M, int N, int K,
                  int aMode, int epMode, int rowOff, SZ aSZ, SZ e1, SZ e2) {
    dim3 grid(M / 128, (N + 127) / 128);
    gemm_k<<<grid, dim3(256), 0, stream>>>(Af, Au8, B, bias, outF, outU8,
                                           M, N, K, aMode, epMode, rowOff,
                                           aSZ.s, aSZ.z, e1.s, e1.z, e2.s, e2.z);
  };

  // ---- FC1: xs codes [T*64+b][400] ----
  gemm(x, nullptr, W1q, b1q, nullptr, xsq, 64000, 400, 257, 2, 0, 0, Zx, Zfc1mm, Zfc1add);

  // ---- GRU layer 1 input projections -> A/C/E codes ----
  gemm(nullptr, xsq, Wiq + 0,      biq + 0,   nullptr, Aq, 64000, 400, 400, 1, 0, 0, Zfc1add, Za_1, Za1);
  gemm(nullptr, xsq, Wiq + 160000, biq + 400, nullptr, Cq, 64000, 400, 400, 1, 0, 0, Zfc1add, Zc_1, Zc1);
  gemm(nullptr, xsq, Wiq + 320000, biq + 800, nullptr, Eq, 64000, 400, 400, 1, 0, 0, Zfc1add, Ze_1, Ze1);
  // ---- GRU layer 1 recurrence ----
  gru_rec<<<dim3(256), dim3(384), 0, stream>>>(WhC, colsum, Aq, Cq, Eq,
                                               bhq + 0, bhq + 400, bhq + 800,
                                               hs1, hpub1, PL1);
  // ---- GRU layer 2 input projections (from hs1 codes) ----
  gemm(nullptr, hs1, Wiq + 480000, biq + 1200, nullptr, Aq, 64000, 400, 400, 1, 0, 0, Zrnn, Za_2, Za2);
  gemm(nullptr, hs1, Wiq + 640000, biq + 1600, nullptr, Cq, 64000, 400, 400, 1, 0, 0, Zrnn, Zc_2, Zc2);
  gemm(nullptr, hs1, Wiq + 800000, biq + 2000, nullptr, Eq, 64000, 400, 400, 1, 0, 0, Zrnn, Ze_2, Ze1);
  // ---- GRU layer 2 recurrence ----
  gru_rec<<<dim3(256), dim3(384), 0, stream>>>(WhC + 480000, colsum + 1200, Aq, Cq, Eq,
                                               bhq + 1200, bhq + 1600, bhq + 2000,
                                               hs2, hpub2, PL2);
  // ---- FC2 -> FC3 -> FC4 in 4 row chunks (activations overlay dead A/C/E region) ----
  for (int rc = 0; rc < 4; ++rc) {
    const unsigned char* a2 = hs2 + (size_t)rc * 16000 * 400;
    gemm(nullptr, a2, W2q, b2q, y2c, nullptr, 16000, 600, 400, 1, 2, 0, Zrnn, Zrnn, Zrnn);
    gemm(y2c, nullptr, W3q, b3q, y3c, nullptr, 16000, 600, 600, 0, 2, 0, Zrnn, Zrnn, Zrnn);
    gemm(y3c, nullptr, W4q, b4q, out, nullptr, 16000, 257, 600, 0, 3, rc * 16000, Zrnn, Zrnn, Zrnn);
  }
  (void)in_sizes; (void)n_in; (void)out_size; (void)ws_size;
}

// Round 4
// 10065.388 us; speedup vs baseline: 5.0643x; 1.0182x over previous
//
#include <hip/hip_runtime.h>
#include <math.h>

#define DEV static __device__ __forceinline__

#if defined(__has_builtin)
#if __has_builtin(__builtin_amdgcn_mfma_i32_16x16x64_i8)
#define HAVE_I8MFMA 1
#endif
#endif

typedef int v4i __attribute__((ext_vector_type(4)));

// ---------------- calibration (s, z) constants, computed like the reference ----------------
struct SZ { float s, z; };

constexpr double cfloor_(double v){ long long i=(long long)v; return ((double)i > v) ? (double)(i-1) : (double)i; }
constexpr double cround_(double v){            // round half-to-even (Python round / nearbyint)
  double fl = cfloor_(v); double fr = v - fl;
  return (fr > 0.5) ? fl + 1.0 : (fr < 0.5 ? fl : ((((long long)fl) & 1LL) == 0 ? fl : fl + 1.0));
}
constexpr SZ mksz(double mn, double mx){
  double s = (mx - mn) / 255.0;
  double z = cround_(-mn / s);
  return SZ{ (float)s, (float)z };
}

constexpr SZ Zx     = mksz(-0.0025095, 0.0022181);
constexpr SZ ZW1    = mksz(-0.22075387835502625, 0.208940327167511);
constexpr SZ Zfc1mm = mksz(-0.00291599917, 0.0017367251);
constexpr SZ Zbfc1  = mksz(-0.48688140511512756, 0.5176185369491577);
constexpr SZ Zfc1add= mksz(-0.48778465390205383, 0.5181604027748108);
// layer-1 weights/biases
constexpr SZ ZWiz1 = mksz(-0.43284985423088074, 0.46175122261047363);
constexpr SZ ZWir1 = mksz(-0.34401071071624756, 0.29191476106643677);
constexpr SZ ZWin1 = mksz(-0.3236880302429199, 0.39607325196266174);
constexpr SZ ZWhz1 = mksz(-1.8417714834213257, 1.7173254489898682);
constexpr SZ ZWhr1 = mksz(-1.1574513912200928, 1.0300449132919312);
constexpr SZ ZWhn1 = mksz(-0.7756922245025635, 0.9530389308929443);
constexpr SZ Zbiz1 = mksz(-0.5063393712043762, 0.36664387583732605);
constexpr SZ Zbir1 = mksz(-0.07920225709676743, 0.20611026883125305);
constexpr SZ Zbin1 = mksz(-0.5539973378181458, 0.17938342690467834);
constexpr SZ Zbhz1 = mksz(-0.5337516665458679, 0.4148772358894348);
constexpr SZ Zbhr1 = mksz(-0.07688436657190323, 0.14814253151416779);
constexpr SZ Zbhn1 = mksz(-0.7828555107116699, 0.9008108973503113);
// layer-2 weights/biases
constexpr SZ ZWiz2 = mksz(-0.9102030992507935, 0.9408696889877319);
constexpr SZ ZWir2 = mksz(-0.9560997486114502, 0.6683358550071716);
constexpr SZ ZWin2 = mksz(-0.4721935987472534, 0.48561596870422363);
constexpr SZ ZWhz2 = mksz(-1.2992678880691528, 1.2991048097610474);
constexpr SZ ZWhr2 = mksz(-0.8318714499473572, 1.1085889339447021);
constexpr SZ ZWhn2 = mksz(-0.955470085144043, 1.046797513961792);
constexpr SZ Zbiz2 = mksz(-0.44805487990379333, 0.1560053527355194);
constexpr SZ Zbir2 = mksz(-0.08767592161893845, 0.11347303539514542);
constexpr SZ Zbin2 = mksz(-0.239909827709198, 0.12033259868621826);
constexpr SZ Zbhz2 = mksz(-0.43745461106300354, 0.12699371576309204);
constexpr SZ Zbhr2 = mksz(-0.09617264568805695, 0.07690174877643585);
constexpr SZ Zbhn2 = mksz(-0.17204178869724274, 0.19739042222499847);
// fc tail
constexpr SZ ZWfc2 = mksz(-1.3657219409942627, 1.158295750617981);
constexpr SZ Zbfc2 = mksz(-0.1750922054052353, 0.1385071724653244);
constexpr SZ ZWfc3 = mksz(-3.1666038036346436, 2.5026357173919678);
constexpr SZ Zbfc3 = mksz(-0.10188056528568268, 0.0899151861667633);
constexpr SZ ZWfc4 = mksz(-1.300571084022522, 1.928941249847412);
constexpr SZ Zbfc4 = mksz(-0.10699586570262909, 0.04597663879394531);
// gru1 stages
constexpr SZ Za_1 = mksz(-0.6389939785003662, 0.7715625762939453);
constexpr SZ Za1  = mksz(-0.6046768426895142, 0.8871182203292847);
constexpr SZ Zb_1 = mksz(-0.004922409541904926, 0.004103424027562141);
constexpr SZ Zb1  = mksz(-0.07475128024816513, 0.14630259573459625);
constexpr SZ Zc_1 = mksz(-1.5660111904144287, 1.0454494953155518);
constexpr SZ Zc1  = mksz(-1.9779117107391357, 1.3700535297393799);
constexpr SZ Zd_1 = mksz(-0.008429044857621193, 0.006403823848813772);
constexpr SZ Zd1  = mksz(-0.5529640316963196, 0.41507571935653687);
constexpr SZ Ze_1 = mksz(-1.3637111186981201, 1.018247127532959);
constexpr SZ Ze1  = mksz(-1.8583884239196777, 1.1587692499160767);
constexpr SZ Zf_1 = mksz(-0.005411399528384209, 0.0061536869034171104);
constexpr SZ Zf1  = mksz(-0.7833794355392456, 0.8978855013847351);
constexpr SZ Zr_1 = mksz(-0.6226556301116943, 0.9800534844398499);
constexpr SZ Zr1  = mksz(0.3491777181625366, 0.7271188497543335);
constexpr SZ Zz_1 = mksz(-2.392332077026367, 1.7851293087005615);
constexpr SZ Zz1  = mksz(0.08375928550958633, 0.856329083442688);
constexpr SZ Zn11 = mksz(-0.5516456365585327, 0.4556601643562317);
constexpr SZ Zn21 = mksz(-2.4100341796875, 1.1423156261444092);
constexpr SZ Zn1  = mksz(-0.983996570110321, 0.8151924014091492);
constexpr SZ Zhn11= mksz(0.143670916557312, 0.9162406921386719);
constexpr SZ Zhn21= mksz(-0.9015777111053467, 0.45391541719436646);
constexpr SZ Zhn31= mksz(-0.0016954239690676332, 0.0016671211924403906);
constexpr SZ Zrnn = mksz(-0.9016271829605103, 0.4546271562576294);
// gru2 explicit entries (the rest fall back to gru1 values, incl. rnn2GRU)
constexpr SZ Za_2 = mksz(-0.681461751461029, 0.9113116264343262);
constexpr SZ Za2  = mksz(-0.7149235010147095, 0.908741295337677);
constexpr SZ Zb_2 = mksz(-0.005148397758603096, 0.011014967225492);
constexpr SZ Zb2g = mksz(-0.09436552226543427, 0.07623167335987091);
constexpr SZ Zc_2 = mksz(-1.2279887199401855, 1.1102137565612793);
constexpr SZ Zc2  = mksz(-1.6760436296463013, 1.200895071029663);
constexpr SZ Zd_2 = mksz(-0.008141756057739258, 0.00894666276872158);
constexpr SZ Zd2  = mksz(-0.43875735998153687, 0.1262134611606598);
constexpr SZ Ze_2 = mksz(-0.6732944250106812, 0.6314664483070374);

struct RecP {
  SZ wr, wz, wn;                 // Wh scale/zero for gates r,z,n
  SZ a, c, e;                    // code grids of A/C/E
  SZ b1, b2, d1, d2, f1, f2;     // b_,b,d_,d,f_,f
  SZ r1, r2, z1, z2;             // r_,r,z_,z
  SZ n1, n2, n3;                 // n1,n2,n
  SZ hn1, hn2, hn3, rnn;
};
constexpr RecP PL1 = { ZWhr1, ZWhz1, ZWhn1, Za1, Zc1, Ze1, Zb_1, Zb1, Zd_1, Zd1, Zf_1, Zf1,
                       Zr_1, Zr1, Zz_1, Zz1, Zn11, Zn21, Zn1, Zhn11, Zhn21, Zhn31, Zrnn };
constexpr RecP PL2 = { ZWhr2, ZWhz2, ZWhn2, Za2, Zc2, Ze1, Zb_2, Zb2g, Zd_2, Zd2, Zf_1, Zf1,
                       Zr_1, Zr1, Zz_1, Zz1, Zn11, Zn21, Zn1, Zhn11, Zhn21, Zhn31, Zrnn };

// ---------------- device helpers ----------------
DEV float fq_(float x, float s, float z){
  float q = rintf(x / s) + z;                 // jnp.round = half-even = rintf
  q = fminf(fmaxf(q, 0.f), 255.f);
  return (q - z) * s;
}
DEV float sigm_(float v){ return 1.f / (1.f + expf(-v)); }

DEV unsigned udot4_(unsigned a, unsigned b, unsigned c){
#if defined(__has_builtin) && __has_builtin(__builtin_amdgcn_udot4)
  return __builtin_amdgcn_udot4(a, b, c, false);
#else
  return c + (a & 255u) * (b & 255u) + ((a >> 8) & 255u) * ((b >> 8) & 255u)
           + ((a >> 16) & 255u) * ((b >> 16) & 255u) + (a >> 24) * (b >> 24);
#endif
}

// ---------------- prep kernels ----------------
__global__ __launch_bounds__(256) void kfq(const float* __restrict__ src, float* __restrict__ dst,
                                           int n, float s, float z){
  int i = blockIdx.x * 256 + threadIdx.x;
  if (i < n) dst[i] = fq_(src[i], s, z);
}
// Wh [400][400] (k-major) -> u8 codes, column-major [j][k]
__global__ __launch_bounds__(256) void kwhc(const float* __restrict__ W, unsigned char* __restrict__ dst,
                                            float s, float z){
  int i = blockIdx.x * 256 + threadIdx.x;
  if (i < 160000) {
    int j = i / 400, k = i - j * 400;
    float q = rintf(W[k * 400 + j] / s) + z;
    q = fminf(fmaxf(q, 0.f), 255.f);
    dst[i] = (unsigned char)q;
  }
}
__global__ __launch_bounds__(256) void kcolsum(const unsigned char* __restrict__ WhC, int* __restrict__ cs){
  int i = blockIdx.x * 256 + threadIdx.x;
  if (i < 2400) {
    const unsigned char* p = WhC + (size_t)i * 400;
    int s = 0;
    for (int k = 0; k < 400; ++k) s += p[k];
    cs[i] = s;
  }
}
// Wi [400 k][400 n] -> transposed biased codes [n][464] (q^0x80, pad 0) + colsum of (q-128)
__global__ __launch_bounds__(256) void kwic(const float* __restrict__ W, signed char* __restrict__ Bt,
                                            int* __restrict__ cs, float s, float z){
  int n = blockIdx.x * 256 + threadIdx.x;
  if (n < 400) {
    int csum = 0;
    signed char* dst = Bt + (size_t)n * 464;
    for (int k = 0; k < 400; ++k) {
      float q = rintf(W[k * 400 + n] / s) + z;
      q = fminf(fmaxf(q, 0.f), 255.f);
      int qi = (int)q;
      csum += qi - 128;
      dst[k] = (signed char)(qi ^ 0x80);
    }
    for (int k = 400; k < 464; ++k) dst[k] = 0;
    cs[n] = csum;
  }
}
// per-row sums of (q-128) over 400 u8 codes
__global__ __launch_bounds__(256) void krsum(const unsigned char* __restrict__ A, int* __restrict__ rs){
  int r = blockIdx.x * 256 + threadIdx.x;   // 64000 rows
  const unsigned* p = (const unsigned*)(A + (size_t)r * 400);
  unsigned s = 0;
  for (int i = 0; i < 100; ++i) s = udot4_(p[i], 0x01010101u, s);
  rs[r] = (int)s - 51200;
}
// init tag-0 slot of both h-publish rings with h0 codes (tag in hi-32 = 0)
__global__ __launch_bounds__(256) void kinit(unsigned long long* __restrict__ hp1,
                                             unsigned long long* __restrict__ hp2, unsigned code){
  int i = blockIdx.x * 256 + threadIdx.x;
  if (i < 6400) {
    unsigned long long w = (unsigned long long)(code * 0x01010101u); // tag 0 in hi-32
    hp1[i] = w; hp2[i] = w;
  }
}

// ---------------- exact-int i8 MFMA GEMM (input projections) ----------------
// M=64000, N=400, K=400 (padded 448). A: u8 codes [M][400]. Bt: biased codes [n][464].
// dot_int = S + (128-zw)*RA' + (128-za)*CW' + 400*(128-za)*(128-zw), S from i8 MFMA.
// Tiles: BM=128, BN=80 (5x16), 256 threads = 4 waves; wave w covers rows [w*32,w*32+32).
__global__ __launch_bounds__(256) void gemm_i8(
    const unsigned char* __restrict__ Au8, const int* __restrict__ rowsum,
    const signed char* __restrict__ Bt, const int* __restrict__ colsum,
    const float* __restrict__ bias, unsigned char* __restrict__ outU8,
    int czw, int cza, int cconst, float ss,
    float e1S, float e1Z, float e2S, float e2Z)
{
  __shared__ __align__(16) signed char Asl[128 * 464];
  __shared__ __align__(16) signed char Bsl[80 * 464];
  const int tid = threadIdx.x;
  const int m0 = blockIdx.x * 128;
  const int n0 = blockIdx.y * 80;
  // stage B: contiguous 80x464
  {
    const uint4* src = (const uint4*)(Bt + (size_t)n0 * 464);
    uint4* dst = (uint4*)Bsl;
    for (int i = tid; i < 80 * 29; i += 256) dst[i] = src[i];
  }
  // stage A: bias bytes, pad k [400,464) with 0
  for (int i = tid; i < 128 * 29; i += 256) {
    int r = i / 29, c = i - r * 29;
    uint4 v;
    if (c < 25) {
      v = *(const uint4*)(Au8 + (size_t)(m0 + r) * 400 + c * 16);
      v.x ^= 0x80808080u; v.y ^= 0x80808080u; v.z ^= 0x80808080u; v.w ^= 0x80808080u;
    } else { v.x = 0u; v.y = 0u; v.z = 0u; v.w = 0u; }
    *(uint4*)(Asl + (size_t)r * 464 + c * 16) = v;
  }
  __syncthreads();
  const int wv = tid >> 6, ln = tid & 63;
  const int lr = ln & 15;        // A row-in-tile / B col-in-tile
  const int lk = ln >> 4;        // k-group (16B)
  v4i acc[2][5];
#pragma unroll
  for (int i = 0; i < 2; ++i)
#pragma unroll
    for (int j = 0; j < 5; ++j) { acc[i][j][0] = 0; acc[i][j][1] = 0; acc[i][j][2] = 0; acc[i][j][3] = 0; }
  for (int kc = 0; kc < 7; ++kc) {
    int kb = kc * 64 + lk * 16;
#ifdef HAVE_I8MFMA
    v4i af[2], bf[5];
#pragma unroll
    for (int i = 0; i < 2; ++i)
      af[i] = *(const v4i*)(Asl + (size_t)(wv * 32 + i * 16 + lr) * 464 + kb);
#pragma unroll
    for (int j = 0; j < 5; ++j)
      bf[j] = *(const v4i*)(Bsl + (size_t)(j * 16 + lr) * 464 + kb);
#pragma unroll
    for (int i = 0; i < 2; ++i)
#pragma unroll
      for (int j = 0; j < 5; ++j)
        acc[i][j] = __builtin_amdgcn_mfma_i32_16x16x64_i8(af[i], bf[j], acc[i][j], 0, 0, 0);
#else
    (void)kb;
#pragma unroll
    for (int i = 0; i < 2; ++i)
      for (int j = 0; j < 5; ++j)
        for (int reg = 0; reg < 4; ++reg) {
          const signed char* ar = Asl + (size_t)(wv * 32 + i * 16 + lk * 4 + reg) * 464 + kc * 64;
          const signed char* br = Bsl + (size_t)(j * 16 + lr) * 464 + kc * 64;
          int s2 = acc[i][j][reg];
          for (int kk = 0; kk < 64; ++kk) s2 += (int)ar[kk] * (int)br[kk];
          acc[i][j][reg] = s2;
        }
#endif
  }
  // epilogue: D row=(lk*4+reg), col=lr per 16x16 tile
#pragma unroll
  for (int i = 0; i < 2; ++i) {
#pragma unroll
    for (int reg = 0; reg < 4; ++reg) {
      int row = m0 + wv * 32 + i * 16 + lk * 4 + reg;
      int RA = rowsum[row];
#pragma unroll
      for (int j = 0; j < 5; ++j) {
        int col = n0 + j * 16 + lr;
        int I = acc[i][j][reg] + czw * RA + cza * colsum[col] + cconst;
        float v = (float)I * ss;
        v = fq_(v, e1S, e1Z) + bias[col];
        float q = rintf(v / e2S) + e2Z;
        q = fminf(fmaxf(q, 0.f), 255.f);
        outU8[(size_t)row * 400 + col] = (unsigned char)q;
      }
    }
  }
}

// ---------------- tiled f32 GEMM with fused fq epilogues ----------------
// BM=BN=128, BK=16, 256 threads, 8x8 microtile. M must be a multiple of 128.
// aMode: 0 = f32 plain, 1 = u8 codes dequant (K%16==0), 2 = x [B,T,F] permuted + fq('x')
// epMode: 0 = fq(e1) + bias -> fq-code(e2) u8 ; 2 = +bias, relu -> f32 ; 3 = +bias, sigmoid -> f32 permuted [B,T,F]
__global__ __launch_bounds__(256) void gemm_k(
    const float* __restrict__ Af, const unsigned char* __restrict__ Au8,
    const float* __restrict__ B, const float* __restrict__ bias,
    float* __restrict__ outF, unsigned char* __restrict__ outU8,
    int M, int N, int K, int aMode, int epMode, int rowOff,
    float aS, float aZ, float e1S, float e1Z, float e2S, float e2Z)
{
  __shared__ __align__(16) float As[16][132];
  __shared__ __align__(16) float Bs[16][132];
  const int tid = threadIdx.x;
  const int m0 = blockIdx.x * 128;
  const int n0 = blockIdx.y * 128;
  const int tx = tid & 15, ty = tid >> 4;
  float acc[8][8];
#pragma unroll
  for (int i = 0; i < 8; ++i)
#pragma unroll
    for (int j = 0; j < 8; ++j) acc[i][j] = 0.f;

  const int kq = tid & 3;
  const int am = tid >> 2;
  const int bc = (tid & 31) * 4;
  const int br = tid >> 5;

  for (int k0 = 0; k0 < K; k0 += 16) {
#pragma unroll
    for (int it = 0; it < 2; ++it) {
      int mr = am + it * 64;
      int row = m0 + mr;
      int kk = k0 + kq * 4;
      float v0, v1, v2, v3;
      if (aMode == 1) {
        const unsigned char* p = Au8 + (size_t)row * K + kk;
        uchar4 c4 = *(const uchar4*)p;
        v0 = ((float)c4.x - aZ) * aS; v1 = ((float)c4.y - aZ) * aS;
        v2 = ((float)c4.z - aZ) * aS; v3 = ((float)c4.w - aZ) * aS;
      } else if (aMode == 0) {
        const float* p = Af + (size_t)row * K + kk;
        if (kk + 3 < K) { float4 f = *(const float4*)p; v0 = f.x; v1 = f.y; v2 = f.z; v3 = f.w; }
        else {
          v0 = (kk     < K) ? p[0] : 0.f; v1 = (kk + 1 < K) ? p[1] : 0.f;
          v2 = (kk + 2 < K) ? p[2] : 0.f; v3 = (kk + 3 < K) ? p[3] : 0.f;
        }
      } else {
        int tt = row >> 6, bb = row & 63;
        const float* p = Af + ((size_t)bb * 1000 + tt) * 257 + kk;
        v0 = (kk     < K) ? fq_(p[0], aS, aZ) : 0.f;
        v1 = (kk + 1 < K) ? fq_(p[1], aS, aZ) : 0.f;
        v2 = (kk + 2 < K) ? fq_(p[2], aS, aZ) : 0.f;
        v3 = (kk + 3 < K) ? fq_(p[3], aS, aZ) : 0.f;
      }
      As[kq * 4 + 0][mr] = v0; As[kq * 4 + 1][mr] = v1;
      As[kq * 4 + 2][mr] = v2; As[kq * 4 + 3][mr] = v3;
    }
#pragma unroll
    for (int it = 0; it < 2; ++it) {
      int rr = br + it * 8;
      int k = k0 + rr;
      int c = n0 + bc;
      float v0 = 0.f, v1 = 0.f, v2 = 0.f, v3 = 0.f;
      if (k < K) {
        const float* p = B + (size_t)k * N + c;
        if (((N & 3) == 0) && (c + 3 < N)) { float4 f = *(const float4*)p; v0 = f.x; v1 = f.y; v2 = f.z; v3 = f.w; }
        else {
          if (c     < N) v0 = p[0];
          if (c + 1 < N) v1 = p[1];
          if (c + 2 < N) v2 = p[2];
          if (c + 3 < N) v3 = p[3];
        }
      }
      float4 f4; f4.x = v0; f4.y = v1; f4.z = v2; f4.w = v3;
      *(float4*)&Bs[rr][bc] = f4;
    }
    __syncthreads();
#pragma unroll
    for (int kk = 0; kk < 16; ++kk) {
      float a_[8], b_[8];
      *(float4*)&a_[0] = *(const float4*)&As[kk][ty * 8];
      *(float4*)&a_[4] = *(const float4*)&As[kk][ty * 8 + 4];
      *(float4*)&b_[0] = *(const float4*)&Bs[kk][tx * 8];
      *(float4*)&b_[4] = *(const float4*)&Bs[kk][tx * 8 + 4];
#pragma unroll
      for (int i = 0; i < 8; ++i)
#pragma unroll
        for (int j = 0; j < 8; ++j) acc[i][j] = fmaf(a_[i], b_[j], acc[i][j]);
    }
    __syncthreads();
  }
#pragma unroll
  for (int i = 0; i < 8; ++i) {
    int row = m0 + ty * 8 + i;
#pragma unroll
    for (int j = 0; j < 8; ++j) {
      int col = n0 + tx * 8 + j;
      if (col >= N) continue;
      float v = acc[i][j];
      if (epMode == 0) {
        v = fq_(v, e1S, e1Z);
        v = v + bias[col];
        float q = rintf(v / e2S) + e2Z;
        q = fminf(fmaxf(q, 0.f), 255.f);
        outU8[(size_t)row * N + col] = (unsigned char)q;
      } else if (epMode == 2) {
        v += bias[col];
        v = fmaxf(v, 0.f);
        outF[(size_t)row * N + col] = v;
      } else {
        v += bias[col];
        v = sigm_(v);
        int rg = rowOff + row;
        int tt = rg >> 6, bb = rg & 63;
        outF[((size_t)bb * 1000 + tt) * 257 + col] = v;
      }
    }
  }
}

// ---------------- GRU recurrence (comm wave owns all global traffic) ----------------
// 256 blocks = 64 rows x 4 col-slices; 384 threads = 5 dot waves + 1 comm wave.
// Comm wave per step: issue A/C/E loads (latency hidden under poll), poll 75 remote
// tagged h-words, compute Sum(h) once, release LDS flag, deliver A/C/E via LDS, and
// store hs[t-1]. Dot waves: own chunk first, remotes behind flag, no hsum, no global.
// Phase C: publish-first, no global loads/stores.
__global__ __launch_bounds__(384) void gru_rec(
    const unsigned char* __restrict__ WhC, const int* __restrict__ colsum,
    const unsigned char* __restrict__ Aq, const unsigned char* __restrict__ Cq,
    const unsigned char* __restrict__ Eq,
    const float* __restrict__ bhr, const float* __restrict__ bhz, const float* __restrict__ bhn,
    unsigned char* __restrict__ hs,
    unsigned long long* hpub, RecP P)
{
  __shared__ __align__(16) uint4 Wlds[9600];     // 300 cols * 32 uint4, chunk-padded+swizzled
  __shared__ __align__(16) uint4 hq_own[7];
  __shared__ __align__(16) uint4 hqr[21];
  __shared__ float dots[2][3][100];
  __shared__ unsigned aceb[75];                  // A(25) C(25) E(25) words for this step
  __shared__ int HqS_s;
  __shared__ int flag;

  const int tid = threadIdx.x;
  const int wv  = tid >> 6;
  const int ln  = tid & 63;
  const int b   = blockIdx.x & 63;
  const int sl  = blockIdx.x >> 6;
  const int jbase = sl * 100;

  unsigned* Wled = (unsigned*)Wlds;
  unsigned* hqow = (unsigned*)hq_own;
  unsigned* hqrw = (unsigned*)hqr;

  for (int idx = tid; idx < 30000; idx += 384) {
    int cid0 = idx / 100, w = idx - cid0 * 100;
    int c = w / 25, p = w - c * 25;
    int g0 = cid0 / 100, jj0 = cid0 - g0 * 100;
    unsigned word = ((const unsigned*)(WhC + ((size_t)(g0 * 400) + jbase + jj0) * 400))[w];
    int slot = (c * 7 + (p >> 2)) ^ (cid0 & 31);
    Wled[cid0 * 128 + slot * 4 + (p & 3)] = word;
  }
  for (int idx = tid; idx < 3600; idx += 384) {
    int cid0 = idx / 12, r = idx - cid0 * 12;
    int c = r / 3, wd = r - c * 3 + 1;
    int slot = (c * 7 + 6) ^ (cid0 & 31);
    Wled[cid0 * 128 + slot * 4 + wd] = 0u;
  }
  const unsigned code0 = (unsigned)fminf(fmaxf(P.rnn.z, 0.f), 255.f);
  if (tid < 28) hqow[tid] = (tid < 25) ? code0 * 0x01010101u : 0u;
  if (tid >= 32 && tid < 41) {
    int r = tid - 32; int o = r / 3, wd = r - o * 3 + 1;
    hqrw[o * 28 + 24 + wd] = 0u;
  }
  if (tid == 383) flag = -1;

  const int cid = tid;
  int g = cid / 100;
  int jj = cid - g * 100;
  float s1S = 1.f, s1Z = 0.f, s2S = 1.f, s2Z = 0.f, biasj = 0.f, swsh = 0.f;
  int zwi = 0, CSj = 0;
  if (tid < 300) {
    int j = jbase + jj;
    SZ w  = (g == 0) ? P.wr : (g == 1) ? P.wz : P.wn;
    SZ s1 = (g == 0) ? P.b1 : (g == 1) ? P.d1 : P.f1;
    SZ s2 = (g == 0) ? P.b2 : (g == 1) ? P.d2 : P.f2;
    zwi = (int)w.z;
    s1S = s1.s; s1Z = s1.z; s2S = s2.s; s2Z = s2.z;
    biasj = ((g == 0) ? bhr : (g == 1) ? bhz : bhn)[j];
    CSj = colsum[g * 400 + j];
    swsh = w.s * P.rnn.s;
  }
  const int zhi = (int)P.rnn.z;
  const int swm = cid & 31;

  unsigned hprev = code0;
  __syncthreads();

  for (int t = 0; t < 1000; ++t) {
    if (wv == 5) {
      // (1) issue A/C/E loads for row t (latency overlapped with the poll below)
      size_t row = (size_t)t * 64 + b;
      int w0 = ln, w1 = 64 + ln;
      int wh0 = w0 / 25, wi0 = w0 - wh0 * 25;
      const unsigned char* p0 = (wh0 == 0) ? Aq : (wh0 == 1) ? Cq : Eq;
      unsigned v0 = *(const unsigned*)(p0 + row * 400 + jbase + wi0 * 4);
      unsigned v1 = 0;
      if (ln < 11) {
        int wh1 = w1 / 25, wi1 = w1 - wh1 * 25;
        const unsigned char* p1 = (wh1 == 0) ? Aq : (wh1 == 1) ? Cq : Eq;
        v1 = *(const unsigned*)(p1 + row * 400 + jbase + wi1 * 4);
      }
      // (2) poll 75 remote tagged words
      const unsigned long long* base = hpub + ((size_t)(t & 3) * 64 + b) * 100;
      unsigned pay0, pay1 = 0;
      {
        int o = ln / 25, p = ln - o * 25;
        int so = (sl + o + 1) & 3;
        const unsigned long long* src = base + so * 25 + p;
        unsigned long long w64;
        while ((unsigned)((w64 = __hip_atomic_load(src, __ATOMIC_RELAXED, __HIP_MEMORY_SCOPE_AGENT)) >> 32)
               != (unsigned)t)
          __builtin_amdgcn_s_sleep(1);
        pay0 = (unsigned)w64;
        hqrw[o * 28 + ((p >> 2) * 4) + (p & 3)] = pay0;
      }
      if (ln < 11) {
        int widx = 64 + ln;
        int o = widx / 25, p = widx - o * 25;
        int so = (sl + o + 1) & 3;
        const unsigned long long* src = base + so * 25 + p;
        unsigned long long w64;
        while ((unsigned)((w64 = __hip_atomic_load(src, __ATOMIC_RELAXED, __HIP_MEMORY_SCOPE_AGENT)) >> 32)
               != (unsigned)t)
          __builtin_amdgcn_s_sleep(1);
        pay1 = (unsigned)w64;
        hqrw[o * 28 + ((p >> 2) * 4) + (p & 3)] = pay1;
      }
      // (3) Sum(h) once: remote payloads + own chunk
      unsigned hp = udot4_(pay0, 0x01010101u, 0u);
      if (ln < 11) hp = udot4_(pay1, 0x01010101u, hp);
      if (ln < 25) hp = udot4_(hqow[ln], 0x01010101u, hp);
#pragma unroll
      for (int off = 32; off; off >>= 1) hp += __shfl_down(hp, off, 64);
      if (ln == 0) HqS_s = (int)hp;
      __hip_atomic_store(&flag, t, __ATOMIC_RELEASE, __HIP_MEMORY_SCOPE_WORKGROUP);
      // (4) deliver A/C/E codes to LDS (Phase C reads after mid barrier)
      aceb[ln] = v0;
      if (ln < 11) aceb[64 + ln] = v1;
      // (5) store previous step's h slice to hs
      if (t > 0 && ln < 25)
        *(unsigned*)(hs + ((size_t)(t - 1) * 64 + b) * 400 + jbase + ln * 4) = hqow[ln];
    } else if (tid < 300) {
      unsigned acc = 0;
      const uint4* wcol = &Wlds[cid * 32];
#pragma unroll
      for (int i = 0; i < 7; ++i) {
        uint4 h = hq_own[i];
        uint4 w = wcol[(sl * 7 + i) ^ swm];
        acc = udot4_(w.x, h.x, acc);
        acc = udot4_(w.y, h.y, acc);
        acc = udot4_(w.z, h.z, acc);
        acc = udot4_(w.w, h.w, acc);
      }
      while (__hip_atomic_load(&flag, __ATOMIC_ACQUIRE, __HIP_MEMORY_SCOPE_WORKGROUP) < t)
        __builtin_amdgcn_s_sleep(1);
#pragma unroll
      for (int o = 0; o < 3; ++o) {
        int c = (sl + o + 1) & 3;
#pragma unroll
        for (int i = 0; i < 7; ++i) {
          uint4 h = hqr[o * 7 + i];
          uint4 w = wcol[(c * 7 + i) ^ swm];
          acc = udot4_(w.x, h.x, acc);
          acc = udot4_(w.y, h.y, acc);
          acc = udot4_(w.z, h.z, acc);
          acc = udot4_(w.w, h.w, acc);
        }
      }
      int I = (int)acc - zwi * HqS_s - zhi * CSj + 400 * zhi * zwi;
      float dot = (float)I * swsh;
      float v = fq_(dot, s1S, s1Z) + biasj;
      v = fq_(v, s2S, s2Z);
      dots[t & 1][g][jj] = v;
    }
    __syncthreads();
    // ---- Phase C: elementwise GRU update + publish-first ----
    if (tid < 128) {
      int m = (tid < 100) ? tid : 99;
      const unsigned char* aceb8 = (const unsigned char*)aceb;
      float a = ((float)aceb8[m]       - P.a.z) * P.a.s;
      float c = ((float)aceb8[100 + m] - P.c.z) * P.c.s;
      float e = ((float)aceb8[200 + m] - P.e.z) * P.e.s;
      float bb = dots[t & 1][0][m], dd = dots[t & 1][1][m], ff = dots[t & 1][2][m];
      float r  = fq_(sigm_(fq_(a + bb, P.r1.s, P.r1.z)), P.r2.s, P.r2.z);
      float zz = fq_(sigm_(fq_(c + dd, P.z1.s, P.z1.z)), P.z2.s, P.z2.z);
      float nn = fq_(tanhf(fq_(e + fq_(r * ff, P.n1.s, P.n1.z), P.n2.s, P.n2.z)), P.n3.s, P.n3.z);
      float hold = ((float)hprev - P.rnn.z) * P.rnn.s;
      float hn2v = fq_(fq_(1.f - zz, P.hn1.s, P.hn1.z) * nn, P.hn2.s, P.hn2.z);
      float hn3v = fq_(zz * hold, P.hn3.s, P.hn3.z);
      float hnew = hn2v + hn3v;
      float q = rintf(hnew / P.rnn.s) + P.rnn.z;
      q = fminf(fmaxf(q, 0.f), 255.f);
      unsigned code = (unsigned)q;
      unsigned c1 = __shfl_down(code, 1);
      unsigned c2 = __shfl_down(code, 2);
      unsigned c3 = __shfl_down(code, 3);
      if (tid < 100) {
        if ((tid & 3) == 0) {
          unsigned packed = code | (c1 << 8) | (c2 << 16) | (c3 << 24);
          unsigned long long out64 = ((unsigned long long)(unsigned)(t + 1) << 32) | packed;
          unsigned long long* dst = hpub + ((size_t)((t + 1) & 3) * 64 + b) * 100 + sl * 25 + (tid >> 2);
          __hip_atomic_store(dst, out64, __ATOMIC_RELAXED, __HIP_MEMORY_SCOPE_AGENT);
          hqow[tid >> 2] = packed;
        }
        hprev = code;
      }
    }
    __syncthreads();
  }
  // final hs row (t=999) from hq_own
  if (wv == 5 && ln < 25)
    *(unsigned*)(hs + ((size_t)999 * 64 + b) * 400 + jbase + ln * 4) = hqow[ln];
}

// ---------------- host launch ----------------
extern "C" void kernel_launch(void* const* d_in, const int* in_sizes, int n_in,
                              void* d_out, int out_size, void* d_ws, size_t ws_size,
                              hipStream_t stream)
{
  const float* x    = (const float*)d_in[0];
  const float* Wfc1 = (const float*)d_in[1];
  const float* bfc1 = (const float*)d_in[2];
  const float* Wiz1 = (const float*)d_in[3];  const float* Whz1 = (const float*)d_in[4];
  const float* biz1 = (const float*)d_in[5];  const float* bhz1 = (const float*)d_in[6];
  const float* Wir1 = (const float*)d_in[7];  const float* Whr1 = (const float*)d_in[8];
  const float* bir1 = (const float*)d_in[9];  const float* bhr1 = (const float*)d_in[10];
  const float* Win1 = (const float*)d_in[11]; const float* Whn1 = (const float*)d_in[12];
  const float* bin1 = (const float*)d_in[13]; const float* bhn1 = (const float*)d_in[14];
  const float* Wiz2 = (const float*)d_in[15]; const float* Whz2 = (const float*)d_in[16];
  const float* biz2 = (const float*)d_in[17]; const float* bhz2 = (const float*)d_in[18];
  const float* Wir2 = (const float*)d_in[19]; const float* Whr2 = (const float*)d_in[20];
  const float* bir2 = (const float*)d_in[21]; const float* bhr2 = (const float*)d_in[22];
  const float* Win2 = (const float*)d_in[23]; const float* Whn2 = (const float*)d_in[24];
  const float* bin2 = (const float*)d_in[25]; const float* bhn2 = (const float*)d_in[26];
  const float* Wfc2 = (const float*)d_in[27]; const float* bfc2 = (const float*)d_in[28];
  const float* Wfc3 = (const float*)d_in[29]; const float* bfc3 = (const float*)d_in[30];
  const float* Wfc4 = (const float*)d_in[31]; const float* bfc4 = (const float*)d_in[32];
  float* out = (float*)d_out;

  char* wp = (char*)d_ws;
  auto alloc = [&](size_t bytes) -> void* {
    void* p = (void*)wp;
    wp += (bytes + 255) & ~(size_t)255;
    return p;
  };
  float* W1q = (float*)alloc(102800 * 4);
  float* Wiq = (float*)alloc(960000 * 4);   // f32 Wi (fallback path only)
  float* W2q = (float*)alloc(240000 * 4);
  float* W3q = (float*)alloc(360000 * 4);
  float* W4q = (float*)alloc(154200 * 4);
  float* b1q = (float*)alloc(400 * 4);
  float* biq = (float*)alloc(2400 * 4);
  float* bhq = (float*)alloc(2400 * 4);
  float* b2q = (float*)alloc(600 * 4);
  float* b3q = (float*)alloc(600 * 4);
  float* b4q = (float*)alloc(257 * 4);
  unsigned char* WhC = (unsigned char*)alloc(960000);
  int* colsum = (int*)alloc(2400 * 4);
  signed char* WiT = (signed char*)alloc(6 * 400 * 464);  // [L*3+g][n][464] biased codes
  int* cwi = (int*)alloc(2400 * 4);                       // Wi colsums (q-128)
  int* rsX = (int*)alloc(64000 * 4);
  int* rsH = (int*)alloc(64000 * 4);
  unsigned char* xsq = (unsigned char*)alloc(25600000);
  unsigned char* Aq  = (unsigned char*)alloc(25600000);
  unsigned char* Cq  = (unsigned char*)alloc(25600000);
  unsigned char* Eq  = (unsigned char*)alloc(25600000);
  unsigned char* hs1 = (unsigned char*)alloc(25600000);
  unsigned char* hs2 = (unsigned char*)alloc(25600000);
  unsigned long long* hpub1 = (unsigned long long*)alloc(4 * 64 * 100 * 8);
  unsigned long long* hpub2 = (unsigned long long*)alloc(4 * 64 * 100 * 8);
  float* y2c = (float*)Aq;
  float* y3c = (float*)(Aq + 38400000);

  auto fqk = [&](const float* s, float* d, int n, SZ p) {
    kfq<<<dim3((n + 255) / 256), dim3(256), 0, stream>>>(s, d, n, p.s, p.z);
  };
  fqk(Wfc1, W1q, 102800, ZW1);
  fqk(Wfc2, W2q, 240000, ZWfc2); fqk(Wfc3, W3q, 360000, ZWfc3); fqk(Wfc4, W4q, 154200, ZWfc4);
  fqk(bfc1, b1q, 400, Zbfc1);
  fqk(bir1, biq + 0, 400, Zbir1);    fqk(biz1, biq + 400, 400, Zbiz1);  fqk(bin1, biq + 800, 400, Zbin1);
  fqk(bir2, biq + 1200, 400, Zbir2); fqk(biz2, biq + 1600, 400, Zbiz2); fqk(bin2, biq + 2000, 400, Zbin2);
  fqk(bhr1, bhq + 0, 400, Zbhr1);    fqk(bhz1, bhq + 400, 400, Zbhz1);  fqk(bhn1, bhq + 800, 400, Zbhn1);
  fqk(bhr2, bhq + 1200, 400, Zbhr2); fqk(bhz2, bhq + 1600, 400, Zbhz2); fqk(bhn2, bhq + 2000, 400, Zbhn2);
  fqk(bfc2, b2q, 600, Zbfc2); fqk(bfc3, b3q, 600, Zbfc3); fqk(bfc4, b4q, 257, Zbfc4);

  dim3 g625((160000 + 255) / 256);
  kwhc<<<g625, dim3(256), 0, stream>>>(Whr1, WhC + 0,      ZWhr1.s, ZWhr1.z);
  kwhc<<<g625, dim3(256), 0, stream>>>(Whz1, WhC + 160000, ZWhz1.s, ZWhz1.z);
  kwhc<<<g625, dim3(256), 0, stream>>>(Whn1, WhC + 320000, ZWhn1.s, ZWhn1.z);
  kwhc<<<g625, dim3(256), 0, stream>>>(Whr2, WhC + 480000, ZWhr2.s, ZWhr2.z);
  kwhc<<<g625, dim3(256), 0, stream>>>(Whz2, WhC + 640000, ZWhz2.s, ZWhz2.z);
  kwhc<<<g625, dim3(256), 0, stream>>>(Whn2, WhC + 800000, ZWhn2.s, ZWhn2.z);
  kcolsum<<<dim3(10), dim3(256), 0, stream>>>(WhC, colsum);
  unsigned code0 = (unsigned)(Zrnn.z < 0.f ? 0.f : (Zrnn.z > 255.f ? 255.f : Zrnn.z));
  kinit<<<dim3(25), dim3(256), 0, stream>>>(hpub1, hpub2, code0);

#ifdef HAVE_I8MFMA
  auto wic = [&](const float* W, int idx, SZ p) {
    kwic<<<dim3(2), dim3(256), 0, stream>>>(W, WiT + (size_t)idx * 400 * 464, cwi + idx * 400, p.s, p.z);
  };
  wic(Wir1, 0, ZWir1); wic(Wiz1, 1, ZWiz1); wic(Win1, 2, ZWin1);
  wic(Wir2, 3, ZWir2); wic(Wiz2, 4, ZWiz2); wic(Win2, 5, ZWin2);
#else
  fqk(Wir1, Wiq + 0,      160000, ZWir1); fqk(Wiz1, Wiq + 160000, 160000, ZWiz1);
  fqk(Win1, Wiq + 320000, 160000, ZWin1);
  fqk(Wir2, Wiq + 480000, 160000, ZWir2); fqk(Wiz2, Wiq + 640000, 160000, ZWiz2);
  fqk(Win2, Wiq + 800000, 160000, ZWin2);
#endif

  auto gemm = [&](const float* Af, const unsigned char* Au8, const float* B, const float* bias,
                  float* outF, unsigned char* outU8, int M, int N, int K,
                  int aMode, int epMode, int rowOff, SZ aSZ, SZ e1, SZ e2) {
    dim3 grid(M / 128, (N + 127) / 128);
    gemm_k<<<grid, dim3(256), 0, stream>>>(Af, Au8, B, bias, outF, outU8,
                                           M, N, K, aMode, epMode, rowOff,
                                           aSZ.s, aSZ.z, e1.s, e1.z, e2.s, e2.z);
  };
#ifdef HAVE_I8MFMA
  auto gi8 = [&](const unsigned char* A, const int* rs, int widx, const float* bias,
                 unsigned char* o, SZ a, SZ w, SZ e1, SZ e2) {
    int czw = 128 - (int)w.z, cza = 128 - (int)a.z;
    int cconst = 400 * cza * czw;
    gemm_i8<<<dim3(500, 5), dim3(256), 0, stream>>>(
        A, rs, WiT + (size_t)widx * 400 * 464, cwi + widx * 400, bias, o,
        czw, cza, cconst, a.s * w.s, e1.s, e1.z, e2.s, e2.z);
  };
#endif

  // ---- FC1: xs codes [T*64+b][400] ----
  gemm(x, nullptr, W1q, b1q, nullptr, xsq, 64000, 400, 257, 2, 0, 0, Zx, Zfc1mm, Zfc1add);

  // ---- GRU layer 1 input projections -> A/C/E codes ----
#ifdef HAVE_I8MFMA
  krsum<<<dim3(250), dim3(256), 0, stream>>>(xsq, rsX);
  gi8(xsq, rsX, 0, biq + 0,   Aq, Zfc1add, ZWir1, Za_1, Za1);
  gi8(xsq, rsX, 1, biq + 400, Cq, Zfc1add, ZWiz1, Zc_1, Zc1);
  gi8(xsq, rsX, 2, biq + 800, Eq, Zfc1add, ZWin1, Ze_1, Ze1);
#else
  gemm(nullptr, xsq, Wiq + 0,      biq + 0,   nullptr, Aq, 64000, 400, 400, 1, 0, 0, Zfc1add, Za_1, Za1);
  gemm(nullptr, xsq, Wiq + 160000, biq + 400, nullptr, Cq, 64000, 400, 400, 1, 0, 0, Zfc1add, Zc_1, Zc1);
  gemm(nullptr, xsq, Wiq + 320000, biq + 800, nullptr, Eq, 64000, 400, 400, 1, 0, 0, Zfc1add, Ze_1, Ze1);
#endif
  // ---- GRU layer 1 recurrence ----
  gru_rec<<<dim3(256), dim3(384), 0, stream>>>(WhC, colsum, Aq, Cq, Eq,
                                               bhq + 0, bhq + 400, bhq + 800,
                                               hs1, hpub1, PL1);
  // ---- GRU layer 2 input projections ----
#ifdef HAVE_I8MFMA
  krsum<<<dim3(250), dim3(256), 0, stream>>>(hs1, rsH);
  gi8(hs1, rsH, 3, biq + 1200, Aq, Zrnn, ZWir2, Za_2, Za2);
  gi8(hs1, rsH, 4, biq + 1600, Cq, Zrnn, ZWiz2, Zc_2, Zc2);
  gi8(hs1, rsH, 5, biq + 2000, Eq, Zrnn, ZWin2, Ze_2, Ze1);
#else
  gemm(nullptr, hs1, Wiq + 480000, biq + 1200, nullptr, Aq, 64000, 400, 400, 1, 0, 0, Zrnn, Za_2, Za2);
  gemm(nullptr, hs1, Wiq + 640000, biq + 1600, nullptr, Cq, 64000, 400, 400, 1, 0, 0, Zrnn, Zc_2, Zc2);
  gemm(nullptr, hs1, Wiq + 800000, biq + 2000, nullptr, Eq, 64000, 400, 400, 1, 0, 0, Zrnn, Ze_2, Ze1);
#endif
  // ---- GRU layer 2 recurrence ----
  gru_rec<<<dim3(256), dim3(384), 0, stream>>>(WhC + 480000, colsum + 1200, Aq, Cq, Eq,
                                               bhq + 1200, bhq + 1600, bhq + 2000,
                                               hs2, hpub2, PL2);
  // ---- FC2 -> FC3 -> FC4 in 4 row chunks ----
  for (int rc = 0; rc < 4; ++rc) {
    const unsigned char* a2 = hs2 + (size_t)rc * 16000 * 400;
    gemm(nullptr, a2, W2q, b2q, y2c, nullptr, 16000, 600, 400, 1, 2, 0, Zrnn, Zrnn, Zrnn);
    gemm(y2c, nullptr, W3q, b3q, y3c, nullptr, 16000, 600, 600, 0, 2, 0, Zrnn, Zrnn, Zrnn);
    gemm(y3c, nullptr, W4q, b4q, out, nullptr, 16000, 257, 600, 0, 3, rc * 16000, Zrnn, Zrnn, Zrnn);
  }
  (void)in_sizes; (void)n_in; (void)out_size; (void)ws_size;
}

// Round 5
// 8356.100 us; speedup vs baseline: 6.1002x; 1.2046x over previous
//
#include <hip/hip_runtime.h>
#include <math.h>

#define DEV static __device__ __forceinline__

typedef int v4i __attribute__((ext_vector_type(4)));

// ---------------- calibration (s, z) constants, computed like the reference ----------------
struct SZ { float s, z; };

constexpr double cfloor_(double v){ long long i=(long long)v; return ((double)i > v) ? (double)(i-1) : (double)i; }
constexpr double cround_(double v){            // round half-to-even (Python round / nearbyint)
  double fl = cfloor_(v); double fr = v - fl;
  return (fr > 0.5) ? fl + 1.0 : (fr < 0.5 ? fl : ((((long long)fl) & 1LL) == 0 ? fl : fl + 1.0));
}
constexpr SZ mksz(double mn, double mx){
  double s = (mx - mn) / 255.0;
  double z = cround_(-mn / s);
  return SZ{ (float)s, (float)z };
}

constexpr SZ Zx     = mksz(-0.0025095, 0.0022181);
constexpr SZ ZW1    = mksz(-0.22075387835502625, 0.208940327167511);
constexpr SZ Zfc1mm = mksz(-0.00291599917, 0.0017367251);
constexpr SZ Zbfc1  = mksz(-0.48688140511512756, 0.5176185369491577);
constexpr SZ Zfc1add= mksz(-0.48778465390205383, 0.5181604027748108);
// layer-1 weights/biases
constexpr SZ ZWiz1 = mksz(-0.43284985423088074, 0.46175122261047363);
constexpr SZ ZWir1 = mksz(-0.34401071071624756, 0.29191476106643677);
constexpr SZ ZWin1 = mksz(-0.3236880302429199, 0.39607325196266174);
constexpr SZ ZWhz1 = mksz(-1.8417714834213257, 1.7173254489898682);
constexpr SZ ZWhr1 = mksz(-1.1574513912200928, 1.0300449132919312);
constexpr SZ ZWhn1 = mksz(-0.7756922245025635, 0.9530389308929443);
constexpr SZ Zbiz1 = mksz(-0.5063393712043762, 0.36664387583732605);
constexpr SZ Zbir1 = mksz(-0.07920225709676743, 0.20611026883125305);
constexpr SZ Zbin1 = mksz(-0.5539973378181458, 0.17938342690467834);
constexpr SZ Zbhz1 = mksz(-0.5337516665458679, 0.4148772358894348);
constexpr SZ Zbhr1 = mksz(-0.07688436657190323, 0.14814253151416779);
constexpr SZ Zbhn1 = mksz(-0.7828555107116699, 0.9008108973503113);
// layer-2 weights/biases
constexpr SZ ZWiz2 = mksz(-0.9102030992507935, 0.9408696889877319);
constexpr SZ ZWir2 = mksz(-0.9560997486114502, 0.6683358550071716);
constexpr SZ ZWin2 = mksz(-0.4721935987472534, 0.48561596870422363);
constexpr SZ ZWhz2 = mksz(-1.2992678880691528, 1.2991048097610474);
constexpr SZ ZWhr2 = mksz(-0.8318714499473572, 1.1085889339447021);
constexpr SZ ZWhn2 = mksz(-0.955470085144043, 1.046797513961792);
constexpr SZ Zbiz2 = mksz(-0.44805487990379333, 0.1560053527355194);
constexpr SZ Zbir2 = mksz(-0.08767592161893845, 0.11347303539514542);
constexpr SZ Zbin2 = mksz(-0.239909827709198, 0.12033259868621826);
constexpr SZ Zbhz2 = mksz(-0.43745461106300354, 0.12699371576309204);
constexpr SZ Zbhr2 = mksz(-0.09617264568805695, 0.07690174877643585);
constexpr SZ Zbhn2 = mksz(-0.17204178869724274, 0.19739042222499847);
// fc tail
constexpr SZ ZWfc2 = mksz(-1.3657219409942627, 1.158295750617981);
constexpr SZ Zbfc2 = mksz(-0.1750922054052353, 0.1385071724653244);
constexpr SZ ZWfc3 = mksz(-3.1666038036346436, 2.5026357173919678);
constexpr SZ Zbfc3 = mksz(-0.10188056528568268, 0.0899151861667633);
constexpr SZ ZWfc4 = mksz(-1.300571084022522, 1.928941249847412);
constexpr SZ Zbfc4 = mksz(-0.10699586570262909, 0.04597663879394531);
// gru1 stages
constexpr SZ Za_1 = mksz(-0.6389939785003662, 0.7715625762939453);
constexpr SZ Za1  = mksz(-0.6046768426895142, 0.8871182203292847);
constexpr SZ Zb_1 = mksz(-0.004922409541904926, 0.004103424027562141);
constexpr SZ Zb1  = mksz(-0.07475128024816513, 0.14630259573459625);
constexpr SZ Zc_1 = mksz(-1.5660111904144287, 1.0454494953155518);
constexpr SZ Zc1  = mksz(-1.9779117107391357, 1.3700535297393799);
constexpr SZ Zd_1 = mksz(-0.008429044857621193, 0.006403823848813772);
constexpr SZ Zd1  = mksz(-0.5529640316963196, 0.41507571935653687);
constexpr SZ Ze_1 = mksz(-1.3637111186981201, 1.018247127532959);
constexpr SZ Ze1  = mksz(-1.8583884239196777, 1.1587692499160767);
constexpr SZ Zf_1 = mksz(-0.005411399528384209, 0.0061536869034171104);
constexpr SZ Zf1  = mksz(-0.7833794355392456, 0.8978855013847351);
constexpr SZ Zr_1 = mksz(-0.6226556301116943, 0.9800534844398499);
constexpr SZ Zr1  = mksz(0.3491777181625366, 0.7271188497543335);
constexpr SZ Zz_1 = mksz(-2.392332077026367, 1.7851293087005615);
constexpr SZ Zz1  = mksz(0.08375928550958633, 0.856329083442688);
constexpr SZ Zn11 = mksz(-0.5516456365585327, 0.4556601643562317);
constexpr SZ Zn21 = mksz(-2.4100341796875, 1.1423156261444092);
constexpr SZ Zn1  = mksz(-0.983996570110321, 0.8151924014091492);
constexpr SZ Zhn11= mksz(0.143670916557312, 0.9162406921386719);
constexpr SZ Zhn21= mksz(-0.9015777111053467, 0.45391541719436646);
constexpr SZ Zhn31= mksz(-0.0016954239690676332, 0.0016671211924403906);
constexpr SZ Zrnn = mksz(-0.9016271829605103, 0.4546271562576294);
// gru2 explicit entries (the rest fall back to gru1 values, incl. rnn2GRU)
constexpr SZ Za_2 = mksz(-0.681461751461029, 0.9113116264343262);
constexpr SZ Za2  = mksz(-0.7149235010147095, 0.908741295337677);
constexpr SZ Zb_2 = mksz(-0.005148397758603096, 0.011014967225492);
constexpr SZ Zb2g = mksz(-0.09436552226543427, 0.07623167335987091);
constexpr SZ Zc_2 = mksz(-1.2279887199401855, 1.1102137565612793);
constexpr SZ Zc2  = mksz(-1.6760436296463013, 1.200895071029663);
constexpr SZ Zd_2 = mksz(-0.008141756057739258, 0.00894666276872158);
constexpr SZ Zd2  = mksz(-0.43875735998153687, 0.1262134611606598);
constexpr SZ Ze_2 = mksz(-0.6732944250106812, 0.6314664483070374);

struct RecP {
  SZ wr, wz, wn;
  SZ a, c, e;
  SZ b1, b2, d1, d2, f1, f2;
  SZ r1, r2, z1, z2;
  SZ n1, n2, n3;
  SZ hn1, hn2, hn3, rnn;
};
constexpr RecP PL1 = { ZWhr1, ZWhz1, ZWhn1, Za1, Zc1, Ze1, Zb_1, Zb1, Zd_1, Zd1, Zf_1, Zf1,
                       Zr_1, Zr1, Zz_1, Zz1, Zn11, Zn21, Zn1, Zhn11, Zhn21, Zhn31, Zrnn };
constexpr RecP PL2 = { ZWhr2, ZWhz2, ZWhn2, Za2, Zc2, Ze1, Zb_2, Zb2g, Zd_2, Zd2, Zf_1, Zf1,
                       Zr_1, Zr1, Zz_1, Zz1, Zn11, Zn21, Zn1, Zhn11, Zhn21, Zhn31, Zrnn };

// ---------------- device helpers ----------------
DEV float fq_(float x, float s, float z){
  float q = rintf(x / s) + z;
  q = fminf(fmaxf(q, 0.f), 255.f);
  return (q - z) * s;
}
DEV float sigm_(float v){ return 1.f / (1.f + expf(-v)); }

DEV unsigned udot4_(unsigned a, unsigned b, unsigned c){
#if defined(__has_builtin) && __has_builtin(__builtin_amdgcn_udot4)
  return __builtin_amdgcn_udot4(a, b, c, false);
#else
  return c + (a & 255u) * (b & 255u) + ((a >> 8) & 255u) * ((b >> 8) & 255u)
           + ((a >> 16) & 255u) * ((b >> 16) & 255u) + (a >> 24) * (b >> 24);
#endif
}

// ---------------- prep kernels ----------------
__global__ __launch_bounds__(256) void kfq(const float* __restrict__ src, float* __restrict__ dst,
                                           int n, float s, float z){
  int i = blockIdx.x * 256 + threadIdx.x;
  if (i < n) dst[i] = fq_(src[i], s, z);
}
// Wh [400][400] (k-major) -> u8 codes, column-major [j][k]
__global__ __launch_bounds__(256) void kwhc(const float* __restrict__ W, unsigned char* __restrict__ dst,
                                            float s, float z){
  int i = blockIdx.x * 256 + threadIdx.x;
  if (i < 160000) {
    int j = i / 400, k = i - j * 400;
    float q = rintf(W[k * 400 + j] / s) + z;
    q = fminf(fmaxf(q, 0.f), 255.f);
    dst[i] = (unsigned char)q;
  }
}
__global__ __launch_bounds__(256) void kcolsum(const unsigned char* __restrict__ WhC, int* __restrict__ cs){
  int i = blockIdx.x * 256 + threadIdx.x;
  if (i < 2400) {
    const unsigned char* p = WhC + (size_t)i * 400;
    int s = 0;
    for (int k = 0; k < 400; ++k) s += p[k];
    cs[i] = s;
  }
}
// W [K][N] f32 -> transposed biased codes Bt [N][464] (code^0x80, pad biased-0) + colsum(q-128)
__global__ __launch_bounds__(256) void kwic(const float* __restrict__ W, signed char* __restrict__ Bt,
                                            int* __restrict__ cs, float s, float z, int K, int N){
  int total1 = K * N, total2 = (464 - K) * N;
  for (int idx = blockIdx.x * 256 + threadIdx.x; idx < total1; idx += gridDim.x * 256) {
    int k = idx / N, n = idx - k * N;
    float q = rintf(W[idx] / s) + z;
    q = fminf(fmaxf(q, 0.f), 255.f);
    int qi = (int)q;
    Bt[(size_t)n * 464 + k] = (signed char)(qi ^ 0x80);
    atomicAdd(&cs[n], qi - 128);
  }
  for (int idx = blockIdx.x * 256 + threadIdx.x; idx < total2; idx += gridDim.x * 256) {
    int n = idx / (464 - K), k = K + (idx - n * (464 - K));
    Bt[(size_t)n * 464 + k] = 0;
  }
}
// quantize x [B,T,F] -> xcq codes [T*64+b][464] (pads = code 128)
__global__ __launch_bounds__(256) void kxq(const float* __restrict__ x, unsigned char* __restrict__ xcq,
                                           float s, float z){
  int idx = blockIdx.x * 256 + threadIdx.x;
  if (idx < 64000 * 464) {
    int row = idx / 464, c = idx - row * 464;
    unsigned char code = 128;
    if (c < 257) {
      int bb = row & 63, tt = row >> 6;
      float q = rintf(x[((size_t)bb * 1000 + tt) * 257 + c] / s) + z;
      q = fminf(fmaxf(q, 0.f), 255.f);
      code = (unsigned char)q;
    }
    xcq[idx] = code;
  }
}
// per-row sums of (q-128) over w4 uint4-words of u8 codes (pads must be code 128)
__global__ __launch_bounds__(256) void krsum(const unsigned char* __restrict__ A, int* __restrict__ rs,
                                             int w4){
  int r = blockIdx.x * 256 + threadIdx.x;   // 64000 rows
  const unsigned* p = (const unsigned*)(A + (size_t)r * (w4 * 16));
  unsigned s = 0;
  for (int i = 0; i < w4 * 4; ++i) s = udot4_(p[i], 0x01010101u, s);
  rs[r] = (int)s - 128 * 4 * (w4 * 4);
}
// init tag-0 slot of both h-publish rings with h0 codes (tag in hi-32 = 0)
__global__ __launch_bounds__(256) void kinit(unsigned long long* __restrict__ hp1,
                                             unsigned long long* __restrict__ hp2, unsigned code){
  int i = blockIdx.x * 256 + threadIdx.x;
  if (i < 6400) {
    unsigned long long w = (unsigned long long)(code * 0x01010101u);
    hp1[i] = w; hp2[i] = w;
  }
}

// ---------------- exact-int i8 MFMA GEMM ----------------
// BM=64, BN=80, K padded to 448 (7 chunks of 64). A: u8 codes, row stride strideA bytes,
// aw4 real uint4/row (rest zero-staged). Bt: biased i8 [n][464]. 1-D grid, n-inner.
// dot_int = S + czw*RA' + cza*CW' + cconst; epMode 0: fq(e1)+bias -> u8(e2); 2: +bias,relu -> f32.
__global__ __launch_bounds__(256) void gemm_i8(
    const unsigned char* __restrict__ Au8, int strideA, int aw4,
    const int* __restrict__ rowsum,
    const signed char* __restrict__ Bt, const int* __restrict__ colsum,
    const float* __restrict__ bias,
    unsigned char* __restrict__ outU8, float* __restrict__ outF,
    int N, int nb, int outStride, int epMode,
    int czw, int cza, int cconst, float ss,
    float e1S, float e1Z, float e2S, float e2Z)
{
  __shared__ __align__(16) signed char Asl[64 * 464];
  __shared__ __align__(16) signed char Bsl[80 * 464];
  const int tid = threadIdx.x;
  const int bm = blockIdx.x / nb;
  const int bn = blockIdx.x - bm * nb;
  const int m0 = bm * 64;
  const int n0 = bn * 80;
  // stage B (zero rows beyond N)
  for (int i = tid; i < 80 * 29; i += 256) {
    int r = i / 29, c = i - r * 29;
    uint4 v;
    if (n0 + r < N) v = *(const uint4*)(Bt + (size_t)(n0 + r) * 464 + c * 16);
    else { v.x = 0u; v.y = 0u; v.z = 0u; v.w = 0u; }
    *(uint4*)(Bsl + (size_t)r * 464 + c * 16) = v;
  }
  // stage A (bias bytes; zero pads beyond aw4)
  for (int i = tid; i < 64 * 29; i += 256) {
    int r = i / 29, c = i - r * 29;
    uint4 v;
    if (c < aw4) {
      v = *(const uint4*)(Au8 + (size_t)(m0 + r) * strideA + c * 16);
      v.x ^= 0x80808080u; v.y ^= 0x80808080u; v.z ^= 0x80808080u; v.w ^= 0x80808080u;
    } else { v.x = 0u; v.y = 0u; v.z = 0u; v.w = 0u; }
    *(uint4*)(Asl + (size_t)r * 464 + c * 16) = v;
  }
  __syncthreads();
  const int wv = tid >> 6, ln = tid & 63;
  const int lr = ln & 15;
  const int lk = ln >> 4;
  v4i acc[5];
#pragma unroll
  for (int j = 0; j < 5; ++j) { acc[j][0] = 0; acc[j][1] = 0; acc[j][2] = 0; acc[j][3] = 0; }
#pragma unroll
  for (int kc = 0; kc < 7; ++kc) {
    int kb = kc * 64 + lk * 16;
    v4i a = *(const v4i*)(Asl + (size_t)(wv * 16 + lr) * 464 + kb);
#pragma unroll
    for (int j = 0; j < 5; ++j) {
      v4i b = *(const v4i*)(Bsl + (size_t)(j * 16 + lr) * 464 + kb);
      acc[j] = __builtin_amdgcn_mfma_i32_16x16x64_i8(a, b, acc[j], 0, 0, 0);
    }
  }
  // epilogue: D row=(lk*4+reg) (m-dim), col=lr (n-dim)
#pragma unroll
  for (int reg = 0; reg < 4; ++reg) {
    int row = m0 + wv * 16 + lk * 4 + reg;
    int RA = rowsum[row];
#pragma unroll
    for (int j = 0; j < 5; ++j) {
      int col = n0 + j * 16 + lr;
      if (col >= N) continue;
      int I = acc[j][reg] + czw * RA + cza * colsum[col] + cconst;
      float v = (float)I * ss;
      if (epMode == 0) {
        v = fq_(v, e1S, e1Z) + bias[col];
        float q = rintf(v / e2S) + e2Z;
        q = fminf(fmaxf(q, 0.f), 255.f);
        outU8[(size_t)row * outStride + col] = (unsigned char)q;
      } else {
        v += bias[col];
        v = fmaxf(v, 0.f);
        outF[(size_t)row * outStride + col] = v;
      }
    }
  }
}

// ---------------- tiled f32 GEMM with fused epilogues (FC3/FC4 only) ----------------
__global__ __launch_bounds__(256) void gemm_k(
    const float* __restrict__ Af,
    const float* __restrict__ B, const float* __restrict__ bias,
    float* __restrict__ outF,
    int M, int N, int K, int epMode, int rowOff)
{
  __shared__ __align__(16) float As[16][132];
  __shared__ __align__(16) float Bs[16][132];
  const int tid = threadIdx.x;
  const int m0 = blockIdx.x * 128;
  const int n0 = blockIdx.y * 128;
  const int tx = tid & 15, ty = tid >> 4;
  float acc[8][8];
#pragma unroll
  for (int i = 0; i < 8; ++i)
#pragma unroll
    for (int j = 0; j < 8; ++j) acc[i][j] = 0.f;

  const int kq = tid & 3;
  const int am = tid >> 2;
  const int bc = (tid & 31) * 4;
  const int br = tid >> 5;

  for (int k0 = 0; k0 < K; k0 += 16) {
#pragma unroll
    for (int it = 0; it < 2; ++it) {
      int mr = am + it * 64;
      int row = m0 + mr;
      int kk = k0 + kq * 4;
      float v0, v1, v2, v3;
      const float* p = Af + (size_t)row * K + kk;
      if (kk + 3 < K) { float4 f = *(const float4*)p; v0 = f.x; v1 = f.y; v2 = f.z; v3 = f.w; }
      else {
        v0 = (kk     < K) ? p[0] : 0.f; v1 = (kk + 1 < K) ? p[1] : 0.f;
        v2 = (kk + 2 < K) ? p[2] : 0.f; v3 = (kk + 3 < K) ? p[3] : 0.f;
      }
      As[kq * 4 + 0][mr] = v0; As[kq * 4 + 1][mr] = v1;
      As[kq * 4 + 2][mr] = v2; As[kq * 4 + 3][mr] = v3;
    }
#pragma unroll
    for (int it = 0; it < 2; ++it) {
      int rr = br + it * 8;
      int k = k0 + rr;
      int c = n0 + bc;
      float v0 = 0.f, v1 = 0.f, v2 = 0.f, v3 = 0.f;
      if (k < K) {
        const float* p = B + (size_t)k * N + c;
        if (((N & 3) == 0) && (c + 3 < N)) { float4 f = *(const float4*)p; v0 = f.x; v1 = f.y; v2 = f.z; v3 = f.w; }
        else {
          if (c     < N) v0 = p[0];
          if (c + 1 < N) v1 = p[1];
          if (c + 2 < N) v2 = p[2];
          if (c + 3 < N) v3 = p[3];
        }
      }
      float4 f4; f4.x = v0; f4.y = v1; f4.z = v2; f4.w = v3;
      *(float4*)&Bs[rr][bc] = f4;
    }
    __syncthreads();
#pragma unroll
    for (int kk = 0; kk < 16; ++kk) {
      float a_[8], b_[8];
      *(float4*)&a_[0] = *(const float4*)&As[kk][ty * 8];
      *(float4*)&a_[4] = *(const float4*)&As[kk][ty * 8 + 4];
      *(float4*)&b_[0] = *(const float4*)&Bs[kk][tx * 8];
      *(float4*)&b_[4] = *(const float4*)&Bs[kk][tx * 8 + 4];
#pragma unroll
      for (int i = 0; i < 8; ++i)
#pragma unroll
        for (int j = 0; j < 8; ++j) acc[i][j] = fmaf(a_[i], b_[j], acc[i][j]);
    }
    __syncthreads();
  }
#pragma unroll
  for (int i = 0; i < 8; ++i) {
    int row = m0 + ty * 8 + i;
#pragma unroll
    for (int j = 0; j < 8; ++j) {
      int col = n0 + tx * 8 + j;
      if (col >= N) continue;
      float v = acc[i][j];
      if (epMode == 2) {
        v += bias[col];
        v = fmaxf(v, 0.f);
        outF[(size_t)row * N + col] = v;
      } else {
        v += bias[col];
        v = sigm_(v);
        int rg = rowOff + row;
        int tt = rg >> 6, bb = rg & 63;
        outF[((size_t)bb * 1000 + tt) * 257 + col] = v;
      }
    }
  }
}

// ---------------- GRU recurrence (comm wave owns all global traffic) ----------------
__global__ __launch_bounds__(384) void gru_rec(
    const unsigned char* __restrict__ WhC, const int* __restrict__ colsum,
    const unsigned char* __restrict__ Aq, const unsigned char* __restrict__ Cq,
    const unsigned char* __restrict__ Eq,
    const float* __restrict__ bhr, const float* __restrict__ bhz, const float* __restrict__ bhn,
    unsigned char* __restrict__ hs,
    unsigned long long* hpub, RecP P)
{
  __shared__ __align__(16) uint4 Wlds[9600];
  __shared__ __align__(16) uint4 hq_own[7];
  __shared__ __align__(16) uint4 hqr[21];
  __shared__ float dots[2][3][100];
  __shared__ unsigned aceb[75];
  __shared__ int HqS_s;
  __shared__ int flag;

  const int tid = threadIdx.x;
  const int wv  = tid >> 6;
  const int ln  = tid & 63;
  const int b   = blockIdx.x & 63;
  const int sl  = blockIdx.x >> 6;
  const int jbase = sl * 100;

  unsigned* Wled = (unsigned*)Wlds;
  unsigned* hqow = (unsigned*)hq_own;
  unsigned* hqrw = (unsigned*)hqr;

  for (int idx = tid; idx < 30000; idx += 384) {
    int cid0 = idx / 100, w = idx - cid0 * 100;
    int c = w / 25, p = w - c * 25;
    int g0 = cid0 / 100, jj0 = cid0 - g0 * 100;
    unsigned word = ((const unsigned*)(WhC + ((size_t)(g0 * 400) + jbase + jj0) * 400))[w];
    int slot = (c * 7 + (p >> 2)) ^ (cid0 & 31);
    Wled[cid0 * 128 + slot * 4 + (p & 3)] = word;
  }
  for (int idx = tid; idx < 3600; idx += 384) {
    int cid0 = idx / 12, r = idx - cid0 * 12;
    int c = r / 3, wd = r - c * 3 + 1;
    int slot = (c * 7 + 6) ^ (cid0 & 31);
    Wled[cid0 * 128 + slot * 4 + wd] = 0u;
  }
  const unsigned code0 = (unsigned)fminf(fmaxf(P.rnn.z, 0.f), 255.f);
  if (tid < 28) hqow[tid] = (tid < 25) ? code0 * 0x01010101u : 0u;
  if (tid >= 32 && tid < 41) {
    int r = tid - 32; int o = r / 3, wd = r - o * 3 + 1;
    hqrw[o * 28 + 24 + wd] = 0u;
  }
  if (tid == 383) flag = -1;

  const int cid = tid;
  int g = cid / 100;
  int jj = cid - g * 100;
  float s1S = 1.f, s1Z = 0.f, s2S = 1.f, s2Z = 0.f, biasj = 0.f, swsh = 0.f;
  int zwi = 0, CSj = 0;
  if (tid < 300) {
    int j = jbase + jj;
    SZ w  = (g == 0) ? P.wr : (g == 1) ? P.wz : P.wn;
    SZ s1 = (g == 0) ? P.b1 : (g == 1) ? P.d1 : P.f1;
    SZ s2 = (g == 0) ? P.b2 : (g == 1) ? P.d2 : P.f2;
    zwi = (int)w.z;
    s1S = s1.s; s1Z = s1.z; s2S = s2.s; s2Z = s2.z;
    biasj = ((g == 0) ? bhr : (g == 1) ? bhz : bhn)[j];
    CSj = colsum[g * 400 + j];
    swsh = w.s * P.rnn.s;
  }
  const int zhi = (int)P.rnn.z;
  const int swm = cid & 31;

  unsigned hprev = code0;
  __syncthreads();

  for (int t = 0; t < 1000; ++t) {
    if (wv == 5) {
      size_t row = (size_t)t * 64 + b;
      int w0 = ln, w1 = 64 + ln;
      int wh0 = w0 / 25, wi0 = w0 - wh0 * 25;
      const unsigned char* p0 = (wh0 == 0) ? Aq : (wh0 == 1) ? Cq : Eq;
      unsigned v0 = *(const unsigned*)(p0 + row * 400 + jbase + wi0 * 4);
      unsigned v1 = 0;
      if (ln < 11) {
        int wh1 = w1 / 25, wi1 = w1 - wh1 * 25;
        const unsigned char* p1 = (wh1 == 0) ? Aq : (wh1 == 1) ? Cq : Eq;
        v1 = *(const unsigned*)(p1 + row * 400 + jbase + wi1 * 4);
      }
      const unsigned long long* base = hpub + ((size_t)(t & 3) * 64 + b) * 100;
      unsigned pay0, pay1 = 0;
      {
        int o = ln / 25, p = ln - o * 25;
        int so = (sl + o + 1) & 3;
        const unsigned long long* src = base + so * 25 + p;
        unsigned long long w64;
        while ((unsigned)((w64 = __hip_atomic_load(src, __ATOMIC_RELAXED, __HIP_MEMORY_SCOPE_AGENT)) >> 32)
               != (unsigned)t) { }
        pay0 = (unsigned)w64;
        hqrw[o * 28 + ((p >> 2) * 4) + (p & 3)] = pay0;
      }
      if (ln < 11) {
        int widx = 64 + ln;
        int o = widx / 25, p = widx - o * 25;
        int so = (sl + o + 1) & 3;
        const unsigned long long* src = base + so * 25 + p;
        unsigned long long w64;
        while ((unsigned)((w64 = __hip_atomic_load(src, __ATOMIC_RELAXED, __HIP_MEMORY_SCOPE_AGENT)) >> 32)
               != (unsigned)t) { }
        pay1 = (unsigned)w64;
        hqrw[o * 28 + ((p >> 2) * 4) + (p & 3)] = pay1;
      }
      unsigned hp = udot4_(pay0, 0x01010101u, 0u);
      if (ln < 11) hp = udot4_(pay1, 0x01010101u, hp);
      if (ln < 25) hp = udot4_(hqow[ln], 0x01010101u, hp);
#pragma unroll
      for (int off = 32; off; off >>= 1) hp += __shfl_down(hp, off, 64);
      if (ln == 0) HqS_s = (int)hp;
      __hip_atomic_store(&flag, t, __ATOMIC_RELEASE, __HIP_MEMORY_SCOPE_WORKGROUP);
      aceb[ln] = v0;
      if (ln < 11) aceb[64 + ln] = v1;
      if (t > 0 && ln < 25)
        *(unsigned*)(hs + ((size_t)(t - 1) * 64 + b) * 400 + jbase + ln * 4) = hqow[ln];
    } else if (tid < 300) {
      unsigned acc = 0;
      const uint4* wcol = &Wlds[cid * 32];
#pragma unroll
      for (int i = 0; i < 7; ++i) {
        uint4 h = hq_own[i];
        uint4 w = wcol[(sl * 7 + i) ^ swm];
        acc = udot4_(w.x, h.x, acc);
        acc = udot4_(w.y, h.y, acc);
        acc = udot4_(w.z, h.z, acc);
        acc = udot4_(w.w, h.w, acc);
      }
      while (__hip_atomic_load(&flag, __ATOMIC_ACQUIRE, __HIP_MEMORY_SCOPE_WORKGROUP) < t)
        __builtin_amdgcn_s_sleep(1);
#pragma unroll
      for (int o = 0; o < 3; ++o) {
        int c = (sl + o + 1) & 3;
#pragma unroll
        for (int i = 0; i < 7; ++i) {
          uint4 h = hqr[o * 7 + i];
          uint4 w = wcol[(c * 7 + i) ^ swm];
          acc = udot4_(w.x, h.x, acc);
          acc = udot4_(w.y, h.y, acc);
          acc = udot4_(w.z, h.z, acc);
          acc = udot4_(w.w, h.w, acc);
        }
      }
      int I = (int)acc - zwi * HqS_s - zhi * CSj + 400 * zhi * zwi;
      float dot = (float)I * swsh;
      float v = fq_(dot, s1S, s1Z) + biasj;
      v = fq_(v, s2S, s2Z);
      dots[t & 1][g][jj] = v;
    }
    __syncthreads();
    if (tid < 128) {
      int m = (tid < 100) ? tid : 99;
      const unsigned char* aceb8 = (const unsigned char*)aceb;
      float a = ((float)aceb8[m]       - P.a.z) * P.a.s;
      float c = ((float)aceb8[100 + m] - P.c.z) * P.c.s;
      float e = ((float)aceb8[200 + m] - P.e.z) * P.e.s;
      float bb = dots[t & 1][0][m], dd = dots[t & 1][1][m], ff = dots[t & 1][2][m];
      float r  = fq_(sigm_(fq_(a + bb, P.r1.s, P.r1.z)), P.r2.s, P.r2.z);
      float zz = fq_(sigm_(fq_(c + dd, P.z1.s, P.z1.z)), P.z2.s, P.z2.z);
      float nn = fq_(tanhf(fq_(e + fq_(r * ff, P.n1.s, P.n1.z), P.n2.s, P.n2.z)), P.n3.s, P.n3.z);
      float hold = ((float)hprev - P.rnn.z) * P.rnn.s;
      float hn2v = fq_(fq_(1.f - zz, P.hn1.s, P.hn1.z) * nn, P.hn2.s, P.hn2.z);
      float hn3v = fq_(zz * hold, P.hn3.s, P.hn3.z);
      float hnew = hn2v + hn3v;
      float q = rintf(hnew / P.rnn.s) + P.rnn.z;
      q = fminf(fmaxf(q, 0.f), 255.f);
      unsigned code = (unsigned)q;
      unsigned c1 = __shfl_down(code, 1);
      unsigned c2 = __shfl_down(code, 2);
      unsigned c3 = __shfl_down(code, 3);
      if (tid < 100) {
        if ((tid & 3) == 0) {
          unsigned packed = code | (c1 << 8) | (c2 << 16) | (c3 << 24);
          unsigned long long out64 = ((unsigned long long)(unsigned)(t + 1) << 32) | packed;
          unsigned long long* dst = hpub + ((size_t)((t + 1) & 3) * 64 + b) * 100 + sl * 25 + (tid >> 2);
          __hip_atomic_store(dst, out64, __ATOMIC_RELAXED, __HIP_MEMORY_SCOPE_AGENT);
          hqow[tid >> 2] = packed;
        }
        hprev = code;
      }
    }
    __syncthreads();
  }
  if (wv == 5 && ln < 25)
    *(unsigned*)(hs + ((size_t)999 * 64 + b) * 400 + jbase + ln * 4) = hqow[ln];
}

// ---------------- host launch ----------------
extern "C" void kernel_launch(void* const* d_in, const int* in_sizes, int n_in,
                              void* d_out, int out_size, void* d_ws, size_t ws_size,
                              hipStream_t stream)
{
  const float* x    = (const float*)d_in[0];
  const float* Wfc1 = (const float*)d_in[1];
  const float* bfc1 = (const float*)d_in[2];
  const float* Wiz1 = (const float*)d_in[3];  const float* Whz1 = (const float*)d_in[4];
  const float* biz1 = (const float*)d_in[5];  const float* bhz1 = (const float*)d_in[6];
  const float* Wir1 = (const float*)d_in[7];  const float* Whr1 = (const float*)d_in[8];
  const float* bir1 = (const float*)d_in[9];  const float* bhr1 = (const float*)d_in[10];
  const float* Win1 = (const float*)d_in[11]; const float* Whn1 = (const float*)d_in[12];
  const float* bin1 = (const float*)d_in[13]; const float* bhn1 = (const float*)d_in[14];
  const float* Wiz2 = (const float*)d_in[15]; const float* Whz2 = (const float*)d_in[16];
  const float* biz2 = (const float*)d_in[17]; const float* bhz2 = (const float*)d_in[18];
  const float* Wir2 = (const float*)d_in[19]; const float* Whr2 = (const float*)d_in[20];
  const float* bir2 = (const float*)d_in[21]; const float* bhr2 = (const float*)d_in[22];
  const float* Win2 = (const float*)d_in[23]; const float* Whn2 = (const float*)d_in[24];
  const float* bin2 = (const float*)d_in[25]; const float* bhn2 = (const float*)d_in[26];
  const float* Wfc2 = (const float*)d_in[27]; const float* bfc2 = (const float*)d_in[28];
  const float* Wfc3 = (const float*)d_in[29]; const float* bfc3 = (const float*)d_in[30];
  const float* Wfc4 = (const float*)d_in[31]; const float* bfc4 = (const float*)d_in[32];
  float* out = (float*)d_out;

  char* wp = (char*)d_ws;
  auto alloc = [&](size_t bytes) -> void* {
    void* p = (void*)wp;
    wp += (bytes + 255) & ~(size_t)255;
    return p;
  };
  float* W3q = (float*)alloc(360000 * 4);
  float* W4q = (float*)alloc(154200 * 4);
  float* b1q = (float*)alloc(400 * 4);
  float* biq = (float*)alloc(2400 * 4);
  float* bhq = (float*)alloc(2400 * 4);
  float* b2q = (float*)alloc(600 * 4);
  float* b3q = (float*)alloc(600 * 4);
  float* b4q = (float*)alloc(257 * 4);
  unsigned char* WhC = (unsigned char*)alloc(960000);
  int* colsum = (int*)alloc(2400 * 4);
  signed char* WiT = (signed char*)alloc(7 * 400 * 464);  // 6 proj + W1
  signed char* Bt2 = (signed char*)alloc(600 * 464);      // W2
  int* cwi = (int*)alloc((7 * 400 + 600) * 4);            // colsums: [0..5]*400 proj, 6*400 W1, 2800+ W2
  int* rsX1 = (int*)alloc(64000 * 4);                     // xcq rowsums
  int* rsX  = (int*)alloc(64000 * 4);                     // xsq rowsums
  int* rsH  = (int*)alloc(64000 * 4);                     // hs1 rowsums
  int* rsH2 = (int*)alloc(64000 * 4);                     // hs2 rowsums
  unsigned char* xsq = (unsigned char*)alloc(25600000);
  unsigned char* Aq  = (unsigned char*)alloc(25600000);
  unsigned char* Cq  = (unsigned char*)alloc(25600000);
  unsigned char* Eq  = (unsigned char*)alloc(25600000);
  unsigned char* hs1 = (unsigned char*)alloc(25600000);
  unsigned char* hs2 = (unsigned char*)alloc(25600000);
  unsigned long long* hpub1 = (unsigned long long*)alloc(4 * 64 * 100 * 8);
  unsigned long long* hpub2 = (unsigned long long*)alloc(4 * 64 * 100 * 8);
  // overlays on dead regions
  float* y2c = (float*)Aq;                       // FC chain chunk buffers (A/C/E dead then)
  float* y3c = (float*)(Aq + 38400000);
  unsigned char* xcq = hs1;                      // x codes [64000][464] (hs1/hs2 dead pre-rec1)

  auto fqk = [&](const float* s, float* d, int n, SZ p) {
    kfq<<<dim3((n + 255) / 256), dim3(256), 0, stream>>>(s, d, n, p.s, p.z);
  };
  fqk(Wfc3, W3q, 360000, ZWfc3); fqk(Wfc4, W4q, 154200, ZWfc4);
  fqk(bfc1, b1q, 400, Zbfc1);
  fqk(bir1, biq + 0, 400, Zbir1);    fqk(biz1, biq + 400, 400, Zbiz1);  fqk(bin1, biq + 800, 400, Zbin1);
  fqk(bir2, biq + 1200, 400, Zbir2); fqk(biz2, biq + 1600, 400, Zbiz2); fqk(bin2, biq + 2000, 400, Zbin2);
  fqk(bhr1, bhq + 0, 400, Zbhr1);    fqk(bhz1, bhq + 400, 400, Zbhz1);  fqk(bhn1, bhq + 800, 400, Zbhn1);
  fqk(bhr2, bhq + 1200, 400, Zbhr2); fqk(bhz2, bhq + 1600, 400, Zbhz2); fqk(bhn2, bhq + 2000, 400, Zbhn2);
  fqk(bfc2, b2q, 600, Zbfc2); fqk(bfc3, b3q, 600, Zbfc3); fqk(bfc4, b4q, 257, Zbfc4);

  dim3 g625((160000 + 255) / 256);
  kwhc<<<g625, dim3(256), 0, stream>>>(Whr1, WhC + 0,      ZWhr1.s, ZWhr1.z);
  kwhc<<<g625, dim3(256), 0, stream>>>(Whz1, WhC + 160000, ZWhz1.s, ZWhz1.z);
  kwhc<<<g625, dim3(256), 0, stream>>>(Whn1, WhC + 320000, ZWhn1.s, ZWhn1.z);
  kwhc<<<g625, dim3(256), 0, stream>>>(Whr2, WhC + 480000, ZWhr2.s, ZWhr2.z);
  kwhc<<<g625, dim3(256), 0, stream>>>(Whz2, WhC + 640000, ZWhz2.s, ZWhz2.z);
  kwhc<<<g625, dim3(256), 0, stream>>>(Whn2, WhC + 800000, ZWhn2.s, ZWhn2.z);
  kcolsum<<<dim3(10), dim3(256), 0, stream>>>(WhC, colsum);
  unsigned code0 = (unsigned)(Zrnn.z < 0.f ? 0.f : (Zrnn.z > 255.f ? 255.f : Zrnn.z));
  kinit<<<dim3(25), dim3(256), 0, stream>>>(hpub1, hpub2, code0);

  // weight codes for the i8 GEMMs
  hipMemsetAsync(cwi, 0, (7 * 400 + 600) * 4, stream);
  auto wic = [&](const float* W, signed char* Bt, int* cs, SZ p, int K, int N) {
    kwic<<<dim3(625), dim3(256), 0, stream>>>(W, Bt, cs, p.s, p.z, K, N);
  };
  wic(Wir1, WiT + (size_t)0 * 185600, cwi + 0,    ZWir1, 400, 400);
  wic(Wiz1, WiT + (size_t)1 * 185600, cwi + 400,  ZWiz1, 400, 400);
  wic(Win1, WiT + (size_t)2 * 185600, cwi + 800,  ZWin1, 400, 400);
  wic(Wir2, WiT + (size_t)3 * 185600, cwi + 1200, ZWir2, 400, 400);
  wic(Wiz2, WiT + (size_t)4 * 185600, cwi + 1600, ZWiz2, 400, 400);
  wic(Win2, WiT + (size_t)5 * 185600, cwi + 2000, ZWin2, 400, 400);
  wic(Wfc1, WiT + (size_t)6 * 185600, cwi + 2400, ZW1,   257, 400);
  wic(Wfc2, Bt2,                      cwi + 2800, ZWfc2, 400, 600);

  auto gi8 = [&](const unsigned char* A, int strideA, int aw4, const int* rs,
                 const signed char* Bt, const int* cs, const float* bias,
                 unsigned char* oU8, float* oF, int M, int N, int outStride, int epMode,
                 SZ a, SZ w, int Kreal, float ss, SZ e1, SZ e2) {
    int czw = 128 - (int)w.z, cza = 128 - (int)a.z;
    int cconst = Kreal * cza * czw;
    int nb = (N + 79) / 80;
    gemm_i8<<<dim3((M / 64) * nb), dim3(256), 0, stream>>>(
        A, strideA, aw4, rs, Bt, cs, bias, oU8, oF, N, nb, outStride, epMode,
        czw, cza, cconst, ss, e1.s, e1.z, e2.s, e2.z);
  };

  // ---- FC1 (exact-int i8): x codes -> xsq codes ----
  kxq<<<dim3((64000 * 464 + 255) / 256), dim3(256), 0, stream>>>(x, xcq, Zx.s, Zx.z);
  krsum<<<dim3(250), dim3(256), 0, stream>>>(xcq, rsX1, 29);
  gi8(xcq, 464, 29, rsX1, WiT + (size_t)6 * 185600, cwi + 2400, b1q,
      xsq, nullptr, 64000, 400, 400, 0, Zx, ZW1, 257, Zx.s * ZW1.s, Zfc1mm, Zfc1add);

  // ---- GRU layer 1 input projections (i8) ----
  krsum<<<dim3(250), dim3(256), 0, stream>>>(xsq, rsX, 25);
  gi8(xsq, 400, 25, rsX, WiT + (size_t)0 * 185600, cwi + 0,    biq + 0,   Aq, nullptr,
      64000, 400, 400, 0, Zfc1add, ZWir1, 400, Zfc1add.s * ZWir1.s, Za_1, Za1);
  gi8(xsq, 400, 25, rsX, WiT + (size_t)1 * 185600, cwi + 400,  biq + 400, Cq, nullptr,
      64000, 400, 400, 0, Zfc1add, ZWiz1, 400, Zfc1add.s * ZWiz1.s, Zc_1, Zc1);
  gi8(xsq, 400, 25, rsX, WiT + (size_t)2 * 185600, cwi + 800,  biq + 800, Eq, nullptr,
      64000, 400, 400, 0, Zfc1add, ZWin1, 400, Zfc1add.s * ZWin1.s, Ze_1, Ze1);
  // ---- GRU layer 1 recurrence ----
  gru_rec<<<dim3(256), dim3(384), 0, stream>>>(WhC, colsum, Aq, Cq, Eq,
                                               bhq + 0, bhq + 400, bhq + 800,
                                               hs1, hpub1, PL1);
  // ---- GRU layer 2 input projections (i8) ----
  krsum<<<dim3(250), dim3(256), 0, stream>>>(hs1, rsH, 25);
  gi8(hs1, 400, 25, rsH, WiT + (size_t)3 * 185600, cwi + 1200, biq + 1200, Aq, nullptr,
      64000, 400, 400, 0, Zrnn, ZWir2, 400, Zrnn.s * ZWir2.s, Za_2, Za2);
  gi8(hs1, 400, 25, rsH, WiT + (size_t)4 * 185600, cwi + 1600, biq + 1600, Cq, nullptr,
      64000, 400, 400, 0, Zrnn, ZWiz2, 400, Zrnn.s * ZWiz2.s, Zc_2, Zc2);
  gi8(hs1, 400, 25, rsH, WiT + (size_t)5 * 185600, cwi + 2000, biq + 2000, Eq, nullptr,
      64000, 400, 400, 0, Zrnn, ZWin2, 400, Zrnn.s * ZWin2.s, Ze_2, Ze1);
  // ---- GRU layer 2 recurrence ----
  gru_rec<<<dim3(256), dim3(384), 0, stream>>>(WhC + 480000, colsum + 1200, Aq, Cq, Eq,
                                               bhq + 1200, bhq + 1600, bhq + 2000,
                                               hs2, hpub2, PL2);
  // ---- FC2 (i8) -> FC3 -> FC4 (f32) in 4 row chunks ----
  krsum<<<dim3(250), dim3(256), 0, stream>>>(hs2, rsH2, 25);
  for (int rc = 0; rc < 4; ++rc) {
    const unsigned char* a2 = hs2 + (size_t)rc * 16000 * 400;
    gi8(a2, 400, 25, rsH2 + rc * 16000, Bt2, cwi + 2800, b2q, nullptr, y2c,
        16000, 600, 600, 2, Zrnn, ZWfc2, 400, Zrnn.s * ZWfc2.s, Zrnn, Zrnn);
    gemm_k<<<dim3(125, 5), dim3(256), 0, stream>>>(y2c, W3q, b3q, y3c, 16000, 600, 600, 2, 0);
    gemm_k<<<dim3(125, 3), dim3(256), 0, stream>>>(y3c, W4q, b4q, out, 16000, 257, 600, 3, rc * 16000);
  }
  (void)in_sizes; (void)n_in; (void)out_size; (void)ws_size;
}

// Round 6
// 7342.952 us; speedup vs baseline: 6.9419x; 1.1380x over previous
//
#include <hip/hip_runtime.h>
#include <math.h>

#define DEV static __device__ __forceinline__

typedef int v4i __attribute__((ext_vector_type(4)));
typedef float v4f __attribute__((ext_vector_type(4)));
typedef __bf16 bf16_t;
typedef __bf16 v8bf __attribute__((ext_vector_type(8)));

// ---------------- calibration (s, z) constants, computed like the reference ----------------
struct SZ { float s, z; };

constexpr double cfloor_(double v){ long long i=(long long)v; return ((double)i > v) ? (double)(i-1) : (double)i; }
constexpr double cround_(double v){            // round half-to-even (Python round / nearbyint)
  double fl = cfloor_(v); double fr = v - fl;
  return (fr > 0.5) ? fl + 1.0 : (fr < 0.5 ? fl : ((((long long)fl) & 1LL) == 0 ? fl : fl + 1.0));
}
constexpr SZ mksz(double mn, double mx){
  double s = (mx - mn) / 255.0;
  double z = cround_(-mn / s);
  return SZ{ (float)s, (float)z };
}

constexpr SZ Zx     = mksz(-0.0025095, 0.0022181);
constexpr SZ ZW1    = mksz(-0.22075387835502625, 0.208940327167511);
constexpr SZ Zfc1mm = mksz(-0.00291599917, 0.0017367251);
constexpr SZ Zbfc1  = mksz(-0.48688140511512756, 0.5176185369491577);
constexpr SZ Zfc1add= mksz(-0.48778465390205383, 0.5181604027748108);
// layer-1 weights/biases
constexpr SZ ZWiz1 = mksz(-0.43284985423088074, 0.46175122261047363);
constexpr SZ ZWir1 = mksz(-0.34401071071624756, 0.29191476106643677);
constexpr SZ ZWin1 = mksz(-0.3236880302429199, 0.39607325196266174);
constexpr SZ ZWhz1 = mksz(-1.8417714834213257, 1.7173254489898682);
constexpr SZ ZWhr1 = mksz(-1.1574513912200928, 1.0300449132919312);
constexpr SZ ZWhn1 = mksz(-0.7756922245025635, 0.9530389308929443);
constexpr SZ Zbiz1 = mksz(-0.5063393712043762, 0.36664387583732605);
constexpr SZ Zbir1 = mksz(-0.07920225709676743, 0.20611026883125305);
constexpr SZ Zbin1 = mksz(-0.5539973378181458, 0.17938342690467834);
constexpr SZ Zbhz1 = mksz(-0.5337516665458679, 0.4148772358894348);
constexpr SZ Zbhr1 = mksz(-0.07688436657190323, 0.14814253151416779);
constexpr SZ Zbhn1 = mksz(-0.7828555107116699, 0.9008108973503113);
// layer-2 weights/biases
constexpr SZ ZWiz2 = mksz(-0.9102030992507935, 0.9408696889877319);
constexpr SZ ZWir2 = mksz(-0.9560997486114502, 0.6683358550071716);
constexpr SZ ZWin2 = mksz(-0.4721935987472534, 0.48561596870422363);
constexpr SZ ZWhz2 = mksz(-1.2992678880691528, 1.2991048097610474);
constexpr SZ ZWhr2 = mksz(-0.8318714499473572, 1.1085889339447021);
constexpr SZ ZWhn2 = mksz(-0.955470085144043, 1.046797513961792);
constexpr SZ Zbiz2 = mksz(-0.44805487990379333, 0.1560053527355194);
constexpr SZ Zbir2 = mksz(-0.08767592161893845, 0.11347303539514542);
constexpr SZ Zbin2 = mksz(-0.239909827709198, 0.12033259868621826);
constexpr SZ Zbhz2 = mksz(-0.43745461106300354, 0.12699371576309204);
constexpr SZ Zbhr2 = mksz(-0.09617264568805695, 0.07690174877643585);
constexpr SZ Zbhn2 = mksz(-0.17204178869724274, 0.19739042222499847);
// fc tail
constexpr SZ ZWfc2 = mksz(-1.3657219409942627, 1.158295750617981);
constexpr SZ Zbfc2 = mksz(-0.1750922054052353, 0.1385071724653244);
constexpr SZ ZWfc3 = mksz(-3.1666038036346436, 2.5026357173919678);
constexpr SZ Zbfc3 = mksz(-0.10188056528568268, 0.0899151861667633);
constexpr SZ ZWfc4 = mksz(-1.300571084022522, 1.928941249847412);
constexpr SZ Zbfc4 = mksz(-0.10699586570262909, 0.04597663879394531);
// gru1 stages
constexpr SZ Za_1 = mksz(-0.6389939785003662, 0.7715625762939453);
constexpr SZ Za1  = mksz(-0.6046768426895142, 0.8871182203292847);
constexpr SZ Zb_1 = mksz(-0.004922409541904926, 0.004103424027562141);
constexpr SZ Zb1  = mksz(-0.07475128024816513, 0.14630259573459625);
constexpr SZ Zc_1 = mksz(-1.5660111904144287, 1.0454494953155518);
constexpr SZ Zc1  = mksz(-1.9779117107391357, 1.3700535297393799);
constexpr SZ Zd_1 = mksz(-0.008429044857621193, 0.006403823848813772);
constexpr SZ Zd1  = mksz(-0.5529640316963196, 0.41507571935653687);
constexpr SZ Ze_1 = mksz(-1.3637111186981201, 1.018247127532959);
constexpr SZ Ze1  = mksz(-1.8583884239196777, 1.1587692499160767);
constexpr SZ Zf_1 = mksz(-0.005411399528384209, 0.0061536869034171104);
constexpr SZ Zf1  = mksz(-0.7833794355392456, 0.8978855013847351);
constexpr SZ Zr_1 = mksz(-0.6226556301116943, 0.9800534844398499);
constexpr SZ Zr1  = mksz(0.3491777181625366, 0.7271188497543335);
constexpr SZ Zz_1 = mksz(-2.392332077026367, 1.7851293087005615);
constexpr SZ Zz1  = mksz(0.08375928550958633, 0.856329083442688);
constexpr SZ Zn11 = mksz(-0.5516456365585327, 0.4556601643562317);
constexpr SZ Zn21 = mksz(-2.4100341796875, 1.1423156261444092);
constexpr SZ Zn1  = mksz(-0.983996570110321, 0.8151924014091492);
constexpr SZ Zhn11= mksz(0.143670916557312, 0.9162406921386719);
constexpr SZ Zhn21= mksz(-0.9015777111053467, 0.45391541719436646);
constexpr SZ Zhn31= mksz(-0.0016954239690676332, 0.0016671211924403906);
constexpr SZ Zrnn = mksz(-0.9016271829605103, 0.4546271562576294);
// gru2 explicit entries (the rest fall back to gru1 values, incl. rnn2GRU)
constexpr SZ Za_2 = mksz(-0.681461751461029, 0.9113116264343262);
constexpr SZ Za2  = mksz(-0.7149235010147095, 0.908741295337677);
constexpr SZ Zb_2 = mksz(-0.005148397758603096, 0.011014967225492);
constexpr SZ Zb2g = mksz(-0.09436552226543427, 0.07623167335987091);
constexpr SZ Zc_2 = mksz(-1.2279887199401855, 1.1102137565612793);
constexpr SZ Zc2  = mksz(-1.6760436296463013, 1.200895071029663);
constexpr SZ Zd_2 = mksz(-0.008141756057739258, 0.00894666276872158);
constexpr SZ Zd2  = mksz(-0.43875735998153687, 0.1262134611606598);
constexpr SZ Ze_2 = mksz(-0.6732944250106812, 0.6314664483070374);

struct RecP {
  SZ wr, wz, wn;
  SZ a, c, e;
  SZ b1, b2, d1, d2, f1, f2;
  SZ r1, r2, z1, z2;
  SZ n1, n2, n3;
  SZ hn1, hn2, hn3, rnn;
};
constexpr RecP PL1 = { ZWhr1, ZWhz1, ZWhn1, Za1, Zc1, Ze1, Zb_1, Zb1, Zd_1, Zd1, Zf_1, Zf1,
                       Zr_1, Zr1, Zz_1, Zz1, Zn11, Zn21, Zn1, Zhn11, Zhn21, Zhn31, Zrnn };
constexpr RecP PL2 = { ZWhr2, ZWhz2, ZWhn2, Za2, Zc2, Ze1, Zb_2, Zb2g, Zd_2, Zd2, Zf_1, Zf1,
                       Zr_1, Zr1, Zz_1, Zz1, Zn11, Zn21, Zn1, Zhn11, Zhn21, Zhn31, Zrnn };

// ---------------- device helpers ----------------
DEV float fq_(float x, float s, float z){
  float q = rintf(x / s) + z;
  q = fminf(fmaxf(q, 0.f), 255.f);
  return (q - z) * s;
}
DEV float sigm_(float v){ return 1.f / (1.f + expf(-v)); }

DEV unsigned udot4_(unsigned a, unsigned b, unsigned c){
#if defined(__has_builtin) && __has_builtin(__builtin_amdgcn_udot4)
  return __builtin_amdgcn_udot4(a, b, c, false);
#else
  return c + (a & 255u) * (b & 255u) + ((a >> 8) & 255u) * ((b >> 8) & 255u)
           + ((a >> 16) & 255u) * ((b >> 16) & 255u) + (a >> 24) * (b >> 24);
#endif
}

// ---------------- prep kernels ----------------
struct BJob { const float* src; float* dst; int n; float s; float z; };
struct BJobs { BJob j[16]; };
__global__ __launch_bounds__(256) void kbias(BJobs jobs){
  BJob J = jobs.j[blockIdx.x];
  for (int i = threadIdx.x; i < J.n; i += 256) J.dst[i] = fq_(J.src[i], J.s, J.z);
}

struct W6 { const float* W[6]; float s[6]; float z[6]; };
// six Wh [400][400] (k-major) -> u8 codes, column-major [m][j][k]
__global__ __launch_bounds__(256) void kwhc6(W6 jb, unsigned char* __restrict__ dst){
  int i = blockIdx.x * 256 + threadIdx.x;
  if (i < 960000) {
    int m = i / 160000, r = i - m * 160000;
    int j = r / 400, k = r - j * 400;
    float q = rintf(jb.W[m][k * 400 + j] / jb.s[m]) + jb.z[m];
    q = fminf(fmaxf(q, 0.f), 255.f);
    dst[i] = (unsigned char)q;
  }
}
__global__ __launch_bounds__(256) void kcolsum(const unsigned char* __restrict__ WhC, int* __restrict__ cs){
  int i = blockIdx.x * 256 + threadIdx.x;
  if (i < 2400) {
    const unsigned char* p = WhC + (size_t)i * 400;
    int s = 0;
    for (int k = 0; k < 400; ++k) s += p[k];
    cs[i] = s;
  }
}
// six Wi [400][400] -> transposed biased codes [m][n][464] + colsum(q-128)
__global__ __launch_bounds__(256) void kwic6(W6 jb, signed char* __restrict__ WiT, int* __restrict__ cs){
  for (int idx = blockIdx.x * 256 + threadIdx.x; idx < 960000; idx += gridDim.x * 256) {
    int m = idx / 160000, r = idx - m * 160000;
    int k = r / 400, n = r - k * 400;
    float q = rintf(jb.W[m][r] / jb.s[m]) + jb.z[m];
    q = fminf(fmaxf(q, 0.f), 255.f);
    int qi = (int)q;
    WiT[(size_t)m * 185600 + (size_t)n * 464 + k] = (signed char)(qi ^ 0x80);
    atomicAdd(&cs[m * 400 + n], qi - 128);
  }
  for (int idx = blockIdx.x * 256 + threadIdx.x; idx < 153600; idx += gridDim.x * 256) {
    int m = idx / 25600, r = idx - m * 25600;
    int n = r / 64, p = r - n * 64;
    WiT[(size_t)m * 185600 + (size_t)n * 464 + 400 + p] = 0;
  }
}
// W [K][N] f32 -> transposed biased codes Bt [N][464] + colsum(q-128)  (FC1/FC2)
__global__ __launch_bounds__(256) void kwic(const float* __restrict__ W, signed char* __restrict__ Bt,
                                            int* __restrict__ cs, float s, float z, int K, int N){
  int total1 = K * N, total2 = (464 - K) * N;
  for (int idx = blockIdx.x * 256 + threadIdx.x; idx < total1; idx += gridDim.x * 256) {
    int k = idx / N, n = idx - k * N;
    float q = rintf(W[idx] / s) + z;
    q = fminf(fmaxf(q, 0.f), 255.f);
    int qi = (int)q;
    Bt[(size_t)n * 464 + k] = (signed char)(qi ^ 0x80);
    atomicAdd(&cs[n], qi - 128);
  }
  for (int idx = blockIdx.x * 256 + threadIdx.x; idx < total2; idx += gridDim.x * 256) {
    int n = idx / (464 - K), k = K + (idx - n * (464 - K));
    Bt[(size_t)n * 464 + k] = 0;
  }
}
// W [K][N] f32 -> transposed bf16 INTEGER codes (q-z) in [N][608] (pad 0)  (FC3/FC4)
__global__ __launch_bounds__(256) void kwbf(const float* __restrict__ W, bf16_t* __restrict__ Bt,
                                            float s, float z, int K, int N){
  int total1 = K * N, total2 = (608 - K) * N;
  for (int idx = blockIdx.x * 256 + threadIdx.x; idx < total1; idx += gridDim.x * 256) {
    int k = idx / N, n = idx - k * N;
    float q = rintf(W[idx] / s) + z;
    q = fminf(fmaxf(q, 0.f), 255.f);
    Bt[(size_t)n * 608 + k] = (bf16_t)(q - z);     // integer in [-255,255]: exact in bf16
  }
  for (int idx = blockIdx.x * 256 + threadIdx.x; idx < total2; idx += gridDim.x * 256) {
    int n = idx / (608 - K), k = K + (idx - n * (608 - K));
    Bt[(size_t)n * 608 + k] = (bf16_t)0.f;
  }
}
// quantize x [B,T,F] -> xcq codes [T*64+b][464] (pads = code 128)
__global__ __launch_bounds__(256) void kxq(const float* __restrict__ x, unsigned char* __restrict__ xcq,
                                           float s, float z){
  int idx = blockIdx.x * 256 + threadIdx.x;
  if (idx < 64000 * 464) {
    int row = idx / 464, c = idx - row * 464;
    unsigned char code = 128;
    if (c < 257) {
      int bb = row & 63, tt = row >> 6;
      float q = rintf(x[((size_t)bb * 1000 + tt) * 257 + c] / s) + z;
      q = fminf(fmaxf(q, 0.f), 255.f);
      code = (unsigned char)q;
    }
    xcq[idx] = code;
  }
}
// per-row sums of (q-128) over w4 uint4-words of u8 codes (pads must be code 128)
__global__ __launch_bounds__(256) void krsum(const unsigned char* __restrict__ A, int* __restrict__ rs,
                                             int w4){
  int r = blockIdx.x * 256 + threadIdx.x;
  const unsigned* p = (const unsigned*)(A + (size_t)r * (w4 * 16));
  unsigned s = 0;
  for (int i = 0; i < w4 * 4; ++i) s = udot4_(p[i], 0x01010101u, s);
  rs[r] = (int)s - 128 * 4 * (w4 * 4);
}
// init tag-0 slot of both h-publish rings with h0 codes (tag in hi-32 = 0)
__global__ __launch_bounds__(256) void kinit(unsigned long long* __restrict__ hp1,
                                             unsigned long long* __restrict__ hp2, unsigned code){
  int i = blockIdx.x * 256 + threadIdx.x;
  if (i < 6400) {
    unsigned long long w = (unsigned long long)(code * 0x01010101u);
    hp1[i] = w; hp2[i] = w;
  }
}

// ---------------- exact-int i8 MFMA GEMM ----------------
// BM=64, BN=80, K padded to 448. dot_int = S + czw*RA' + cza*CW' + cconst.
__global__ __launch_bounds__(256) void gemm_i8(
    const unsigned char* __restrict__ Au8, int strideA, int aw4,
    const int* __restrict__ rowsum,
    const signed char* __restrict__ Bt, const int* __restrict__ colsum,
    const float* __restrict__ bias,
    unsigned char* __restrict__ outU8, float* __restrict__ outF,
    int N, int nb, int outStride, int epMode,
    int czw, int cza, int cconst, float ss,
    float e1S, float e1Z, float e2S, float e2Z)
{
  __shared__ __align__(16) signed char Asl[64 * 464];
  __shared__ __align__(16) signed char Bsl[80 * 464];
  const int tid = threadIdx.x;
  const int bm = blockIdx.x / nb;
  const int bn = blockIdx.x - bm * nb;
  const int m0 = bm * 64;
  const int n0 = bn * 80;
  for (int i = tid; i < 80 * 29; i += 256) {
    int r = i / 29, c = i - r * 29;
    uint4 v;
    if (n0 + r < N) v = *(const uint4*)(Bt + (size_t)(n0 + r) * 464 + c * 16);
    else { v.x = 0u; v.y = 0u; v.z = 0u; v.w = 0u; }
    *(uint4*)(Bsl + (size_t)r * 464 + c * 16) = v;
  }
  for (int i = tid; i < 64 * 29; i += 256) {
    int r = i / 29, c = i - r * 29;
    uint4 v;
    if (c < aw4) {
      v = *(const uint4*)(Au8 + (size_t)(m0 + r) * strideA + c * 16);
      v.x ^= 0x80808080u; v.y ^= 0x80808080u; v.z ^= 0x80808080u; v.w ^= 0x80808080u;
    } else { v.x = 0u; v.y = 0u; v.z = 0u; v.w = 0u; }
    *(uint4*)(Asl + (size_t)r * 464 + c * 16) = v;
  }
  __syncthreads();
  const int wv = tid >> 6, ln = tid & 63;
  const int lr = ln & 15;
  const int lk = ln >> 4;
  v4i acc[5];
#pragma unroll
  for (int j = 0; j < 5; ++j) { acc[j][0] = 0; acc[j][1] = 0; acc[j][2] = 0; acc[j][3] = 0; }
#pragma unroll
  for (int kc = 0; kc < 7; ++kc) {
    int kb = kc * 64 + lk * 16;
    v4i a = *(const v4i*)(Asl + (size_t)(wv * 16 + lr) * 464 + kb);
#pragma unroll
    for (int j = 0; j < 5; ++j) {
      v4i b = *(const v4i*)(Bsl + (size_t)(j * 16 + lr) * 464 + kb);
      acc[j] = __builtin_amdgcn_mfma_i32_16x16x64_i8(a, b, acc[j], 0, 0, 0);
    }
  }
#pragma unroll
  for (int reg = 0; reg < 4; ++reg) {
    int row = m0 + wv * 16 + lk * 4 + reg;
    int RA = rowsum[row];
#pragma unroll
    for (int j = 0; j < 5; ++j) {
      int col = n0 + j * 16 + lr;
      if (col >= N) continue;
      int I = acc[j][reg] + czw * RA + cza * colsum[col] + cconst;
      float v = (float)I * ss;
      if (epMode == 0) {
        v = fq_(v, e1S, e1Z) + bias[col];
        float q = rintf(v / e2S) + e2Z;
        q = fminf(fmaxf(q, 0.f), 255.f);
        outU8[(size_t)row * outStride + col] = (unsigned char)q;
      } else {
        v += bias[col];
        v = fmaxf(v, 0.f);
        outF[(size_t)row * outStride + col] = v;
      }
    }
  }
}

// ---------------- bf16x2-split MFMA GEMM (FC3/FC4) ----------------
// A: f32 [M][600] (hi/lo bf16 split in registers). B: exact bf16 integer codes [N][608]
// full-K resident in LDS. BM=128 (8 waves x 16 rows), BN=128. out = ep(acc*sc + bias).
__global__ __launch_bounds__(512) void gemm_bf(
    const float* __restrict__ A, const bf16_t* __restrict__ Bt,
    const float* __restrict__ bias, float* __restrict__ outF,
    int N, int nb, int epMode, int rowOff, float sc)
{
  __shared__ __align__(16) bf16_t Bs[128 * 616];   // row stride 616 (conflict-free b128)
  const int tid = threadIdx.x;
  const int bm = blockIdx.x / nb;
  const int bn = blockIdx.x - bm * nb;
  const int m0 = bm * 128;
  const int n0 = bn * 128;
  for (int i = tid; i < 128 * 76; i += 512) {
    int r = i / 76, c = i - r * 76;
    uint4 v; v.x = 0u; v.y = 0u; v.z = 0u; v.w = 0u;
    if (n0 + r < N) v = *(const uint4*)((const char*)(Bt + (size_t)(n0 + r) * 608) + c * 16);
    *(uint4*)((char*)(Bs + (size_t)r * 616) + c * 16) = v;
  }
  __syncthreads();
  const int wv = tid >> 6, ln = tid & 63;
  const int lr = ln & 15, quad = ln >> 4;
  const float* arp = A + (size_t)(m0 + wv * 16 + lr) * 600;
  v4f acc[8];
#pragma unroll
  for (int j = 0; j < 8; ++j) { acc[j][0] = 0.f; acc[j][1] = 0.f; acc[j][2] = 0.f; acc[j][3] = 0.f; }
  for (int kc = 0; kc < 19; ++kc) {
    int kb = kc * 32 + quad * 8;
    float af[8];
    if (kc == 18 && quad == 3) {
#pragma unroll
      for (int j = 0; j < 8; ++j) af[j] = 0.f;
    } else {
      *(float4*)&af[0] = *(const float4*)(arp + kb);
      *(float4*)&af[4] = *(const float4*)(arp + kb + 4);
    }
    v8bf ah, al;
#pragma unroll
    for (int j = 0; j < 8; ++j) {
      float xx = af[j];
      bf16_t h = (bf16_t)xx;
      ah[j] = h;
      al[j] = (bf16_t)(xx - (float)h);
    }
#pragma unroll
    for (int nf = 0; nf < 8; ++nf) {
      v8bf bfrag = *(const v8bf*)(Bs + (size_t)(nf * 16 + lr) * 616 + kc * 32 + quad * 8);
      acc[nf] = __builtin_amdgcn_mfma_f32_16x16x32_bf16(ah, bfrag, acc[nf], 0, 0, 0);
      acc[nf] = __builtin_amdgcn_mfma_f32_16x16x32_bf16(al, bfrag, acc[nf], 0, 0, 0);
    }
  }
  // epilogue: C col = lane&15, row = quad*4 + reg (within wave's 16-row strip)
#pragma unroll
  for (int nf = 0; nf < 8; ++nf) {
    int col = n0 + nf * 16 + lr;
    if (col >= N) continue;
    float bcol = bias[col];
#pragma unroll
    for (int reg = 0; reg < 4; ++reg) {
      int row = m0 + wv * 16 + quad * 4 + reg;
      float v = acc[nf][reg] * sc + bcol;
      if (epMode == 2) {
        v = fmaxf(v, 0.f);
        outF[(size_t)row * N + col] = v;
      } else {
        v = sigm_(v);
        int rg = rowOff + row;
        int tt = rg >> 6, bb = rg & 63;
        outF[((size_t)bb * 1000 + tt) * 257 + col] = v;
      }
    }
  }
}

// ---------------- GRU recurrence (unchanged from R5; known-good) ----------------
__global__ __launch_bounds__(384) void gru_rec(
    const unsigned char* __restrict__ WhC, const int* __restrict__ colsum,
    const unsigned char* __restrict__ Aq, const unsigned char* __restrict__ Cq,
    const unsigned char* __restrict__ Eq,
    const float* __restrict__ bhr, const float* __restrict__ bhz, const float* __restrict__ bhn,
    unsigned char* __restrict__ hs,
    unsigned long long* hpub, RecP P)
{
  __shared__ __align__(16) uint4 Wlds[9600];
  __shared__ __align__(16) uint4 hq_own[7];
  __shared__ __align__(16) uint4 hqr[21];
  __shared__ float dots[2][3][100];
  __shared__ unsigned aceb[75];
  __shared__ int HqS_s;
  __shared__ int flag;

  const int tid = threadIdx.x;
  const int wv  = tid >> 6;
  const int ln  = tid & 63;
  const int b   = blockIdx.x & 63;
  const int sl  = blockIdx.x >> 6;
  const int jbase = sl * 100;

  unsigned* Wled = (unsigned*)Wlds;
  unsigned* hqow = (unsigned*)hq_own;
  unsigned* hqrw = (unsigned*)hqr;

  for (int idx = tid; idx < 30000; idx += 384) {
    int cid0 = idx / 100, w = idx - cid0 * 100;
    int c = w / 25, p = w - c * 25;
    int g0 = cid0 / 100, jj0 = cid0 - g0 * 100;
    unsigned word = ((const unsigned*)(WhC + ((size_t)(g0 * 400) + jbase + jj0) * 400))[w];
    int slot = (c * 7 + (p >> 2)) ^ (cid0 & 31);
    Wled[cid0 * 128 + slot * 4 + (p & 3)] = word;
  }
  for (int idx = tid; idx < 3600; idx += 384) {
    int cid0 = idx / 12, r = idx - cid0 * 12;
    int c = r / 3, wd = r - c * 3 + 1;
    int slot = (c * 7 + 6) ^ (cid0 & 31);
    Wled[cid0 * 128 + slot * 4 + wd] = 0u;
  }
  const unsigned code0 = (unsigned)fminf(fmaxf(P.rnn.z, 0.f), 255.f);
  if (tid < 28) hqow[tid] = (tid < 25) ? code0 * 0x01010101u : 0u;
  if (tid >= 32 && tid < 41) {
    int r = tid - 32; int o = r / 3, wd = r - o * 3 + 1;
    hqrw[o * 28 + 24 + wd] = 0u;
  }
  if (tid == 383) flag = -1;

  const int cid = tid;
  int g = cid / 100;
  int jj = cid - g * 100;
  float s1S = 1.f, s1Z = 0.f, s2S = 1.f, s2Z = 0.f, biasj = 0.f, swsh = 0.f;
  int zwi = 0, CSj = 0;
  if (tid < 300) {
    int j = jbase + jj;
    SZ w  = (g == 0) ? P.wr : (g == 1) ? P.wz : P.wn;
    SZ s1 = (g == 0) ? P.b1 : (g == 1) ? P.d1 : P.f1;
    SZ s2 = (g == 0) ? P.b2 : (g == 1) ? P.d2 : P.f2;
    zwi = (int)w.z;
    s1S = s1.s; s1Z = s1.z; s2S = s2.s; s2Z = s2.z;
    biasj = ((g == 0) ? bhr : (g == 1) ? bhz : bhn)[j];
    CSj = colsum[g * 400 + j];
    swsh = w.s * P.rnn.s;
  }
  const int zhi = (int)P.rnn.z;
  const int swm = cid & 31;

  unsigned hprev = code0;
  __syncthreads();

  for (int t = 0; t < 1000; ++t) {
    if (wv == 5) {
      size_t row = (size_t)t * 64 + b;
      int w0 = ln, w1 = 64 + ln;
      int wh0 = w0 / 25, wi0 = w0 - wh0 * 25;
      const unsigned char* p0 = (wh0 == 0) ? Aq : (wh0 == 1) ? Cq : Eq;
      unsigned v0 = *(const unsigned*)(p0 + row * 400 + jbase + wi0 * 4);
      unsigned v1 = 0;
      if (ln < 11) {
        int wh1 = w1 / 25, wi1 = w1 - wh1 * 25;
        const unsigned char* p1 = (wh1 == 0) ? Aq : (wh1 == 1) ? Cq : Eq;
        v1 = *(const unsigned*)(p1 + row * 400 + jbase + wi1 * 4);
      }
      const unsigned long long* base = hpub + ((size_t)(t & 3) * 64 + b) * 100;
      unsigned pay0, pay1 = 0;
      {
        int o = ln / 25, p = ln - o * 25;
        int so = (sl + o + 1) & 3;
        const unsigned long long* src = base + so * 25 + p;
        unsigned long long w64;
        while ((unsigned)((w64 = __hip_atomic_load(src, __ATOMIC_RELAXED, __HIP_MEMORY_SCOPE_AGENT)) >> 32)
               != (unsigned)t) { }
        pay0 = (unsigned)w64;
        hqrw[o * 28 + ((p >> 2) * 4) + (p & 3)] = pay0;
      }
      if (ln < 11) {
        int widx = 64 + ln;
        int o = widx / 25, p = widx - o * 25;
        int so = (sl + o + 1) & 3;
        const unsigned long long* src = base + so * 25 + p;
        unsigned long long w64;
        while ((unsigned)((w64 = __hip_atomic_load(src, __ATOMIC_RELAXED, __HIP_MEMORY_SCOPE_AGENT)) >> 32)
               != (unsigned)t) { }
        pay1 = (unsigned)w64;
        hqrw[o * 28 + ((p >> 2) * 4) + (p & 3)] = pay1;
      }
      unsigned hp = udot4_(pay0, 0x01010101u, 0u);
      if (ln < 11) hp = udot4_(pay1, 0x01010101u, hp);
      if (ln < 25) hp = udot4_(hqow[ln], 0x01010101u, hp);
#pragma unroll
      for (int off = 32; off; off >>= 1) hp += __shfl_down(hp, off, 64);
      if (ln == 0) HqS_s = (int)hp;
      __hip_atomic_store(&flag, t, __ATOMIC_RELEASE, __HIP_MEMORY_SCOPE_WORKGROUP);
      aceb[ln] = v0;
      if (ln < 11) aceb[64 + ln] = v1;
      if (t > 0 && ln < 25)
        *(unsigned*)(hs + ((size_t)(t - 1) * 64 + b) * 400 + jbase + ln * 4) = hqow[ln];
    } else if (tid < 300) {
      unsigned acc = 0;
      const uint4* wcol = &Wlds[cid * 32];
#pragma unroll
      for (int i = 0; i < 7; ++i) {
        uint4 h = hq_own[i];
        uint4 w = wcol[(sl * 7 + i) ^ swm];
        acc = udot4_(w.x, h.x, acc);
        acc = udot4_(w.y, h.y, acc);
        acc = udot4_(w.z, h.z, acc);
        acc = udot4_(w.w, h.w, acc);
      }
      while (__hip_atomic_load(&flag, __ATOMIC_ACQUIRE, __HIP_MEMORY_SCOPE_WORKGROUP) < t)
        __builtin_amdgcn_s_sleep(1);
#pragma unroll
      for (int o = 0; o < 3; ++o) {
        int c = (sl + o + 1) & 3;
#pragma unroll
        for (int i = 0; i < 7; ++i) {
          uint4 h = hqr[o * 7 + i];
          uint4 w = wcol[(c * 7 + i) ^ swm];
          acc = udot4_(w.x, h.x, acc);
          acc = udot4_(w.y, h.y, acc);
          acc = udot4_(w.z, h.z, acc);
          acc = udot4_(w.w, h.w, acc);
        }
      }
      int I = (int)acc - zwi * HqS_s - zhi * CSj + 400 * zhi * zwi;
      float dot = (float)I * swsh;
      float v = fq_(dot, s1S, s1Z) + biasj;
      v = fq_(v, s2S, s2Z);
      dots[t & 1][g][jj] = v;
    }
    __syncthreads();
    if (tid < 128) {
      int m = (tid < 100) ? tid : 99;
      const unsigned char* aceb8 = (const unsigned char*)aceb;
      float a = ((float)aceb8[m]       - P.a.z) * P.a.s;
      float c = ((float)aceb8[100 + m] - P.c.z) * P.c.s;
      float e = ((float)aceb8[200 + m] - P.e.z) * P.e.s;
      float bb = dots[t & 1][0][m], dd = dots[t & 1][1][m], ff = dots[t & 1][2][m];
      float r  = fq_(sigm_(fq_(a + bb, P.r1.s, P.r1.z)), P.r2.s, P.r2.z);
      float zz = fq_(sigm_(fq_(c + dd, P.z1.s, P.z1.z)), P.z2.s, P.z2.z);
      float nn = fq_(tanhf(fq_(e + fq_(r * ff, P.n1.s, P.n1.z), P.n2.s, P.n2.z)), P.n3.s, P.n3.z);
      float hold = ((float)hprev - P.rnn.z) * P.rnn.s;
      float hn2v = fq_(fq_(1.f - zz, P.hn1.s, P.hn1.z) * nn, P.hn2.s, P.hn2.z);
      float hn3v = fq_(zz * hold, P.hn3.s, P.hn3.z);
      float hnew = hn2v + hn3v;
      float q = rintf(hnew / P.rnn.s) + P.rnn.z;
      q = fminf(fmaxf(q, 0.f), 255.f);
      unsigned code = (unsigned)q;
      unsigned c1 = __shfl_down(code, 1);
      unsigned c2 = __shfl_down(code, 2);
      unsigned c3 = __shfl_down(code, 3);
      if (tid < 100) {
        if ((tid & 3) == 0) {
          unsigned packed = code | (c1 << 8) | (c2 << 16) | (c3 << 24);
          unsigned long long out64 = ((unsigned long long)(unsigned)(t + 1) << 32) | packed;
          unsigned long long* dst = hpub + ((size_t)((t + 1) & 3) * 64 + b) * 100 + sl * 25 + (tid >> 2);
          __hip_atomic_store(dst, out64, __ATOMIC_RELAXED, __HIP_MEMORY_SCOPE_AGENT);
          hqow[tid >> 2] = packed;
        }
        hprev = code;
      }
    }
    __syncthreads();
  }
  if (wv == 5 && ln < 25)
    *(unsigned*)(hs + ((size_t)999 * 64 + b) * 400 + jbase + ln * 4) = hqow[ln];
}

// ---------------- host launch ----------------
extern "C" void kernel_launch(void* const* d_in, const int* in_sizes, int n_in,
                              void* d_out, int out_size, void* d_ws, size_t ws_size,
                              hipStream_t stream)
{
  const float* x    = (const float*)d_in[0];
  const float* Wfc1 = (const float*)d_in[1];
  const float* bfc1 = (const float*)d_in[2];
  const float* Wiz1 = (const float*)d_in[3];  const float* Whz1 = (const float*)d_in[4];
  const float* biz1 = (const float*)d_in[5];  const float* bhz1 = (const float*)d_in[6];
  const float* Wir1 = (const float*)d_in[7];  const float* Whr1 = (const float*)d_in[8];
  const float* bir1 = (const float*)d_in[9];  const float* bhr1 = (const float*)d_in[10];
  const float* Win1 = (const float*)d_in[11]; const float* Whn1 = (const float*)d_in[12];
  const float* bin1 = (const float*)d_in[13]; const float* bhn1 = (const float*)d_in[14];
  const float* Wiz2 = (const float*)d_in[15]; const float* Whz2 = (const float*)d_in[16];
  const float* biz2 = (const float*)d_in[17]; const float* bhz2 = (const float*)d_in[18];
  const float* Wir2 = (const float*)d_in[19]; const float* Whr2 = (const float*)d_in[20];
  const float* bir2 = (const float*)d_in[21]; const float* bhr2 = (const float*)d_in[22];
  const float* Win2 = (const float*)d_in[23]; const float* Whn2 = (const float*)d_in[24];
  const float* bin2 = (const float*)d_in[25]; const float* bhn2 = (const float*)d_in[26];
  const float* Wfc2 = (const float*)d_in[27]; const float* bfc2 = (const float*)d_in[28];
  const float* Wfc3 = (const float*)d_in[29]; const float* bfc3 = (const float*)d_in[30];
  const float* Wfc4 = (const float*)d_in[31]; const float* bfc4 = (const float*)d_in[32];
  float* out = (float*)d_out;

  char* wp = (char*)d_ws;
  auto alloc = [&](size_t bytes) -> void* {
    void* p = (void*)wp;
    wp += (bytes + 255) & ~(size_t)255;
    return p;
  };
  float* b1q = (float*)alloc(400 * 4);
  float* biq = (float*)alloc(2400 * 4);
  float* bhq = (float*)alloc(2400 * 4);
  float* b2q = (float*)alloc(600 * 4);
  float* b3q = (float*)alloc(600 * 4);
  float* b4q = (float*)alloc(257 * 4);
  unsigned char* WhC = (unsigned char*)alloc(960000);
  int* colsum = (int*)alloc(2400 * 4);
  signed char* WiT = (signed char*)alloc(7 * 400 * 464);  // 6 proj + W1
  signed char* Bt2 = (signed char*)alloc(600 * 464);      // W2 (i8)
  bf16_t* Bt3 = (bf16_t*)alloc(600 * 608 * 2);            // W3 bf16 codes
  bf16_t* Bt4 = (bf16_t*)alloc(257 * 608 * 2);            // W4 bf16 codes
  int* cwi = (int*)alloc((7 * 400 + 600) * 4);
  int* rsX1 = (int*)alloc(64000 * 4);
  int* rsX  = (int*)alloc(64000 * 4);
  int* rsH  = (int*)alloc(64000 * 4);
  int* rsH2 = (int*)alloc(64000 * 4);
  unsigned char* xsq = (unsigned char*)alloc(25600000);
  unsigned char* Aq  = (unsigned char*)alloc(25600000);
  unsigned char* Cq  = (unsigned char*)alloc(25600000);
  unsigned char* Eq  = (unsigned char*)alloc(25600000);
  unsigned char* hs1 = (unsigned char*)alloc(25600000);
  unsigned char* hs2 = (unsigned char*)alloc(25600000);
  unsigned long long* hpub1 = (unsigned long long*)alloc(4 * 64 * 100 * 8);
  unsigned long long* hpub2 = (unsigned long long*)alloc(4 * 64 * 100 * 8);
  // overlays on dead regions
  float* y2c = (float*)Aq;                       // 38.4 MB (A/C/E dead during FC chain)
  float* y3c = (float*)(Aq + 38400000);          // 38.4 MB
  unsigned char* xcq = hs1;                      // x codes [64000][464] (hs1 dead pre-rec1)

  // ---- merged prep: all 16 bias fq in one launch ----
  BJobs bj;
  bj.j[0]  = { bfc1, b1q,        400, Zbfc1.s, Zbfc1.z };
  bj.j[1]  = { bir1, biq + 0,    400, Zbir1.s, Zbir1.z };
  bj.j[2]  = { biz1, biq + 400,  400, Zbiz1.s, Zbiz1.z };
  bj.j[3]  = { bin1, biq + 800,  400, Zbin1.s, Zbin1.z };
  bj.j[4]  = { bir2, biq + 1200, 400, Zbir2.s, Zbir2.z };
  bj.j[5]  = { biz2, biq + 1600, 400, Zbiz2.s, Zbiz2.z };
  bj.j[6]  = { bin2, biq + 2000, 400, Zbin2.s, Zbin2.z };
  bj.j[7]  = { bhr1, bhq + 0,    400, Zbhr1.s, Zbhr1.z };
  bj.j[8]  = { bhz1, bhq + 400,  400, Zbhz1.s, Zbhz1.z };
  bj.j[9]  = { bhn1, bhq + 800,  400, Zbhn1.s, Zbhn1.z };
  bj.j[10] = { bhr2, bhq + 1200, 400, Zbhr2.s, Zbhr2.z };
  bj.j[11] = { bhz2, bhq + 1600, 400, Zbhz2.s, Zbhz2.z };
  bj.j[12] = { bhn2, bhq + 2000, 400, Zbhn2.s, Zbhn2.z };
  bj.j[13] = { bfc2, b2q,        600, Zbfc2.s, Zbfc2.z };
  bj.j[14] = { bfc3, b3q,        600, Zbfc3.s, Zbfc3.z };
  bj.j[15] = { bfc4, b4q,        257, Zbfc4.s, Zbfc4.z };
  kbias<<<dim3(16), dim3(256), 0, stream>>>(bj);

  W6 wh = { { Whr1, Whz1, Whn1, Whr2, Whz2, Whn2 },
            { ZWhr1.s, ZWhz1.s, ZWhn1.s, ZWhr2.s, ZWhz2.s, ZWhn2.s },
            { ZWhr1.z, ZWhz1.z, ZWhn1.z, ZWhr2.z, ZWhz2.z, ZWhn2.z } };
  kwhc6<<<dim3(3750), dim3(256), 0, stream>>>(wh, WhC);
  kcolsum<<<dim3(10), dim3(256), 0, stream>>>(WhC, colsum);
  unsigned code0 = (unsigned)(Zrnn.z < 0.f ? 0.f : (Zrnn.z > 255.f ? 255.f : Zrnn.z));
  kinit<<<dim3(25), dim3(256), 0, stream>>>(hpub1, hpub2, code0);

  hipMemsetAsync(cwi, 0, (7 * 400 + 600) * 4, stream);
  W6 wi = { { Wir1, Wiz1, Win1, Wir2, Wiz2, Win2 },
            { ZWir1.s, ZWiz1.s, ZWin1.s, ZWir2.s, ZWiz2.s, ZWin2.s },
            { ZWir1.z, ZWiz1.z, ZWin1.z, ZWir2.z, ZWiz2.z, ZWin2.z } };
  kwic6<<<dim3(625), dim3(256), 0, stream>>>(wi, WiT, cwi);
  kwic<<<dim3(625), dim3(256), 0, stream>>>(Wfc1, WiT + (size_t)6 * 185600, cwi + 2400, ZW1.s, ZW1.z, 257, 400);
  kwic<<<dim3(625), dim3(256), 0, stream>>>(Wfc2, Bt2, cwi + 2800, ZWfc2.s, ZWfc2.z, 400, 600);
  kwbf<<<dim3(625), dim3(256), 0, stream>>>(Wfc3, Bt3, ZWfc3.s, ZWfc3.z, 600, 600);
  kwbf<<<dim3(625), dim3(256), 0, stream>>>(Wfc4, Bt4, ZWfc4.s, ZWfc4.z, 600, 257);

  auto gi8 = [&](const unsigned char* A, int strideA, int aw4, const int* rs,
                 const signed char* Bt, const int* cs, const float* bias,
                 unsigned char* oU8, float* oF, int M, int N, int outStride, int epMode,
                 SZ a, SZ w, int Kreal, float ss, SZ e1, SZ e2) {
    int czw = 128 - (int)w.z, cza = 128 - (int)a.z;
    int cconst = Kreal * cza * czw;
    int nb = (N + 79) / 80;
    gemm_i8<<<dim3((M / 64) * nb), dim3(256), 0, stream>>>(
        A, strideA, aw4, rs, Bt, cs, bias, oU8, oF, N, nb, outStride, epMode,
        czw, cza, cconst, ss, e1.s, e1.z, e2.s, e2.z);
  };

  // ---- FC1 (exact-int i8): x codes -> xsq codes ----
  kxq<<<dim3((64000 * 464 + 255) / 256), dim3(256), 0, stream>>>(x, xcq, Zx.s, Zx.z);
  krsum<<<dim3(250), dim3(256), 0, stream>>>(xcq, rsX1, 29);
  gi8(xcq, 464, 29, rsX1, WiT + (size_t)6 * 185600, cwi + 2400, b1q,
      xsq, nullptr, 64000, 400, 400, 0, Zx, ZW1, 257, Zx.s * ZW1.s, Zfc1mm, Zfc1add);

  // ---- GRU layer 1 input projections (i8) ----
  krsum<<<dim3(250), dim3(256), 0, stream>>>(xsq, rsX, 25);
  gi8(xsq, 400, 25, rsX, WiT + (size_t)0 * 185600, cwi + 0,    biq + 0,   Aq, nullptr,
      64000, 400, 400, 0, Zfc1add, ZWir1, 400, Zfc1add.s * ZWir1.s, Za_1, Za1);
  gi8(xsq, 400, 25, rsX, WiT + (size_t)1 * 185600, cwi + 400,  biq + 400, Cq, nullptr,
      64000, 400, 400, 0, Zfc1add, ZWiz1, 400, Zfc1add.s * ZWiz1.s, Zc_1, Zc1);
  gi8(xsq, 400, 25, rsX, WiT + (size_t)2 * 185600, cwi + 800,  biq + 800, Eq, nullptr,
      64000, 400, 400, 0, Zfc1add, ZWin1, 400, Zfc1add.s * ZWin1.s, Ze_1, Ze1);
  // ---- GRU layer 1 recurrence ----
  gru_rec<<<dim3(256), dim3(384), 0, stream>>>(WhC, colsum, Aq, Cq, Eq,
                                               bhq + 0, bhq + 400, bhq + 800,
                                               hs1, hpub1, PL1);
  // ---- GRU layer 2 input projections (i8) ----
  krsum<<<dim3(250), dim3(256), 0, stream>>>(hs1, rsH, 25);
  gi8(hs1, 400, 25, rsH, WiT + (size_t)3 * 185600, cwi + 1200, biq + 1200, Aq, nullptr,
      64000, 400, 400, 0, Zrnn, ZWir2, 400, Zrnn.s * ZWir2.s, Za_2, Za2);
  gi8(hs1, 400, 25, rsH, WiT + (size_t)4 * 185600, cwi + 1600, biq + 1600, Cq, nullptr,
      64000, 400, 400, 0, Zrnn, ZWiz2, 400, Zrnn.s * ZWiz2.s, Zc_2, Zc2);
  gi8(hs1, 400, 25, rsH, WiT + (size_t)5 * 185600, cwi + 2000, biq + 2000, Eq, nullptr,
      64000, 400, 400, 0, Zrnn, ZWin2, 400, Zrnn.s * ZWin2.s, Ze_2, Ze1);
  // ---- GRU layer 2 recurrence ----
  gru_rec<<<dim3(256), dim3(384), 0, stream>>>(WhC + 480000, colsum + 1200, Aq, Cq, Eq,
                                               bhq + 1200, bhq + 1600, bhq + 2000,
                                               hs2, hpub2, PL2);
  // ---- FC2 (i8) -> FC3 -> FC4 (bf16x2 MFMA) in 4 row chunks ----
  krsum<<<dim3(250), dim3(256), 0, stream>>>(hs2, rsH2, 25);
  for (int rc = 0; rc < 4; ++rc) {
    const unsigned char* a2 = hs2 + (size_t)rc * 16000 * 400;
    gi8(a2, 400, 25, rsH2 + rc * 16000, Bt2, cwi + 2800, b2q, nullptr, y2c,
        16000, 600, 600, 2, Zrnn, ZWfc2, 400, Zrnn.s * ZWfc2.s, Zrnn, Zrnn);
    gemm_bf<<<dim3(125 * 5), dim3(512), 0, stream>>>(y2c, Bt3, b3q, y3c, 600, 5, 2, 0, ZWfc3.s);
    gemm_bf<<<dim3(125 * 3), dim3(512), 0, stream>>>(y3c, Bt4, b4q, out, 257, 3, 3, rc * 16000, ZWfc4.s);
  }
  (void)in_sizes; (void)n_in; (void)out_size; (void)ws_size;
}